// Round 1
// baseline (1768.135 us; speedup 1.0000x reference)
//
#include <hip/hip_runtime.h>
#include <math.h>

// ---------------------------------------------------------------------------
// Upnet_v3 pipeline, f32 baseline (round 0).
// Stages: proj GEMM (S=6 batched NT) -> col-mean -> attn MLP+softmax2 ->
// fuse+reverse -> in-proj GEMM -> causal dwconv+silu -> xp GEMM -> delta ->
// selective scan -> gate -> out GEMM -> residual+LN -> cat -> merge GEMM ->
// bilinear 4x upsample (into zero-padded buf) -> 3x3 conv as 9 shifted GEMMs.
// ---------------------------------------------------------------------------

namespace {
constexpr int kS   = 6;
constexpr int kHP  = 37;
constexpr int kWP  = 37;
constexpr int kN   = 1369;      // HP*WP
constexpr int kCIN = 1536;
constexpr int kCO  = 256;
constexpr int kDS  = 16;
constexpr int kDI  = 512;
constexpr int kHID = 384;
constexpr int kOH  = 148;
constexpr int kOW  = 148;
constexpr int kXPW = 545;       // 2*DS + DI + 1
constexpr long kXPS = 746112;   // padded kN*kXPW (746105 -> 746112)

// workspace offsets (floats). up_pad aliases the early-stage region (all dead
// by the time it is memset).
constexpr long OFF_UPPAD   = 0;         // 150*150*256 = 5,760,000
constexpr long OFF_PF      = 0;         // 2,102,784
constexpr long OFF_COLPART = 2102784;   // 11*1536 = 16,896
constexpr long OFF_WFIN    = 2119680;   // 16
constexpr long OFF_FUSED   = 2119696;   // 2*350,464 (fused + xrev)
constexpr long OFF_ZG      = 2820624;   // 2*1,401,856 (ends 5,624,336 < 5,760,000)
constexpr long OFF_Z       = 5760000;   // 2*700,928
constexpr long OFF_XP      = 7161856;   // 2*746,112
constexpr long OFF_DELTA   = 8654080;   // 2*700,928
constexpr long OFF_Y       = 10055936;  // 2*700,928 (y, then y*silu(gate) in place)
constexpr long OFF_GT      = 11457792;  // 2*350,464
constexpr long OFF_SSMOUT  = 12158720;  // 2*350,464
constexpr long OFF_CAT     = 12859648;  // 700,928
constexpr long OFF_MERGED  = 13560576;  // 350,464  -> total 13,911,040 floats (55.6 MB)
} // namespace

// ---------------------------------------------------------------------------
// Generic tiled GEMM: C[m,n] = sum_k A[m,k] * B(k,n).
// NT=1: B stored (Nn, K) k-major (row n contiguous in k)  -> Bs from rows.
// NT=0: B stored (K, Nn) n-major                          -> Bs coalesced in n.
// BM=BN=64, BK=16, 256 threads, 4x4 per thread. Batched via blockIdx.z:
// B pointer = (bz==1 && B1) ? B1 : B0 + bz*sB  (handles split f/b weights).
// ---------------------------------------------------------------------------
template<int NT>
__global__ __launch_bounds__(256)
void gemm_tile(const float* __restrict__ A, int lda, long sA,
               const float* __restrict__ B0, const float* __restrict__ B1,
               int ldb, long sB,
               float* __restrict__ C, int ldc, long sC,
               int M, int Nn, int K)
{
    __shared__ float As[16][65];
    __shared__ float Bs[16][65];
    const int bz = blockIdx.z;
    const float* Ab = A + (long)bz * sA;
    const float* Bb = (B1 != nullptr && bz == 1) ? B1 : B0 + (long)bz * sB;
    float* Cb = C + (long)bz * sC;
    const int m0 = blockIdx.x * 64, n0 = blockIdx.y * 64;
    const int t = threadIdx.x;
    const int tx = t & 15, ty = t >> 4;
    float acc[4][4] = {};
    for (int k0 = 0; k0 < K; k0 += 16) {
        #pragma unroll
        for (int p = 0; p < 4; ++p) {
            int lm = (t >> 4) + p * 16;
            int gm = m0 + lm; if (gm >= M) gm = M - 1;
            As[t & 15][lm] = Ab[(long)gm * lda + k0 + (t & 15)];
        }
        if (NT) {
            #pragma unroll
            for (int p = 0; p < 4; ++p) {
                int ln = (t >> 4) + p * 16;
                int gn = n0 + ln; if (gn >= Nn) gn = Nn - 1;
                Bs[t & 15][ln] = Bb[(long)gn * ldb + k0 + (t & 15)];
            }
        } else {
            #pragma unroll
            for (int p = 0; p < 4; ++p) {
                int kk = (t >> 6) + p * 4;
                int ln = t & 63;
                int gn = n0 + ln; if (gn >= Nn) gn = Nn - 1;
                Bs[kk][ln] = Bb[(long)(k0 + kk) * ldb + gn];
            }
        }
        __syncthreads();
        #pragma unroll
        for (int k = 0; k < 16; ++k) {
            float a[4], b4[4];
            #pragma unroll
            for (int i = 0; i < 4; ++i) a[i] = As[k][ty * 4 + i];
            #pragma unroll
            for (int j = 0; j < 4; ++j) b4[j] = Bs[k][tx * 4 + j];
            #pragma unroll
            for (int i = 0; i < 4; ++i)
                #pragma unroll
                for (int j = 0; j < 4; ++j) acc[i][j] += a[i] * b4[j];
        }
        __syncthreads();
    }
    #pragma unroll
    for (int i = 0; i < 4; ++i) {
        int gm = m0 + ty * 4 + i;
        if (gm >= M) continue;
        #pragma unroll
        for (int j = 0; j < 4; ++j) {
            int gn = n0 + tx * 4 + j;
            if (gn >= Nn) continue;
            Cb[(long)gm * ldc + gn] = acc[i][j];
        }
    }
}

// partial column sums of pf over n (deterministic two-stage mean)
__global__ __launch_bounds__(256)
void colmean_kernel(const float* __restrict__ pf, float* __restrict__ colpart)
{
    int s = blockIdx.x, ch = blockIdx.y, o = threadIdx.x;
    int n0 = ch * 128, n1 = n0 + 128 > kN ? kN : n0 + 128;
    float a = 0.f;
    for (int n = n0; n < n1; ++n) a += pf[((long)s * kN + n) * kCO + o];
    colpart[ch * kS * kCO + s * kCO + o] = a;
}

// attention MLP + double softmax -> wfin[6]
__global__ __launch_bounds__(384)
void attn_kernel(const float* __restrict__ colpart,
                 const float* __restrict__ w1, const float* __restrict__ b1,
                 const float* __restrict__ w2, const float* __restrict__ b2,
                 const float* __restrict__ ss, float* __restrict__ wfin)
{
    __shared__ float cm[kS * kCO];
    __shared__ float h[kHID];
    __shared__ float logits[8];
    int t = threadIdx.x;
    for (int c = t; c < kS * kCO; c += kHID) {
        float a = 0.f;
        for (int ch = 0; ch < 11; ++ch) a += colpart[ch * kS * kCO + c];
        cm[c] = a * (1.f / kN);
    }
    __syncthreads();
    float acc = b1[t];
    for (int c = 0; c < kS * kCO; ++c) acc += cm[c] * w1[(long)c * kHID + t];
    h[t] = fmaxf(acc, 0.f);
    __syncthreads();
    if (t < kS) {
        float l = b2[t];
        for (int j = 0; j < kHID; ++j) l += h[j] * w2[j * kS + t];
        logits[t] = l;
    }
    __syncthreads();
    if (t == 0) {
        float w[kS], mx = -1e30f, sum = 0.f;
        for (int s = 0; s < kS; ++s) mx = fmaxf(mx, logits[s]);
        for (int s = 0; s < kS; ++s) { w[s] = expf(logits[s] - mx); sum += w[s]; }
        for (int s = 0; s < kS; ++s) w[s] /= sum;
        mx = -1e30f;
        for (int s = 0; s < kS; ++s) { w[s] *= ss[s]; mx = fmaxf(mx, w[s]); }
        sum = 0.f;
        float e[kS];
        for (int s = 0; s < kS; ++s) { e[s] = expf(w[s] - mx); sum += e[s]; }
        for (int s = 0; s < kS; ++s) wfin[s] = e[s] / sum;
    }
}

// fused = sum_s wfin[s]*pf[s]; also writes the n-reversed copy for the bwd SSM
__global__ __launch_bounds__(256)
void fuse_kernel(const float* __restrict__ pf, const float* __restrict__ wfin,
                 float* __restrict__ fused2)
{
    long idx = (long)blockIdx.x * 256 + threadIdx.x;
    if (idx >= (long)kN * kCO) return;
    float acc = 0.f;
    #pragma unroll
    for (int s = 0; s < kS; ++s) acc += wfin[s] * pf[(long)s * kN * kCO + idx];
    fused2[idx] = acc;
    long n = idx / kCO; int c = (int)(idx % kCO);
    fused2[(long)kN * kCO + (kN - 1 - n) * kCO + c] = acc;
}

// causal depthwise conv (K=4) + silu on first half of zg
__global__ __launch_bounds__(256)
void dwconv_kernel(const float* __restrict__ zg2,
                   const float* __restrict__ wf, const float* __restrict__ bf,
                   const float* __restrict__ wb, const float* __restrict__ bb,
                   float* __restrict__ z2)
{
    long idx = (long)blockIdx.x * 256 + threadIdx.x;
    int dir = blockIdx.y;
    if (idx >= (long)kN * kDI) return;
    long n = idx >> 9; int i = (int)(idx & (kDI - 1));
    const float* zg = zg2 + (long)dir * kN * 2 * kDI;
    const float* w  = dir ? wb : wf;
    const float* b  = dir ? bb : bf;
    float acc = b[i];
    #pragma unroll
    for (int k = 0; k < 4; ++k) {
        long m = n - 3 + k;
        if (m >= 0) acc += w[k * kDI + i] * zg[m * 2 * kDI + i];
    }
    float sg = 1.f / (1.f + expf(-acc));
    z2[(long)dir * kN * kDI + idx] = acc * sg;
}

// delta = softplus(xp[:,32+i] + xp[:,544])
__global__ __launch_bounds__(256)
void delta_kernel(const float* __restrict__ xp2, float* __restrict__ delta2)
{
    long idx = (long)blockIdx.x * 256 + threadIdx.x;
    int dir = blockIdx.y;
    if (idx >= (long)kN * kDI) return;
    long n = idx >> 9; int i = (int)(idx & (kDI - 1));
    const float* xp = xp2 + (long)dir * kXPS + n * kXPW;
    float x = xp[2 * kDS + i] + xp[kXPW - 1];
    float sp = fmaxf(x, 0.f) + log1pf(expf(-fabsf(x)));
    delta2[(long)dir * kN * kDI + idx] = sp;
}

// selective scan: h[n] = exp(-delta*A)*h[n-1] + delta*B*z ; y = <h,C> + D*z
// thread = (i_local, s): 16 channels x 16 states per block; 32 blocks/dir.
__global__ __launch_bounds__(256)
void scan_kernel(const float* __restrict__ delta2, const float* __restrict__ z2,
                 const float* __restrict__ xp2,
                 const float* __restrict__ Df, const float* __restrict__ Db,
                 const float* __restrict__ Alogf, const float* __restrict__ Alogb,
                 float* __restrict__ ybuf2)
{
    int dir = blockIdx.x >> 5;
    int blk = blockIdx.x & 31;
    int t = threadIdx.x;
    int s = t & 15, il = t >> 4;
    int i = blk * 16 + il;
    const float* delta = delta2 + (long)dir * kN * kDI;
    const float* z     = z2     + (long)dir * kN * kDI;
    const float* xp    = xp2    + (long)dir * kXPS;
    const float* D     = dir ? Db : Df;
    const float* Alog  = dir ? Alogb : Alogf;
    float* y           = ybuf2  + (long)dir * kN * kDI;
    float A  = expf(Alog[i * kDS + s]);
    float Dv = D[i];
    float h = 0.f;
    for (int n = 0; n < kN; ++n) {
        float dlt = delta[(long)n * kDI + i];
        float zv  = z[(long)n * kDI + i];
        float Bv  = xp[(long)n * kXPW + s];
        float Cv  = xp[(long)n * kXPW + kDS + s];
        float dA  = __expf(-dlt * A);
        h = dA * h + dlt * Bv * zv;
        float c = h * Cv;
        c += __shfl_xor(c, 1, 16);
        c += __shfl_xor(c, 2, 16);
        c += __shfl_xor(c, 4, 16);
        c += __shfl_xor(c, 8, 16);
        if (s == 0) y[(long)n * kDI + i] = c + Dv * zv;
    }
}

// y *= silu(gate)   (in place on ybuf)
__global__ __launch_bounds__(256)
void mulgate_kernel(const float* __restrict__ zg2, float* __restrict__ ybuf2)
{
    long idx = (long)blockIdx.x * 256 + threadIdx.x;
    int dir = blockIdx.y;
    if (idx >= (long)kN * kDI) return;
    long n = idx >> 9; int i = (int)(idx & (kDI - 1));
    float g = zg2[(long)dir * kN * 2 * kDI + n * 2 * kDI + kDI + i];
    float sg = 1.f / (1.f + expf(-g));
    ybuf2[(long)dir * kN * kDI + idx] *= g * sg;
}

// r = gemm_out + x ; layernorm over CO=256
__global__ __launch_bounds__(256)
void resid_ln_kernel(const float* __restrict__ gt2, const float* __restrict__ x2,
                     const float* __restrict__ gf, const float* __restrict__ betf,
                     const float* __restrict__ gb, const float* __restrict__ betb,
                     float* __restrict__ out2)
{
    int n = blockIdx.x, dir = blockIdx.y, t = threadIdx.x;
    const float* gt = gt2 + ((long)dir * kN + n) * kCO;
    const float* x  = x2  + ((long)dir * kN + n) * kCO;
    const float* g  = dir ? gb : gf;
    const float* be = dir ? betb : betf;
    float r = gt[t] + x[t];
    float s1 = r, s2 = r * r;
    #pragma unroll
    for (int m = 32; m >= 1; m >>= 1) {
        s1 += __shfl_xor(s1, m, 64);
        s2 += __shfl_xor(s2, m, 64);
    }
    __shared__ float red[8];
    int w = t >> 6;
    if ((t & 63) == 0) { red[w] = s1; red[4 + w] = s2; }
    __syncthreads();
    float S1 = red[0] + red[1] + red[2] + red[3];
    float S2 = red[4] + red[5] + red[6] + red[7];
    float mu  = S1 * (1.f / kCO);
    float var = S2 * (1.f / kCO) - mu * mu;
    float inv = rsqrtf(var + 1e-5f);
    out2[((long)dir * kN + n) * kCO + t] = g[t] * (r - mu) * inv + be[t];
}

// cat[n, 0:256] = fwd[n]; cat[n, 256:512] = bwd_rev[N-1-n]
__global__ __launch_bounds__(256)
void cat_kernel(const float* __restrict__ sout2, float* __restrict__ cat)
{
    long idx = (long)blockIdx.x * 256 + threadIdx.x;
    if (idx >= (long)kN * 2 * kCO) return;
    long n = idx / (2 * kCO); int c = (int)(idx % (2 * kCO));
    float v;
    if (c < kCO) v = sout2[n * kCO + c];
    else         v = sout2[(long)kN * kCO + (kN - 1 - n) * kCO + (c - kCO)];
    cat[idx] = v;
}

// bilinear 4x upsample (jax.image.resize triangle, edge-renormalized) into
// zero-padded (150,150,256) buffer interior
__global__ __launch_bounds__(256)
void upsample_kernel(const float* __restrict__ merged, float* __restrict__ up_pad)
{
    int p = blockIdx.x;
    int oy = p / kOW, ox = p - oy * kOW;
    int c = threadIdx.x;
    float sy = (oy + 0.5f) * ((float)kHP / (float)kOH) - 0.5f;
    float sx = (ox + 0.5f) * ((float)kWP / (float)kOW) - 0.5f;
    int iy0 = (int)floorf(sy); float fy = sy - (float)iy0;
    int ix0 = (int)floorf(sx); float fx = sx - (float)ix0;
    float wy0 = 1.f - fy, wy1 = fy, wx0 = 1.f - fx, wx1 = fx;
    int iy1 = iy0 + 1, ix1 = ix0 + 1;
    if (iy0 < 0)       { iy0 = 0;       wy0 = 0.f; }
    if (iy1 > kHP - 1) { iy1 = kHP - 1; wy1 = 0.f; }
    if (ix0 < 0)       { ix0 = 0;       wx0 = 0.f; }
    if (ix1 > kWP - 1) { ix1 = kWP - 1; wx1 = 0.f; }
    float wys = wy0 + wy1; wy0 /= wys; wy1 /= wys;
    float wxs = wx0 + wx1; wx0 /= wxs; wx1 /= wxs;
    const float* M00 = merged + (long)(iy0 * kWP + ix0) * kCO;
    const float* M01 = merged + (long)(iy0 * kWP + ix1) * kCO;
    const float* M10 = merged + (long)(iy1 * kWP + ix0) * kCO;
    const float* M11 = merged + (long)(iy1 * kWP + ix1) * kCO;
    float v = wy0 * (wx0 * M00[c] + wx1 * M01[c]) + wy1 * (wx0 * M10[c] + wx1 * M11[c]);
    up_pad[((long)(oy + 1) * 150 + (ox + 1)) * kCO + c] = v;
}

// 3x3 SAME conv as 9 accumulating shifted GEMMs; output NCHW + bias
__global__ __launch_bounds__(256)
void conv_kernel(const float* __restrict__ up_pad, const float* __restrict__ w,
                 const float* __restrict__ bias, float* __restrict__ out)
{
    __shared__ float As[16][65];
    __shared__ float Bs[16][65];
    int ox0 = blockIdx.x * 64;
    int oy  = blockIdx.y;
    int n0  = blockIdx.z * 64;
    int t = threadIdx.x;
    int tx = t & 15, ty = t >> 4;
    float acc[4][4] = {};
    for (int tap = 0; tap < 9; ++tap) {
        int ky = tap / 3, kx = tap - ky * 3;
        const float* Arow = up_pad + ((long)(oy + ky) * 150 + kx) * kCO;
        const float* Bw   = w + (long)tap * kCO * kCO;
        for (int k0 = 0; k0 < kCO; k0 += 16) {
            #pragma unroll
            for (int p = 0; p < 4; ++p) {
                int lm = (t >> 4) + p * 16;
                int gx = ox0 + lm; if (gx > kOW - 1) gx = kOW - 1;
                As[t & 15][lm] = Arow[(long)gx * kCO + k0 + (t & 15)];
            }
            #pragma unroll
            for (int p = 0; p < 4; ++p) {
                int kk = (t >> 6) + p * 4;
                Bs[kk][t & 63] = Bw[(k0 + kk) * kCO + n0 + (t & 63)];
            }
            __syncthreads();
            #pragma unroll
            for (int k = 0; k < 16; ++k) {
                float a[4], b4[4];
                #pragma unroll
                for (int i2 = 0; i2 < 4; ++i2) a[i2] = As[k][ty * 4 + i2];
                #pragma unroll
                for (int j = 0; j < 4; ++j) b4[j] = Bs[k][tx * 4 + j];
                #pragma unroll
                for (int i2 = 0; i2 < 4; ++i2)
                    #pragma unroll
                    for (int j = 0; j < 4; ++j) acc[i2][j] += a[i2] * b4[j];
            }
            __syncthreads();
        }
    }
    #pragma unroll
    for (int i2 = 0; i2 < 4; ++i2) {
        int gx = ox0 + ty * 4 + i2;
        if (gx >= kOW) continue;
        #pragma unroll
        for (int j = 0; j < 4; ++j) {
            int o = n0 + tx * 4 + j;
            out[(long)o * kOH * kOW + (long)oy * kOW + gx] = acc[i2][j] + bias[o];
        }
    }
}

extern "C" void kernel_launch(void* const* d_in, const int* in_sizes, int n_in,
                              void* d_out, int out_size, void* d_ws, size_t ws_size,
                              hipStream_t stream)
{
    (void)in_sizes; (void)n_in; (void)out_size; (void)ws_size;
    const float* features  = (const float*)d_in[0];
    const float* proj_w    = (const float*)d_in[1];
    const float* attn_w1   = (const float*)d_in[2];
    const float* attn_b1   = (const float*)d_in[3];
    const float* attn_w2   = (const float*)d_in[4];
    const float* attn_b2   = (const float*)d_in[5];
    const float* src_scale = (const float*)d_in[6];
    const float* f_in_w    = (const float*)d_in[7];
    const float* f_conv_w  = (const float*)d_in[8];
    const float* f_conv_b  = (const float*)d_in[9];
    const float* f_xp_w    = (const float*)d_in[10];
    const float* f_Alog    = (const float*)d_in[11];
    const float* f_D       = (const float*)d_in[12];
    const float* f_out_w   = (const float*)d_in[13];
    const float* f_ln_g    = (const float*)d_in[14];
    const float* f_ln_b    = (const float*)d_in[15];
    const float* b_in_w    = (const float*)d_in[16];
    const float* b_conv_w  = (const float*)d_in[17];
    const float* b_conv_b  = (const float*)d_in[18];
    const float* b_xp_w    = (const float*)d_in[19];
    const float* b_Alog    = (const float*)d_in[20];
    const float* b_D       = (const float*)d_in[21];
    const float* b_out_w   = (const float*)d_in[22];
    const float* b_ln_g    = (const float*)d_in[23];
    const float* b_ln_b    = (const float*)d_in[24];
    const float* merge_w   = (const float*)d_in[25];
    const float* co1_w     = (const float*)d_in[26];
    const float* co1_b     = (const float*)d_in[27];

    float* ws      = (float*)d_ws;
    float* outp    = (float*)d_out;
    float* pf      = ws + OFF_PF;
    float* colpart = ws + OFF_COLPART;
    float* wfin    = ws + OFF_WFIN;
    float* fused2  = ws + OFF_FUSED;
    float* zg2     = ws + OFF_ZG;
    float* z2      = ws + OFF_Z;
    float* xp2     = ws + OFF_XP;
    float* delta2  = ws + OFF_DELTA;
    float* ybuf2   = ws + OFF_Y;
    float* gt2     = ws + OFF_GT;
    float* sout2   = ws + OFF_SSMOUT;
    float* catb    = ws + OFF_CAT;
    float* merged  = ws + OFF_MERGED;
    float* up_pad  = ws + OFF_UPPAD;

    // 1. pf[s] = feats[s] @ proj_w[s]^T   (NT, batch 6)
    gemm_tile<1><<<dim3(22, 4, 6), 256, 0, stream>>>(
        features, kCIN, (long)kN * kCIN,
        proj_w, nullptr, kCIN, (long)kCO * kCIN,
        pf, kCO, (long)kN * kCO, kN, kCO, kCIN);
    // 2. deterministic column partial sums
    colmean_kernel<<<dim3(6, 11), 256, 0, stream>>>(pf, colpart);
    // 3. attention weights
    attn_kernel<<<1, 384, 0, stream>>>(colpart, attn_w1, attn_b1, attn_w2, attn_b2,
                                       src_scale, wfin);
    // 4. fuse sources + reversed copy
    fuse_kernel<<<dim3(1369), 256, 0, stream>>>(pf, wfin, fused2);
    // 5. zg = x @ in_w   (NN, batch 2)
    gemm_tile<0><<<dim3(22, 16, 2), 256, 0, stream>>>(
        fused2, kCO, (long)kN * kCO,
        f_in_w, b_in_w, 2 * kDI, 0,
        zg2, 2 * kDI, (long)kN * 2 * kDI, kN, 2 * kDI, kCO);
    // 6. causal dwconv + silu
    dwconv_kernel<<<dim3(2738, 2), 256, 0, stream>>>(zg2, f_conv_w, f_conv_b,
                                                     b_conv_w, b_conv_b, z2);
    // 7. xp = z @ xp_w   (NN, batch 2)
    gemm_tile<0><<<dim3(22, 9, 2), 256, 0, stream>>>(
        z2, kDI, (long)kN * kDI,
        f_xp_w, b_xp_w, kXPW, 0,
        xp2, kXPW, kXPS, kN, kXPW, kDI);
    // 8. delta = softplus(...)
    delta_kernel<<<dim3(2738, 2), 256, 0, stream>>>(xp2, delta2);
    // 9. selective scan
    scan_kernel<<<dim3(64), 256, 0, stream>>>(delta2, z2, xp2, f_D, b_D,
                                              f_Alog, b_Alog, ybuf2);
    // 10. y *= silu(gate)
    mulgate_kernel<<<dim3(2738, 2), 256, 0, stream>>>(zg2, ybuf2);
    // 11. out = y2 @ out_w   (NN, batch 2)
    gemm_tile<0><<<dim3(22, 4, 2), 256, 0, stream>>>(
        ybuf2, kDI, (long)kN * kDI,
        f_out_w, b_out_w, kCO, 0,
        gt2, kCO, (long)kN * kCO, kN, kCO, kDI);
    // 12. residual + layernorm
    resid_ln_kernel<<<dim3(1369, 2), 256, 0, stream>>>(gt2, fused2, f_ln_g, f_ln_b,
                                                       b_ln_g, b_ln_b, sout2);
    // 13. concat fwd / reversed-bwd
    cat_kernel<<<dim3(2738), 256, 0, stream>>>(sout2, catb);
    // 14. merged = cat @ merge_w   (NN)
    gemm_tile<0><<<dim3(22, 4, 1), 256, 0, stream>>>(
        catb, 2 * kCO, 0,
        merge_w, nullptr, kCO, 0,
        merged, kCO, 0, kN, kCO, 2 * kCO);
    // 15. zero padded upsample buffer (aliases dead early-stage ws)
    hipMemsetAsync(up_pad, 0, (size_t)150 * 150 * 256 * sizeof(float), stream);
    // 16. bilinear upsample into padded interior
    upsample_kernel<<<dim3(kOH * kOW), 256, 0, stream>>>(merged, up_pad);
    // 17. 3x3 conv + bias, NCHW output
    conv_kernel<<<dim3(3, 148, 4), 256, 0, stream>>>(up_pad, co1_w, co1_b, outp);
}

// Round 2
// 1158.037 us; speedup vs baseline: 1.5268x; 1.5268x over previous
//
#include <hip/hip_runtime.h>
#include <math.h>

// ---------------------------------------------------------------------------
// Upnet_v3 pipeline, round 1: conv3x3 and proj moved to bf16 MFMA
// (register-only GEMMs, no LDS). Everything else unchanged f32.
// ---------------------------------------------------------------------------

namespace {
constexpr int kS   = 6;
constexpr int kHP  = 37;
constexpr int kWP  = 37;
constexpr int kN   = 1369;      // HP*WP
constexpr int kCIN = 1536;
constexpr int kCO  = 256;
constexpr int kDS  = 16;
constexpr int kDI  = 512;
constexpr int kHID = 384;
constexpr int kOH  = 148;
constexpr int kOW  = 148;
constexpr int kNP  = kOH * kOW; // 21904 output pixels
constexpr int kXPW = 545;       // 2*DS + DI + 1
constexpr long kXPS = 746112;   // padded kN*kXPW

// workspace offsets in f32 units (total 13,911,040 f32 = 55.6 MB)
constexpr long OFF_UPB     = 0;         // bf16 padded upsample: 5,760,000 shorts = 2,880,000 f32
constexpr long OFF_PF      = 0;         // 2,102,784  (dead before upsample)
constexpr long OFF_COLPART = 2102784;   // 16,896
constexpr long OFF_WFIN    = 2119680;   // 16
constexpr long OFF_FUSED   = 2119696;   // 2*350,464
constexpr long OFF_PROJWB  = 2200000;   // bf16 proj_w: 2,359,296 shorts = 1,179,648 f32 (live only during proj)
constexpr long OFF_ZG      = 2820624;   // 2*1,401,856 (ends 5,624,336)
constexpr long OFF_Z       = 5760000;   // 2*700,928 (ends 7,161,856)
constexpr long OFF_WCONVB  = 6000000;   // bf16 conv w^T: 589,824 shorts = 294,912 f32 (live only at conv)
constexpr long OFF_FEATB   = 7161856;   // bf16 features: 12,616,704 shorts = 6,308,352 f32 (live only during proj)
constexpr long OFF_XP      = 7161856;   // 2*746,112
constexpr long OFF_DELTA   = 8654080;   // 2*700,928
constexpr long OFF_Y       = 10055936;  // 2*700,928
constexpr long OFF_GT      = 11457792;  // 2*350,464
constexpr long OFF_SSMOUT  = 12158720;  // 2*350,464
constexpr long OFF_CAT     = 12859648;  // 700,928
constexpr long OFF_MERGED  = 13560576;  // 350,464 -> total 13,911,040
} // namespace

typedef __attribute__((ext_vector_type(8))) short bf16x8;
typedef __attribute__((ext_vector_type(4))) float f32x4;

__device__ __forceinline__ short f2bf(float x) {
    unsigned u = __builtin_bit_cast(unsigned, x);
    unsigned r = u + 0x7fffu + ((u >> 16) & 1u);
    return (short)(r >> 16);
}

// cast 8 consecutive f32 -> bf16x8 per thread
__global__ __launch_bounds__(256)
void cast8_kernel(const float* __restrict__ in, short* __restrict__ out, long n8)
{
    long i = (long)blockIdx.x * 256 + threadIdx.x;
    if (i >= n8) return;
    const float4* p = (const float4*)(in + i * 8);
    float4 x = p[0], y = p[1];
    union { short s[8]; bf16x8 v; } u;
    u.s[0] = f2bf(x.x); u.s[1] = f2bf(x.y); u.s[2] = f2bf(x.z); u.s[3] = f2bf(x.w);
    u.s[4] = f2bf(y.x); u.s[5] = f2bf(y.y); u.s[6] = f2bf(y.z); u.s[7] = f2bf(y.w);
    *(bf16x8*)(out + i * 8) = u.v;
}

// conv weight: (tap*256+cin, cout) f32 -> bf16 transposed [cout][2304]
__global__ __launch_bounds__(256)
void castw_conv_kernel(const float* __restrict__ w, short* __restrict__ wt)
{
    long idx = (long)blockIdx.x * 256 + threadIdx.x; // 589,824 total
    int co = (int)(idx / 2304), k = (int)(idx % 2304);
    wt[idx] = f2bf(w[(long)k * kCO + co]);
}

// ---------------------------------------------------------------------------
// proj MFMA: pf[s][m][n] = sum_k featb[s][m][k] * projwb[s][n][k]
// grid (22, 4, 6); 4 waves, wave tile 32x32 (acc 2x2 frags). Register-only.
// ---------------------------------------------------------------------------
__global__ __launch_bounds__(256)
void proj_mfma_kernel(const short* __restrict__ featb, const short* __restrict__ pwb,
                      float* __restrict__ pf)
{
    const int s = blockIdx.z;
    const short* A = featb + (long)s * kN * kCIN;
    const short* B = pwb   + (long)s * kCO * kCIN;
    float* C = pf + (long)s * kN * kCO;
    const int t = threadIdx.x, w = t >> 6, l = t & 63;
    const int lr = l & 15, lk = (l >> 4) * 8;
    const int m0 = blockIdx.x * 64 + (w >> 1) * 32;
    const int n0 = blockIdx.y * 64 + (w & 1) * 32;
    long arow[2];
    #pragma unroll
    for (int mi = 0; mi < 2; ++mi) {
        int m = m0 + mi * 16 + lr; if (m >= kN) m = kN - 1;
        arow[mi] = (long)m * kCIN;
    }
    f32x4 acc[2][2] = {};
    for (int k0 = 0; k0 < kCIN; k0 += 32) {
        bf16x8 a[2], b[2];
        #pragma unroll
        for (int mi = 0; mi < 2; ++mi)
            a[mi] = *(const bf16x8*)(A + arow[mi] + k0 + lk);
        #pragma unroll
        for (int ni = 0; ni < 2; ++ni)
            b[ni] = *(const bf16x8*)(B + (long)(n0 + ni * 16 + lr) * kCIN + k0 + lk);
        #pragma unroll
        for (int mi = 0; mi < 2; ++mi)
            #pragma unroll
            for (int ni = 0; ni < 2; ++ni)
                acc[mi][ni] = __builtin_amdgcn_mfma_f32_16x16x32_bf16(a[mi], b[ni], acc[mi][ni], 0, 0, 0);
    }
    const int q = l >> 4;
    #pragma unroll
    for (int mi = 0; mi < 2; ++mi)
        #pragma unroll
        for (int ni = 0; ni < 2; ++ni)
            #pragma unroll
            for (int r = 0; r < 4; ++r) {
                int m = m0 + mi * 16 + q * 4 + r;
                if (m < kN)
                    C[(long)m * kCO + n0 + ni * 16 + lr] = acc[mi][ni][r];
            }
}

// ---------------------------------------------------------------------------
// conv3x3 MFMA: out[co][p] = bias[co] + sum_{tap,cin} up[(oy+ky)*150+ox+kx][cin]
//                                              * wt[co][tap*256+cin]
// grid (343, 2); 4 waves, wave tile 32 pixels x 64 couts. Register-only.
// ---------------------------------------------------------------------------
__global__ __launch_bounds__(256)
void conv_mfma_kernel(const short* __restrict__ up, const short* __restrict__ wt,
                      const float* __restrict__ bias, float* __restrict__ out)
{
    const int t = threadIdx.x, w = t >> 6, l = t & 63;
    const int lr = l & 15, lk = (l >> 4) * 8;
    const int m0 = blockIdx.x * 64 + (w >> 1) * 32;
    const int n0 = blockIdx.y * 128 + (w & 1) * 64;
    long abase[2];
    #pragma unroll
    for (int mi = 0; mi < 2; ++mi) {
        int p = m0 + mi * 16 + lr; if (p >= kNP) p = kNP - 1;
        int oy = p / kOW, ox = p - oy * kOW;
        abase[mi] = ((long)oy * 150 + ox) * kCO;
    }
    f32x4 acc[2][4] = {};
    for (int tap = 0; tap < 9; ++tap) {
        const int ky = tap / 3, kx = tap - ky * 3;
        const long toff = ((long)ky * 150 + kx) * kCO;
        const long woff = (long)tap * kCO;
        for (int c0 = 0; c0 < kCO; c0 += 32) {
            bf16x8 a[2], b[4];
            #pragma unroll
            for (int mi = 0; mi < 2; ++mi)
                a[mi] = *(const bf16x8*)(up + abase[mi] + toff + c0 + lk);
            #pragma unroll
            for (int ni = 0; ni < 4; ++ni)
                b[ni] = *(const bf16x8*)(wt + (long)(n0 + ni * 16 + lr) * 2304 + woff + c0 + lk);
            #pragma unroll
            for (int mi = 0; mi < 2; ++mi)
                #pragma unroll
                for (int ni = 0; ni < 4; ++ni)
                    acc[mi][ni] = __builtin_amdgcn_mfma_f32_16x16x32_bf16(a[mi], b[ni], acc[mi][ni], 0, 0, 0);
        }
    }
    const int q = l >> 4;
    #pragma unroll
    for (int mi = 0; mi < 2; ++mi)
        #pragma unroll
        for (int ni = 0; ni < 4; ++ni) {
            const int co = n0 + ni * 16 + lr;
            const float bv = bias[co];
            #pragma unroll
            for (int r = 0; r < 4; ++r) {
                int p = m0 + mi * 16 + q * 4 + r;
                if (p < kNP)
                    out[(long)co * kNP + p] = acc[mi][ni][r] + bv;
            }
        }
}

// ---------------------------------------------------------------------------
// f32 tiled GEMM (NN only now): C[m,n] = sum_k A[m,k]*B[k,n]
// ---------------------------------------------------------------------------
template<int NT>
__global__ __launch_bounds__(256)
void gemm_tile(const float* __restrict__ A, int lda, long sA,
               const float* __restrict__ B0, const float* __restrict__ B1,
               int ldb, long sB,
               float* __restrict__ C, int ldc, long sC,
               int M, int Nn, int K)
{
    __shared__ float As[16][65];
    __shared__ float Bs[16][65];
    const int bz = blockIdx.z;
    const float* Ab = A + (long)bz * sA;
    const float* Bb = (B1 != nullptr && bz == 1) ? B1 : B0 + (long)bz * sB;
    float* Cb = C + (long)bz * sC;
    const int m0 = blockIdx.x * 64, n0 = blockIdx.y * 64;
    const int t = threadIdx.x;
    const int tx = t & 15, ty = t >> 4;
    float acc[4][4] = {};
    for (int k0 = 0; k0 < K; k0 += 16) {
        #pragma unroll
        for (int p = 0; p < 4; ++p) {
            int lm = (t >> 4) + p * 16;
            int gm = m0 + lm; if (gm >= M) gm = M - 1;
            As[t & 15][lm] = Ab[(long)gm * lda + k0 + (t & 15)];
        }
        if (NT) {
            #pragma unroll
            for (int p = 0; p < 4; ++p) {
                int ln = (t >> 4) + p * 16;
                int gn = n0 + ln; if (gn >= Nn) gn = Nn - 1;
                Bs[t & 15][ln] = Bb[(long)gn * ldb + k0 + (t & 15)];
            }
        } else {
            #pragma unroll
            for (int p = 0; p < 4; ++p) {
                int kk = (t >> 6) + p * 4;
                int ln = t & 63;
                int gn = n0 + ln; if (gn >= Nn) gn = Nn - 1;
                Bs[kk][ln] = Bb[(long)(k0 + kk) * ldb + gn];
            }
        }
        __syncthreads();
        #pragma unroll
        for (int k = 0; k < 16; ++k) {
            float a[4], b4[4];
            #pragma unroll
            for (int i = 0; i < 4; ++i) a[i] = As[k][ty * 4 + i];
            #pragma unroll
            for (int j = 0; j < 4; ++j) b4[j] = Bs[k][tx * 4 + j];
            #pragma unroll
            for (int i = 0; i < 4; ++i)
                #pragma unroll
                for (int j = 0; j < 4; ++j) acc[i][j] += a[i] * b4[j];
        }
        __syncthreads();
    }
    #pragma unroll
    for (int i = 0; i < 4; ++i) {
        int gm = m0 + ty * 4 + i;
        if (gm >= M) continue;
        #pragma unroll
        for (int j = 0; j < 4; ++j) {
            int gn = n0 + tx * 4 + j;
            if (gn >= Nn) continue;
            Cb[(long)gm * ldc + gn] = acc[i][j];
        }
    }
}

// partial column sums of pf over n (deterministic two-stage mean)
__global__ __launch_bounds__(256)
void colmean_kernel(const float* __restrict__ pf, float* __restrict__ colpart)
{
    int s = blockIdx.x, ch = blockIdx.y, o = threadIdx.x;
    int n0 = ch * 128, n1 = n0 + 128 > kN ? kN : n0 + 128;
    float a = 0.f;
    for (int n = n0; n < n1; ++n) a += pf[((long)s * kN + n) * kCO + o];
    colpart[ch * kS * kCO + s * kCO + o] = a;
}

// attention MLP + double softmax -> wfin[6]
__global__ __launch_bounds__(384)
void attn_kernel(const float* __restrict__ colpart,
                 const float* __restrict__ w1, const float* __restrict__ b1,
                 const float* __restrict__ w2, const float* __restrict__ b2,
                 const float* __restrict__ ss, float* __restrict__ wfin)
{
    __shared__ float cm[kS * kCO];
    __shared__ float h[kHID];
    __shared__ float logits[8];
    int t = threadIdx.x;
    for (int c = t; c < kS * kCO; c += kHID) {
        float a = 0.f;
        for (int ch = 0; ch < 11; ++ch) a += colpart[ch * kS * kCO + c];
        cm[c] = a * (1.f / kN);
    }
    __syncthreads();
    float acc = b1[t];
    for (int c = 0; c < kS * kCO; ++c) acc += cm[c] * w1[(long)c * kHID + t];
    h[t] = fmaxf(acc, 0.f);
    __syncthreads();
    if (t < kS) {
        float l = b2[t];
        for (int j = 0; j < kHID; ++j) l += h[j] * w2[j * kS + t];
        logits[t] = l;
    }
    __syncthreads();
    if (t == 0) {
        float w[kS], mx = -1e30f, sum = 0.f;
        for (int s = 0; s < kS; ++s) mx = fmaxf(mx, logits[s]);
        for (int s = 0; s < kS; ++s) { w[s] = expf(logits[s] - mx); sum += w[s]; }
        for (int s = 0; s < kS; ++s) w[s] /= sum;
        mx = -1e30f;
        for (int s = 0; s < kS; ++s) { w[s] *= ss[s]; mx = fmaxf(mx, w[s]); }
        sum = 0.f;
        float e[kS];
        for (int s = 0; s < kS; ++s) { e[s] = expf(w[s] - mx); sum += e[s]; }
        for (int s = 0; s < kS; ++s) wfin[s] = e[s] / sum;
    }
}

// fused = sum_s wfin[s]*pf[s]; also writes the n-reversed copy for the bwd SSM
__global__ __launch_bounds__(256)
void fuse_kernel(const float* __restrict__ pf, const float* __restrict__ wfin,
                 float* __restrict__ fused2)
{
    long idx = (long)blockIdx.x * 256 + threadIdx.x;
    if (idx >= (long)kN * kCO) return;
    float acc = 0.f;
    #pragma unroll
    for (int s = 0; s < kS; ++s) acc += wfin[s] * pf[(long)s * kN * kCO + idx];
    fused2[idx] = acc;
    long n = idx / kCO; int c = (int)(idx % kCO);
    fused2[(long)kN * kCO + (kN - 1 - n) * kCO + c] = acc;
}

// causal depthwise conv (K=4) + silu on first half of zg
__global__ __launch_bounds__(256)
void dwconv_kernel(const float* __restrict__ zg2,
                   const float* __restrict__ wf, const float* __restrict__ bf,
                   const float* __restrict__ wb, const float* __restrict__ bb,
                   float* __restrict__ z2)
{
    long idx = (long)blockIdx.x * 256 + threadIdx.x;
    int dir = blockIdx.y;
    if (idx >= (long)kN * kDI) return;
    long n = idx >> 9; int i = (int)(idx & (kDI - 1));
    const float* zg = zg2 + (long)dir * kN * 2 * kDI;
    const float* w  = dir ? wb : wf;
    const float* b  = dir ? bb : bf;
    float acc = b[i];
    #pragma unroll
    for (int k = 0; k < 4; ++k) {
        long m = n - 3 + k;
        if (m >= 0) acc += w[k * kDI + i] * zg[m * 2 * kDI + i];
    }
    float sg = 1.f / (1.f + expf(-acc));
    z2[(long)dir * kN * kDI + idx] = acc * sg;
}

// delta = softplus(xp[:,32+i] + xp[:,544])
__global__ __launch_bounds__(256)
void delta_kernel(const float* __restrict__ xp2, float* __restrict__ delta2)
{
    long idx = (long)blockIdx.x * 256 + threadIdx.x;
    int dir = blockIdx.y;
    if (idx >= (long)kN * kDI) return;
    long n = idx >> 9; int i = (int)(idx & (kDI - 1));
    const float* xp = xp2 + (long)dir * kXPS + n * kXPW;
    float x = xp[2 * kDS + i] + xp[kXPW - 1];
    float sp = fmaxf(x, 0.f) + log1pf(expf(-fabsf(x)));
    delta2[(long)dir * kN * kDI + idx] = sp;
}

// selective scan
__global__ __launch_bounds__(256)
void scan_kernel(const float* __restrict__ delta2, const float* __restrict__ z2,
                 const float* __restrict__ xp2,
                 const float* __restrict__ Df, const float* __restrict__ Db,
                 const float* __restrict__ Alogf, const float* __restrict__ Alogb,
                 float* __restrict__ ybuf2)
{
    int dir = blockIdx.x >> 5;
    int blk = blockIdx.x & 31;
    int t = threadIdx.x;
    int s = t & 15, il = t >> 4;
    int i = blk * 16 + il;
    const float* delta = delta2 + (long)dir * kN * kDI;
    const float* z     = z2     + (long)dir * kN * kDI;
    const float* xp    = xp2    + (long)dir * kXPS;
    const float* D     = dir ? Db : Df;
    const float* Alog  = dir ? Alogb : Alogf;
    float* y           = ybuf2  + (long)dir * kN * kDI;
    float A  = expf(Alog[i * kDS + s]);
    float Dv = D[i];
    float h = 0.f;
    for (int n = 0; n < kN; ++n) {
        float dlt = delta[(long)n * kDI + i];
        float zv  = z[(long)n * kDI + i];
        float Bv  = xp[(long)n * kXPW + s];
        float Cv  = xp[(long)n * kXPW + kDS + s];
        float dA  = __expf(-dlt * A);
        h = dA * h + dlt * Bv * zv;
        float c = h * Cv;
        c += __shfl_xor(c, 1, 16);
        c += __shfl_xor(c, 2, 16);
        c += __shfl_xor(c, 4, 16);
        c += __shfl_xor(c, 8, 16);
        if (s == 0) y[(long)n * kDI + i] = c + Dv * zv;
    }
}

// y *= silu(gate)
__global__ __launch_bounds__(256)
void mulgate_kernel(const float* __restrict__ zg2, float* __restrict__ ybuf2)
{
    long idx = (long)blockIdx.x * 256 + threadIdx.x;
    int dir = blockIdx.y;
    if (idx >= (long)kN * kDI) return;
    long n = idx >> 9; int i = (int)(idx & (kDI - 1));
    float g = zg2[(long)dir * kN * 2 * kDI + n * 2 * kDI + kDI + i];
    float sg = 1.f / (1.f + expf(-g));
    ybuf2[(long)dir * kN * kDI + idx] *= g * sg;
}

// r = gemm_out + x ; layernorm over CO=256
__global__ __launch_bounds__(256)
void resid_ln_kernel(const float* __restrict__ gt2, const float* __restrict__ x2,
                     const float* __restrict__ gf, const float* __restrict__ betf,
                     const float* __restrict__ gb, const float* __restrict__ betb,
                     float* __restrict__ out2)
{
    int n = blockIdx.x, dir = blockIdx.y, t = threadIdx.x;
    const float* gt = gt2 + ((long)dir * kN + n) * kCO;
    const float* x  = x2  + ((long)dir * kN + n) * kCO;
    const float* g  = dir ? gb : gf;
    const float* be = dir ? betb : betf;
    float r = gt[t] + x[t];
    float s1 = r, s2 = r * r;
    #pragma unroll
    for (int m = 32; m >= 1; m >>= 1) {
        s1 += __shfl_xor(s1, m, 64);
        s2 += __shfl_xor(s2, m, 64);
    }
    __shared__ float red[8];
    int w = t >> 6;
    if ((t & 63) == 0) { red[w] = s1; red[4 + w] = s2; }
    __syncthreads();
    float S1 = red[0] + red[1] + red[2] + red[3];
    float S2 = red[4] + red[5] + red[6] + red[7];
    float mu  = S1 * (1.f / kCO);
    float var = S2 * (1.f / kCO) - mu * mu;
    float inv = rsqrtf(var + 1e-5f);
    out2[((long)dir * kN + n) * kCO + t] = g[t] * (r - mu) * inv + be[t];
}

// cat fwd / reversed-bwd
__global__ __launch_bounds__(256)
void cat_kernel(const float* __restrict__ sout2, float* __restrict__ cat)
{
    long idx = (long)blockIdx.x * 256 + threadIdx.x;
    if (idx >= (long)kN * 2 * kCO) return;
    long n = idx / (2 * kCO); int c = (int)(idx % (2 * kCO));
    float v;
    if (c < kCO) v = sout2[n * kCO + c];
    else         v = sout2[(long)kN * kCO + (kN - 1 - n) * kCO + (c - kCO)];
    cat[idx] = v;
}

// bilinear 4x upsample -> bf16 into zero-padded (150,150,256) buffer interior
__global__ __launch_bounds__(256)
void upsample_kernel(const float* __restrict__ merged, short* __restrict__ up)
{
    int p = blockIdx.x;
    int oy = p / kOW, ox = p - oy * kOW;
    int c = threadIdx.x;
    float sy = (oy + 0.5f) * ((float)kHP / (float)kOH) - 0.5f;
    float sx = (ox + 0.5f) * ((float)kWP / (float)kOW) - 0.5f;
    int iy0 = (int)floorf(sy); float fy = sy - (float)iy0;
    int ix0 = (int)floorf(sx); float fx = sx - (float)ix0;
    float wy0 = 1.f - fy, wy1 = fy, wx0 = 1.f - fx, wx1 = fx;
    int iy1 = iy0 + 1, ix1 = ix0 + 1;
    if (iy0 < 0)       { iy0 = 0;       wy0 = 0.f; }
    if (iy1 > kHP - 1) { iy1 = kHP - 1; wy1 = 0.f; }
    if (ix0 < 0)       { ix0 = 0;       wx0 = 0.f; }
    if (ix1 > kWP - 1) { ix1 = kWP - 1; wx1 = 0.f; }
    float wys = wy0 + wy1; wy0 /= wys; wy1 /= wys;
    float wxs = wx0 + wx1; wx0 /= wxs; wx1 /= wxs;
    const float* M00 = merged + (long)(iy0 * kWP + ix0) * kCO;
    const float* M01 = merged + (long)(iy0 * kWP + ix1) * kCO;
    const float* M10 = merged + (long)(iy1 * kWP + ix0) * kCO;
    const float* M11 = merged + (long)(iy1 * kWP + ix1) * kCO;
    float v = wy0 * (wx0 * M00[c] + wx1 * M01[c]) + wy1 * (wx0 * M10[c] + wx1 * M11[c]);
    up[((long)(oy + 1) * 150 + (ox + 1)) * kCO + c] = f2bf(v);
}

extern "C" void kernel_launch(void* const* d_in, const int* in_sizes, int n_in,
                              void* d_out, int out_size, void* d_ws, size_t ws_size,
                              hipStream_t stream)
{
    (void)in_sizes; (void)n_in; (void)out_size; (void)ws_size;
    const float* features  = (const float*)d_in[0];
    const float* proj_w    = (const float*)d_in[1];
    const float* attn_w1   = (const float*)d_in[2];
    const float* attn_b1   = (const float*)d_in[3];
    const float* attn_w2   = (const float*)d_in[4];
    const float* attn_b2   = (const float*)d_in[5];
    const float* src_scale = (const float*)d_in[6];
    const float* f_in_w    = (const float*)d_in[7];
    const float* f_conv_w  = (const float*)d_in[8];
    const float* f_conv_b  = (const float*)d_in[9];
    const float* f_xp_w    = (const float*)d_in[10];
    const float* f_Alog    = (const float*)d_in[11];
    const float* f_D       = (const float*)d_in[12];
    const float* f_out_w   = (const float*)d_in[13];
    const float* f_ln_g    = (const float*)d_in[14];
    const float* f_ln_b    = (const float*)d_in[15];
    const float* b_in_w    = (const float*)d_in[16];
    const float* b_conv_w  = (const float*)d_in[17];
    const float* b_conv_b  = (const float*)d_in[18];
    const float* b_xp_w    = (const float*)d_in[19];
    const float* b_Alog    = (const float*)d_in[20];
    const float* b_D       = (const float*)d_in[21];
    const float* b_out_w   = (const float*)d_in[22];
    const float* b_ln_g    = (const float*)d_in[23];
    const float* b_ln_b    = (const float*)d_in[24];
    const float* merge_w   = (const float*)d_in[25];
    const float* co1_w     = (const float*)d_in[26];
    const float* co1_b     = (const float*)d_in[27];

    float* ws      = (float*)d_ws;
    float* outp    = (float*)d_out;
    float* pf      = ws + OFF_PF;
    float* colpart = ws + OFF_COLPART;
    float* wfin    = ws + OFF_WFIN;
    float* fused2  = ws + OFF_FUSED;
    float* zg2     = ws + OFF_ZG;
    float* z2      = ws + OFF_Z;
    float* xp2     = ws + OFF_XP;
    float* delta2  = ws + OFF_DELTA;
    float* ybuf2   = ws + OFF_Y;
    float* gt2     = ws + OFF_GT;
    float* sout2   = ws + OFF_SSMOUT;
    float* catb    = ws + OFF_CAT;
    float* merged  = ws + OFF_MERGED;
    short* featb   = (short*)(ws + OFF_FEATB);
    short* projwb  = (short*)(ws + OFF_PROJWB);
    short* upb     = (short*)(ws + OFF_UPB);
    short* wconvb  = (short*)(ws + OFF_WCONVB);

    // 0. bf16 casts for proj
    cast8_kernel<<<dim3((6 * 1369 * 1536 / 8 + 255) / 256), 256, 0, stream>>>(
        features, featb, (long)6 * 1369 * 1536 / 8);
    cast8_kernel<<<dim3((6 * 256 * 1536 / 8 + 255) / 256), 256, 0, stream>>>(
        proj_w, projwb, (long)6 * 256 * 1536 / 8);
    // 1. pf[s] = feats[s] @ proj_w[s]^T   (bf16 MFMA)
    proj_mfma_kernel<<<dim3(22, 4, 6), 256, 0, stream>>>(featb, projwb, pf);
    // 2. deterministic column partial sums
    colmean_kernel<<<dim3(6, 11), 256, 0, stream>>>(pf, colpart);
    // 3. attention weights
    attn_kernel<<<1, 384, 0, stream>>>(colpart, attn_w1, attn_b1, attn_w2, attn_b2,
                                       src_scale, wfin);
    // 4. fuse sources + reversed copy
    fuse_kernel<<<dim3(1369), 256, 0, stream>>>(pf, wfin, fused2);
    // 5. zg = x @ in_w   (NN, batch 2)
    gemm_tile<0><<<dim3(22, 16, 2), 256, 0, stream>>>(
        fused2, kCO, (long)kN * kCO,
        f_in_w, b_in_w, 2 * kDI, 0,
        zg2, 2 * kDI, (long)kN * 2 * kDI, kN, 2 * kDI, kCO);
    // 6. causal dwconv + silu
    dwconv_kernel<<<dim3(2738, 2), 256, 0, stream>>>(zg2, f_conv_w, f_conv_b,
                                                     b_conv_w, b_conv_b, z2);
    // 7. xp = z @ xp_w   (NN, batch 2)
    gemm_tile<0><<<dim3(22, 9, 2), 256, 0, stream>>>(
        z2, kDI, (long)kN * kDI,
        f_xp_w, b_xp_w, kXPW, 0,
        xp2, kXPW, kXPS, kN, kXPW, kDI);
    // 8. delta = softplus(...)
    delta_kernel<<<dim3(2738, 2), 256, 0, stream>>>(xp2, delta2);
    // 9. selective scan
    scan_kernel<<<dim3(64), 256, 0, stream>>>(delta2, z2, xp2, f_D, b_D,
                                              f_Alog, b_Alog, ybuf2);
    // 10. y *= silu(gate)
    mulgate_kernel<<<dim3(2738, 2), 256, 0, stream>>>(zg2, ybuf2);
    // 11. out = y2 @ out_w   (NN, batch 2)
    gemm_tile<0><<<dim3(22, 4, 2), 256, 0, stream>>>(
        ybuf2, kDI, (long)kN * kDI,
        f_out_w, b_out_w, kCO, 0,
        gt2, kCO, (long)kN * kCO, kN, kCO, kDI);
    // 12. residual + layernorm
    resid_ln_kernel<<<dim3(1369, 2), 256, 0, stream>>>(gt2, fused2, f_ln_g, f_ln_b,
                                                       b_ln_g, b_ln_b, sout2);
    // 13. concat fwd / reversed-bwd
    cat_kernel<<<dim3(2738), 256, 0, stream>>>(sout2, catb);
    // 14. merged = cat @ merge_w   (NN)
    gemm_tile<0><<<dim3(22, 4, 1), 256, 0, stream>>>(
        catb, 2 * kCO, 0,
        merge_w, nullptr, kCO, 0,
        merged, kCO, 0, kN, kCO, 2 * kCO);
    // 15. conv weight -> bf16 transposed [cout][2304] (z2 region now dead)
    castw_conv_kernel<<<dim3(2304), 256, 0, stream>>>(co1_w, wconvb);
    // 16. zero the padded bf16 upsample buffer (aliases dead early-stage ws)
    hipMemsetAsync(upb, 0, (size_t)150 * 150 * 256 * sizeof(short), stream);
    // 17. bilinear upsample -> bf16 padded interior
    upsample_kernel<<<dim3(kOH * kOW), 256, 0, stream>>>(merged, upb);
    // 18. 3x3 conv via bf16 MFMA, NCHW output + bias
    conv_mfma_kernel<<<dim3(343, 2), 256, 0, stream>>>(upb, wconvb, co1_b, outp);
}

// Round 3
// 494.344 us; speedup vs baseline: 3.5767x; 2.3426x over previous
//
#include <hip/hip_runtime.h>
#include <math.h>

// ---------------------------------------------------------------------------
// Upnet_v3 pipeline, round 2:
//  - selective scan -> 3-pass chunk-parallel scan (24 chunks, 1536 blocks)
//  - all remaining dense GEMMs (in-proj, xp, out, merge) -> bf16 MFMA with
//    pre-transposed bf16 weights; producers emit bf16 activation copies
//  - resid_ln + cat fused, cat output bf16
// ---------------------------------------------------------------------------

namespace {
constexpr int kS   = 6;
constexpr int kHP  = 37;
constexpr int kWP  = 37;
constexpr int kN   = 1369;      // HP*WP
constexpr int kCIN = 1536;
constexpr int kCO  = 256;
constexpr int kDS  = 16;
constexpr int kDI  = 512;
constexpr int kHID = 384;
constexpr int kOH  = 148;
constexpr int kOW  = 148;
constexpr int kNP  = kOH * kOW; // 21904
constexpr int kXPW = 545;       // 2*DS + DI + 1
constexpr long kXPS = 746112;   // padded kN*kXPW per dir
constexpr int kNC  = 24;        // scan chunks
constexpr int kCH  = 58;        // chunk length (24*58 = 1392 >= 1369)

// ---- workspace ledger (f32 units, total <= 13,911,040 = 55.6 MB) ----------
// region [0 .. 2,102,784) = pf during steps 1-4, then reused:
constexpr long OFF_PF      = 0;         // pf: 6*1369*256 = 2,102,784 (dead after fuse)
constexpr long OFF_Z2B     = 0;         // z2b bf16 2*1369*512 sh = 700,928 f32 (steps 6-9)
constexpr long OFF_YGB     = 0;         // ygb bf16 same size (steps 12-13, after z2b dead)
constexpr long OFF_SCANP   = 700928;    // chunkP 16384*24 = 393,216
constexpr long OFF_SCANH   = 1094144;   // chunkH 393,216
constexpr long OFF_HIN     = 1487360;   // hin    393,216 (ends 1,880,576)
constexpr long OFF_OUTWT   = 1880576;   // out_wt bf16 2*256*512 sh = 131,072 f32 (ends 2,011,648)
// region [2,102,784 ..):
constexpr long OFF_COLPART = 2102784;   // 16,896
constexpr long OFF_WFIN    = 2119680;   // 16
constexpr long OFF_FUSED   = 2119696;   // f32 fused+rev: 700,928 (ends 2,820,624)... see note
// projwb region [2,200,000 .. 3,379,648) lives only during proj; reused:
constexpr long OFF_PROJWB  = 2200000;   // bf16 proj_w 2,359,296 sh = 1,179,648 f32
constexpr long OFF_INWT    = 2200000;   // in_wt bf16 2*1024*256 sh = 262,144 f32 (after proj)
constexpr long OFF_FUSEDB  = 2462144;   // fusedb bf16 2*1369*256 sh = 350,464 f32 (ends 2,812,608)
constexpr long OFF_ZG      = 2820624;   // zg2 f32 2*1,401,856 (ends 5,624,336)
constexpr long OFF_Z       = 5760000;   // z2 f32 2*700,928 (ends 7,161,856)
constexpr long OFF_WCONVB  = 6000000;   // conv w^T bf16 589,824 sh = 294,912 f32 (step 16+, z2 dead)
constexpr long OFF_FEATB   = 7161856;   // featb bf16 12,616,704 sh = 6,308,352 f32 (steps 0-1 only)
constexpr long OFF_XP      = 7161856;   // xp2 f32 2*746,112 (after featb dead)
constexpr long OFF_DELTA   = 8654080;   // delta2 f32 2*700,928
constexpr long OFF_Y       = 10055936;  // ybuf2 f32 2*700,928
constexpr long OFF_GT      = 11457792;  // gt2 f32 2*350,464 (ends 12,158,720)
constexpr long OFF_XPWT    = 11457792;  // xp_wt bf16 2*545*512 sh = 279,040 f32 (dead before gt2)
constexpr long OFF_CAT     = 12859648;  // catb bf16 1369*512 sh = 350,464 f32 (ends 13,210,112)
constexpr long OFF_MERGEWT = 13210112;  // merge_wt bf16 256*512 sh = 65,536 f32 (ends 13,275,648)
constexpr long OFF_MERGED  = 13560576;  // merged f32 350,464 (ends 13,911,040)
constexpr long OFF_UPB     = 0;         // up_pad bf16 5,760,000 sh = 2,880,000 f32 (steps 16+)
// NOTE: OFF_FUSED..(+700,928) = [2,119,696..2,820,624) overlaps OFF_INWT/OFF_FUSEDB
// declared above?  No: fused2 f32 lives at 2,119,696..2,820,624 -- that DOES
// overlap in_wt (2,200,000..2,462,144). Fix: move fused2 f32 to the sout2
// region which is now free: [12,158,720..12,859,648) = 700,928 exactly.
constexpr long OFF_FUSED2  = 12158720;  // f32 fused + reversed: 700,928 (ends 12,859,648)
} // namespace

typedef __attribute__((ext_vector_type(8))) short bf16x8;
typedef __attribute__((ext_vector_type(4))) float f32x4;

__device__ __forceinline__ short f2bf(float x) {
    unsigned u = __builtin_bit_cast(unsigned, x);
    unsigned r = u + 0x7fffu + ((u >> 16) & 1u);
    return (short)(r >> 16);
}

// cast 8 consecutive f32 -> bf16x8 per thread
__global__ __launch_bounds__(256)
void cast8_kernel(const float* __restrict__ in, short* __restrict__ out, long n8)
{
    long i = (long)blockIdx.x * 256 + threadIdx.x;
    if (i >= n8) return;
    const float4* p = (const float4*)(in + i * 8);
    float4 x = p[0], y = p[1];
    union { short s[8]; bf16x8 v; } u;
    u.s[0] = f2bf(x.x); u.s[1] = f2bf(x.y); u.s[2] = f2bf(x.z); u.s[3] = f2bf(x.w);
    u.s[4] = f2bf(y.x); u.s[5] = f2bf(y.y); u.s[6] = f2bf(y.z); u.s[7] = f2bf(y.w);
    *(bf16x8*)(out + i * 8) = u.v;
}

// tiled transpose+cast: w (K x N f32, row-major) -> wt (N x K bf16, row-major)
__global__ __launch_bounds__(256)
void transpose_cast_kernel(const float* __restrict__ w0, const float* __restrict__ w1,
                           short* __restrict__ wt, int K, int N)
{
    __shared__ float tile[32][33];
    int dir = blockIdx.z;
    const float* w = dir ? w1 : w0;
    short* o = wt + (long)dir * K * N;
    int k0 = blockIdx.x * 32, n0 = blockIdx.y * 32;
    int tx = threadIdx.x & 31, ty = threadIdx.x >> 5; // 32 x 8
    #pragma unroll
    for (int r = 0; r < 32; r += 8) {
        int k = k0 + ty + r, n = n0 + tx;
        tile[ty + r][tx] = (k < K && n < N) ? w[(long)k * N + n] : 0.f;
    }
    __syncthreads();
    #pragma unroll
    for (int r = 0; r < 32; r += 8) {
        int n = n0 + ty + r, k = k0 + tx;
        if (n < N && k < K) o[(long)n * K + k] = f2bf(tile[tx][ty + r]);
    }
}

// conv weight: (tap*256+cin, cout) f32 -> bf16 transposed [cout][2304]
__global__ __launch_bounds__(256)
void castw_conv_kernel(const float* __restrict__ w, short* __restrict__ wt)
{
    long idx = (long)blockIdx.x * 256 + threadIdx.x; // 589,824 total
    int co = (int)(idx / 2304), k = (int)(idx % 2304);
    wt[idx] = f2bf(w[(long)k * kCO + co]);
}

// ---------------------------------------------------------------------------
// generic register-only bf16 MFMA GEMM, NT form:
// C[m,n] = sum_k A[m*K+k] * B[n*K+k]; block 64x64 (4 waves, wave 32x32)
// ---------------------------------------------------------------------------
__global__ __launch_bounds__(256)
void mfma_nt(const short* __restrict__ A, long sA,
             const short* __restrict__ B, long sB,
             float* __restrict__ C, long sC,
             int M, int N, int K)
{
    const int bz = blockIdx.z;
    const short* Ab = A + (long)bz * sA;
    const short* Bb = B + (long)bz * sB;
    float* Cb = C + (long)bz * sC;
    const int t = threadIdx.x, w = t >> 6, l = t & 63;
    const int lr = l & 15, lk = (l >> 4) * 8;
    const int m0 = blockIdx.x * 64 + (w >> 1) * 32;
    const int n0 = blockIdx.y * 64 + (w & 1) * 32;
    long arow[2], brow[2];
    #pragma unroll
    for (int mi = 0; mi < 2; ++mi) {
        int m = m0 + mi * 16 + lr; if (m >= M) m = M - 1;
        arow[mi] = (long)m * K;
    }
    #pragma unroll
    for (int ni = 0; ni < 2; ++ni) {
        int n = n0 + ni * 16 + lr; if (n >= N) n = N - 1;
        brow[ni] = (long)n * K;
    }
    f32x4 acc[2][2] = {};
    for (int k0 = 0; k0 < K; k0 += 32) {
        bf16x8 a[2], b[2];
        #pragma unroll
        for (int mi = 0; mi < 2; ++mi)
            a[mi] = *(const bf16x8*)(Ab + arow[mi] + k0 + lk);
        #pragma unroll
        for (int ni = 0; ni < 2; ++ni)
            b[ni] = *(const bf16x8*)(Bb + brow[ni] + k0 + lk);
        #pragma unroll
        for (int mi = 0; mi < 2; ++mi)
            #pragma unroll
            for (int ni = 0; ni < 2; ++ni)
                acc[mi][ni] = __builtin_amdgcn_mfma_f32_16x16x32_bf16(a[mi], b[ni], acc[mi][ni], 0, 0, 0);
    }
    const int q = l >> 4;
    #pragma unroll
    for (int mi = 0; mi < 2; ++mi)
        #pragma unroll
        for (int ni = 0; ni < 2; ++ni)
            #pragma unroll
            for (int r = 0; r < 4; ++r) {
                int m = m0 + mi * 16 + q * 4 + r;
                int n = n0 + ni * 16 + lr;
                if (m < M && n < N)
                    Cb[(long)m * N + n] = acc[mi][ni][r];
            }
}

// ---------------------------------------------------------------------------
// proj MFMA: pf[s][m][n] = sum_k featb[s][m][k] * projwb[s][n][k]
// ---------------------------------------------------------------------------
__global__ __launch_bounds__(256)
void proj_mfma_kernel(const short* __restrict__ featb, const short* __restrict__ pwb,
                      float* __restrict__ pf)
{
    const int s = blockIdx.z;
    const short* A = featb + (long)s * kN * kCIN;
    const short* B = pwb   + (long)s * kCO * kCIN;
    float* C = pf + (long)s * kN * kCO;
    const int t = threadIdx.x, w = t >> 6, l = t & 63;
    const int lr = l & 15, lk = (l >> 4) * 8;
    const int m0 = blockIdx.x * 64 + (w >> 1) * 32;
    const int n0 = blockIdx.y * 64 + (w & 1) * 32;
    long arow[2];
    #pragma unroll
    for (int mi = 0; mi < 2; ++mi) {
        int m = m0 + mi * 16 + lr; if (m >= kN) m = kN - 1;
        arow[mi] = (long)m * kCIN;
    }
    f32x4 acc[2][2] = {};
    for (int k0 = 0; k0 < kCIN; k0 += 32) {
        bf16x8 a[2], b[2];
        #pragma unroll
        for (int mi = 0; mi < 2; ++mi)
            a[mi] = *(const bf16x8*)(A + arow[mi] + k0 + lk);
        #pragma unroll
        for (int ni = 0; ni < 2; ++ni)
            b[ni] = *(const bf16x8*)(B + (long)(n0 + ni * 16 + lr) * kCIN + k0 + lk);
        #pragma unroll
        for (int mi = 0; mi < 2; ++mi)
            #pragma unroll
            for (int ni = 0; ni < 2; ++ni)
                acc[mi][ni] = __builtin_amdgcn_mfma_f32_16x16x32_bf16(a[mi], b[ni], acc[mi][ni], 0, 0, 0);
    }
    const int q = l >> 4;
    #pragma unroll
    for (int mi = 0; mi < 2; ++mi)
        #pragma unroll
        for (int ni = 0; ni < 2; ++ni)
            #pragma unroll
            for (int r = 0; r < 4; ++r) {
                int m = m0 + mi * 16 + q * 4 + r;
                if (m < kN)
                    C[(long)m * kCO + n0 + ni * 16 + lr] = acc[mi][ni][r];
            }
}

// ---------------------------------------------------------------------------
// conv3x3 MFMA (unchanged from round 1)
// ---------------------------------------------------------------------------
__global__ __launch_bounds__(256)
void conv_mfma_kernel(const short* __restrict__ up, const short* __restrict__ wt,
                      const float* __restrict__ bias, float* __restrict__ out)
{
    const int t = threadIdx.x, w = t >> 6, l = t & 63;
    const int lr = l & 15, lk = (l >> 4) * 8;
    const int m0 = blockIdx.x * 64 + (w >> 1) * 32;
    const int n0 = blockIdx.y * 128 + (w & 1) * 64;
    long abase[2];
    #pragma unroll
    for (int mi = 0; mi < 2; ++mi) {
        int p = m0 + mi * 16 + lr; if (p >= kNP) p = kNP - 1;
        int oy = p / kOW, ox = p - oy * kOW;
        abase[mi] = ((long)oy * 150 + ox) * kCO;
    }
    f32x4 acc[2][4] = {};
    for (int tap = 0; tap < 9; ++tap) {
        const int ky = tap / 3, kx = tap - ky * 3;
        const long toff = ((long)ky * 150 + kx) * kCO;
        const long woff = (long)tap * kCO;
        for (int c0 = 0; c0 < kCO; c0 += 32) {
            bf16x8 a[2], b[4];
            #pragma unroll
            for (int mi = 0; mi < 2; ++mi)
                a[mi] = *(const bf16x8*)(up + abase[mi] + toff + c0 + lk);
            #pragma unroll
            for (int ni = 0; ni < 4; ++ni)
                b[ni] = *(const bf16x8*)(wt + (long)(n0 + ni * 16 + lr) * 2304 + woff + c0 + lk);
            #pragma unroll
            for (int mi = 0; mi < 2; ++mi)
                #pragma unroll
                for (int ni = 0; ni < 4; ++ni)
                    acc[mi][ni] = __builtin_amdgcn_mfma_f32_16x16x32_bf16(a[mi], b[ni], acc[mi][ni], 0, 0, 0);
        }
    }
    const int q = l >> 4;
    #pragma unroll
    for (int mi = 0; mi < 2; ++mi)
        #pragma unroll
        for (int ni = 0; ni < 4; ++ni) {
            const int co = n0 + ni * 16 + lr;
            const float bv = bias[co];
            #pragma unroll
            for (int r = 0; r < 4; ++r) {
                int p = m0 + mi * 16 + q * 4 + r;
                if (p < kNP)
                    out[(long)co * kNP + p] = acc[mi][ni][r] + bv;
            }
        }
}

// partial column sums of pf over n
__global__ __launch_bounds__(256)
void colmean_kernel(const float* __restrict__ pf, float* __restrict__ colpart)
{
    int s = blockIdx.x, ch = blockIdx.y, o = threadIdx.x;
    int n0 = ch * 128, n1 = n0 + 128 > kN ? kN : n0 + 128;
    float a = 0.f;
    for (int n = n0; n < n1; ++n) a += pf[((long)s * kN + n) * kCO + o];
    colpart[ch * kS * kCO + s * kCO + o] = a;
}

// attention MLP + double softmax -> wfin[6]
__global__ __launch_bounds__(384)
void attn_kernel(const float* __restrict__ colpart,
                 const float* __restrict__ w1, const float* __restrict__ b1,
                 const float* __restrict__ w2, const float* __restrict__ b2,
                 const float* __restrict__ ss, float* __restrict__ wfin)
{
    __shared__ float cm[kS * kCO];
    __shared__ float h[kHID];
    __shared__ float logits[8];
    int t = threadIdx.x;
    for (int c = t; c < kS * kCO; c += kHID) {
        float a = 0.f;
        for (int ch = 0; ch < 11; ++ch) a += colpart[ch * kS * kCO + c];
        cm[c] = a * (1.f / kN);
    }
    __syncthreads();
    float acc = b1[t];
    for (int c = 0; c < kS * kCO; ++c) acc += cm[c] * w1[(long)c * kHID + t];
    h[t] = fmaxf(acc, 0.f);
    __syncthreads();
    if (t < kS) {
        float l = b2[t];
        for (int j = 0; j < kHID; ++j) l += h[j] * w2[j * kS + t];
        logits[t] = l;
    }
    __syncthreads();
    if (t == 0) {
        float w[kS], mx = -1e30f, sum = 0.f;
        for (int s = 0; s < kS; ++s) mx = fmaxf(mx, logits[s]);
        for (int s = 0; s < kS; ++s) { w[s] = expf(logits[s] - mx); sum += w[s]; }
        for (int s = 0; s < kS; ++s) w[s] /= sum;
        mx = -1e30f;
        for (int s = 0; s < kS; ++s) { w[s] *= ss[s]; mx = fmaxf(mx, w[s]); }
        sum = 0.f;
        float e[kS];
        for (int s = 0; s < kS; ++s) { e[s] = expf(w[s] - mx); sum += e[s]; }
        for (int s = 0; s < kS; ++s) wfin[s] = e[s] / sum;
    }
}

// fused = sum_s wfin[s]*pf[s]; writes f32 fwd+rev and bf16 fwd+rev
__global__ __launch_bounds__(256)
void fuse_kernel(const float* __restrict__ pf, const float* __restrict__ wfin,
                 float* __restrict__ fused2, short* __restrict__ fusedb2)
{
    long idx = (long)blockIdx.x * 256 + threadIdx.x;
    if (idx >= (long)kN * kCO) return;
    float acc = 0.f;
    #pragma unroll
    for (int s = 0; s < kS; ++s) acc += wfin[s] * pf[(long)s * kN * kCO + idx];
    long n = idx / kCO; int c = (int)(idx % kCO);
    long ridx = (long)kN * kCO + (kN - 1 - n) * kCO + c;
    short bv = f2bf(acc);
    fused2[idx] = acc;
    fused2[ridx] = acc;
    fusedb2[idx] = bv;
    fusedb2[ridx] = bv;
}

// causal depthwise conv (K=4) + silu; writes f32 z2 and bf16 z2b
__global__ __launch_bounds__(256)
void dwconv_kernel(const float* __restrict__ zg2,
                   const float* __restrict__ wf, const float* __restrict__ bf,
                   const float* __restrict__ wb, const float* __restrict__ bb,
                   float* __restrict__ z2, short* __restrict__ z2b)
{
    long idx = (long)blockIdx.x * 256 + threadIdx.x;
    int dir = blockIdx.y;
    if (idx >= (long)kN * kDI) return;
    long n = idx >> 9; int i = (int)(idx & (kDI - 1));
    const float* zg = zg2 + (long)dir * kN * 2 * kDI;
    const float* w  = dir ? wb : wf;
    const float* b  = dir ? bb : bf;
    float acc = b[i];
    #pragma unroll
    for (int k = 0; k < 4; ++k) {
        long m = n - 3 + k;
        if (m >= 0) acc += w[k * kDI + i] * zg[m * 2 * kDI + i];
    }
    float sg = 1.f / (1.f + expf(-acc));
    float v = acc * sg;
    z2 [(long)dir * kN * kDI + idx] = v;
    z2b[(long)dir * kN * kDI + idx] = f2bf(v);
}

// delta = softplus(xp[:,32+i] + xp[:,544])
__global__ __launch_bounds__(256)
void delta_kernel(const float* __restrict__ xp2, float* __restrict__ delta2)
{
    long idx = (long)blockIdx.x * 256 + threadIdx.x;
    int dir = blockIdx.y;
    if (idx >= (long)kN * kDI) return;
    long n = idx >> 9; int i = (int)(idx & (kDI - 1));
    const float* xp = xp2 + (long)dir * kXPS + n * kXPW;
    float x = xp[2 * kDS + i] + xp[kXPW - 1];
    float sp = fmaxf(x, 0.f) + log1pf(expf(-fabsf(x)));
    delta2[(long)dir * kN * kDI + idx] = sp;
}

// ---- chunk-parallel scan: pass A (local scan, h_in = 0) -------------------
__global__ __launch_bounds__(256)
void scan_partA(const float* __restrict__ delta2, const float* __restrict__ z2,
                const float* __restrict__ xp2,
                const float* __restrict__ Alogf, const float* __restrict__ Alogb,
                float* __restrict__ chunkP, float* __restrict__ chunkH)
{
    int bx = blockIdx.x;            // dir*32 + iblk
    int c  = blockIdx.y;            // chunk
    int dir = bx >> 5, iblk = bx & 31;
    int t = threadIdx.x;
    int s = t & 15, il = t >> 4;
    int i = iblk * 16 + il;
    int gid = dir * 8192 + iblk * 256 + t;
    const float* delta = delta2 + (long)dir * kN * kDI;
    const float* z     = z2     + (long)dir * kN * kDI;
    const float* xp    = xp2    + (long)dir * kXPS;
    const float* Alog  = dir ? Alogb : Alogf;
    float A = expf(Alog[i * kDS + s]);
    int n0 = c * kCH, n1 = n0 + kCH; if (n1 > kN) n1 = kN;
    float h = 0.f, P = 1.f;
    for (int n = n0; n < n1; ++n) {
        float dlt = delta[(long)n * kDI + i];
        float zv  = z[(long)n * kDI + i];
        float Bv  = xp[(long)n * kXPW + s];
        float dA  = __expf(-dlt * A);
        h = dA * h + dlt * Bv * zv;
        P *= dA;
    }
    chunkP[(long)c * 16384 + gid] = P;
    chunkH[(long)c * 16384 + gid] = h;
}

// ---- pass B: serial combine over chunks -> h_in per chunk -----------------
__global__ __launch_bounds__(256)
void scan_partB(const float* __restrict__ chunkP, const float* __restrict__ chunkH,
                float* __restrict__ hin)
{
    int gid = blockIdx.x * 256 + threadIdx.x; // 16384 threads
    float H = 0.f;
    for (int c = 0; c < kNC; ++c) {
        hin[(long)c * 16384 + gid] = H;
        H = chunkP[(long)c * 16384 + gid] * H + chunkH[(long)c * 16384 + gid];
    }
}

// ---- pass C: re-scan with true h_in, emit y -------------------------------
__global__ __launch_bounds__(256)
void scan_partC(const float* __restrict__ delta2, const float* __restrict__ z2,
                const float* __restrict__ xp2,
                const float* __restrict__ Df, const float* __restrict__ Db,
                const float* __restrict__ Alogf, const float* __restrict__ Alogb,
                const float* __restrict__ hin, float* __restrict__ ybuf2)
{
    int bx = blockIdx.x;
    int c  = blockIdx.y;
    int dir = bx >> 5, iblk = bx & 31;
    int t = threadIdx.x;
    int s = t & 15, il = t >> 4;
    int i = iblk * 16 + il;
    int gid = dir * 8192 + iblk * 256 + t;
    const float* delta = delta2 + (long)dir * kN * kDI;
    const float* z     = z2     + (long)dir * kN * kDI;
    const float* xp    = xp2    + (long)dir * kXPS;
    const float* D     = dir ? Db : Df;
    const float* Alog  = dir ? Alogb : Alogf;
    float* y           = ybuf2  + (long)dir * kN * kDI;
    float A  = expf(Alog[i * kDS + s]);
    float Dv = D[i];
    int n0 = c * kCH, n1 = n0 + kCH; if (n1 > kN) n1 = kN;
    float h = hin[(long)c * 16384 + gid];
    for (int n = n0; n < n1; ++n) {
        float dlt = delta[(long)n * kDI + i];
        float zv  = z[(long)n * kDI + i];
        float Bv  = xp[(long)n * kXPW + s];
        float Cv  = xp[(long)n * kXPW + kDS + s];
        float dA  = __expf(-dlt * A);
        h = dA * h + dlt * Bv * zv;
        float cc = h * Cv;
        cc += __shfl_xor(cc, 1, 16);
        cc += __shfl_xor(cc, 2, 16);
        cc += __shfl_xor(cc, 4, 16);
        cc += __shfl_xor(cc, 8, 16);
        if (s == 0) y[(long)n * kDI + i] = cc + Dv * zv;
    }
}

// ygb = bf16( y * silu(gate) )
__global__ __launch_bounds__(256)
void mulgate_kernel(const float* __restrict__ zg2, const float* __restrict__ ybuf2,
                    short* __restrict__ ygb)
{
    long idx = (long)blockIdx.x * 256 + threadIdx.x;
    int dir = blockIdx.y;
    if (idx >= (long)kN * kDI) return;
    long n = idx >> 9; int i = (int)(idx & (kDI - 1));
    float g = zg2[(long)dir * kN * 2 * kDI + n * 2 * kDI + kDI + i];
    float sg = 1.f / (1.f + expf(-g));
    float v = ybuf2[(long)dir * kN * kDI + idx] * g * sg;
    ygb[(long)dir * kN * kDI + idx] = f2bf(v);
}

// r = gemm_out + x; layernorm over CO=256; write bf16 cat (fwd cols 0:256,
// reversed-bwd cols 256:512)
__global__ __launch_bounds__(256)
void resid_ln_cat_kernel(const float* __restrict__ gt2, const float* __restrict__ x2,
                         const float* __restrict__ gf, const float* __restrict__ betf,
                         const float* __restrict__ gb, const float* __restrict__ betb,
                         short* __restrict__ catb)
{
    int n = blockIdx.x, dir = blockIdx.y, t = threadIdx.x;
    const float* gt = gt2 + ((long)dir * kN + n) * kCO;
    const float* x  = x2  + ((long)dir * kN + n) * kCO;
    const float* g  = dir ? gb : gf;
    const float* be = dir ? betb : betf;
    float r = gt[t] + x[t];
    float s1 = r, s2 = r * r;
    #pragma unroll
    for (int m = 32; m >= 1; m >>= 1) {
        s1 += __shfl_xor(s1, m, 64);
        s2 += __shfl_xor(s2, m, 64);
    }
    __shared__ float red[8];
    int w = t >> 6;
    if ((t & 63) == 0) { red[w] = s1; red[4 + w] = s2; }
    __syncthreads();
    float S1 = red[0] + red[1] + red[2] + red[3];
    float S2 = red[4] + red[5] + red[6] + red[7];
    float mu  = S1 * (1.f / kCO);
    float var = S2 * (1.f / kCO) - mu * mu;
    float inv = rsqrtf(var + 1e-5f);
    float v = g[t] * (r - mu) * inv + be[t];
    int row = dir ? (kN - 1 - n) : n;
    catb[(long)row * (2 * kCO) + dir * kCO + t] = f2bf(v);
}

// bilinear 4x upsample -> bf16 into zero-padded (150,150,256) interior
__global__ __launch_bounds__(256)
void upsample_kernel(const float* __restrict__ merged, short* __restrict__ up)
{
    int p = blockIdx.x;
    int oy = p / kOW, ox = p - oy * kOW;
    int c = threadIdx.x;
    float sy = (oy + 0.5f) * ((float)kHP / (float)kOH) - 0.5f;
    float sx = (ox + 0.5f) * ((float)kWP / (float)kOW) - 0.5f;
    int iy0 = (int)floorf(sy); float fy = sy - (float)iy0;
    int ix0 = (int)floorf(sx); float fx = sx - (float)ix0;
    float wy0 = 1.f - fy, wy1 = fy, wx0 = 1.f - fx, wx1 = fx;
    int iy1 = iy0 + 1, ix1 = ix0 + 1;
    if (iy0 < 0)       { iy0 = 0;       wy0 = 0.f; }
    if (iy1 > kHP - 1) { iy1 = kHP - 1; wy1 = 0.f; }
    if (ix0 < 0)       { ix0 = 0;       wx0 = 0.f; }
    if (ix1 > kWP - 1) { ix1 = kWP - 1; wx1 = 0.f; }
    float wys = wy0 + wy1; wy0 /= wys; wy1 /= wys;
    float wxs = wx0 + wx1; wx0 /= wxs; wx1 /= wxs;
    const float* M00 = merged + (long)(iy0 * kWP + ix0) * kCO;
    const float* M01 = merged + (long)(iy0 * kWP + ix1) * kCO;
    const float* M10 = merged + (long)(iy1 * kWP + ix0) * kCO;
    const float* M11 = merged + (long)(iy1 * kWP + ix1) * kCO;
    float v = wy0 * (wx0 * M00[c] + wx1 * M01[c]) + wy1 * (wx0 * M10[c] + wx1 * M11[c]);
    up[((long)(oy + 1) * 150 + (ox + 1)) * kCO + c] = f2bf(v);
}

extern "C" void kernel_launch(void* const* d_in, const int* in_sizes, int n_in,
                              void* d_out, int out_size, void* d_ws, size_t ws_size,
                              hipStream_t stream)
{
    (void)in_sizes; (void)n_in; (void)out_size; (void)ws_size;
    const float* features  = (const float*)d_in[0];
    const float* proj_w    = (const float*)d_in[1];
    const float* attn_w1   = (const float*)d_in[2];
    const float* attn_b1   = (const float*)d_in[3];
    const float* attn_w2   = (const float*)d_in[4];
    const float* attn_b2   = (const float*)d_in[5];
    const float* src_scale = (const float*)d_in[6];
    const float* f_in_w    = (const float*)d_in[7];
    const float* f_conv_w  = (const float*)d_in[8];
    const float* f_conv_b  = (const float*)d_in[9];
    const float* f_xp_w    = (const float*)d_in[10];
    const float* f_Alog    = (const float*)d_in[11];
    const float* f_D       = (const float*)d_in[12];
    const float* f_out_w   = (const float*)d_in[13];
    const float* f_ln_g    = (const float*)d_in[14];
    const float* f_ln_b    = (const float*)d_in[15];
    const float* b_in_w    = (const float*)d_in[16];
    const float* b_conv_w  = (const float*)d_in[17];
    const float* b_conv_b  = (const float*)d_in[18];
    const float* b_xp_w    = (const float*)d_in[19];
    const float* b_Alog    = (const float*)d_in[20];
    const float* b_D       = (const float*)d_in[21];
    const float* b_out_w   = (const float*)d_in[22];
    const float* b_ln_g    = (const float*)d_in[23];
    const float* b_ln_b    = (const float*)d_in[24];
    const float* merge_w   = (const float*)d_in[25];
    const float* co1_w     = (const float*)d_in[26];
    const float* co1_b     = (const float*)d_in[27];

    float* ws      = (float*)d_ws;
    float* outp    = (float*)d_out;
    float* pf      = ws + OFF_PF;
    float* colpart = ws + OFF_COLPART;
    float* wfin    = ws + OFF_WFIN;
    float* fused2  = ws + OFF_FUSED2;
    float* zg2     = ws + OFF_ZG;
    float* z2      = ws + OFF_Z;
    float* xp2     = ws + OFF_XP;
    float* delta2  = ws + OFF_DELTA;
    float* ybuf2   = ws + OFF_Y;
    float* gt2     = ws + OFF_GT;
    float* merged  = ws + OFF_MERGED;
    float* chunkP  = ws + OFF_SCANP;
    float* chunkH  = ws + OFF_SCANH;
    float* hin     = ws + OFF_HIN;
    short* featb   = (short*)(ws + OFF_FEATB);
    short* projwb  = (short*)(ws + OFF_PROJWB);
    short* in_wt   = (short*)(ws + OFF_INWT);
    short* xp_wt   = (short*)(ws + OFF_XPWT);
    short* out_wt  = (short*)(ws + OFF_OUTWT);
    short* mrg_wt  = (short*)(ws + OFF_MERGEWT);
    short* fusedb2 = (short*)(ws + OFF_FUSEDB);
    short* z2b     = (short*)(ws + OFF_Z2B);
    short* ygb     = (short*)(ws + OFF_YGB);
    short* catb    = (short*)(ws + OFF_CAT);
    short* upb     = (short*)(ws + OFF_UPB);
    short* wconvb  = (short*)(ws + OFF_WCONVB);

    // 0. bf16 casts for proj
    cast8_kernel<<<dim3(6161), 256, 0, stream>>>(features, featb, 1577088L);
    cast8_kernel<<<dim3(1152), 256, 0, stream>>>(proj_w, projwb, 294912L);
    // 1. pf[s] = feats[s] @ proj_w[s]^T   (bf16 MFMA)
    proj_mfma_kernel<<<dim3(22, 4, 6), 256, 0, stream>>>(featb, projwb, pf);
    // 2. weight transposes (featb/projwb now dead)
    transpose_cast_kernel<<<dim3(8, 32, 2), 256, 0, stream>>>(f_in_w, b_in_w, in_wt, 256, 1024);
    transpose_cast_kernel<<<dim3(16, 18, 2), 256, 0, stream>>>(f_xp_w, b_xp_w, xp_wt, 512, 545);
    transpose_cast_kernel<<<dim3(16, 8, 1), 256, 0, stream>>>(merge_w, merge_w, mrg_wt, 512, 256);
    // 3. column sums + attention weights
    colmean_kernel<<<dim3(6, 11), 256, 0, stream>>>(pf, colpart);
    attn_kernel<<<1, 384, 0, stream>>>(colpart, attn_w1, attn_b1, attn_w2, attn_b2,
                                       src_scale, wfin);
    // 4. fuse sources (+ reversed), f32 + bf16
    fuse_kernel<<<dim3(1369), 256, 0, stream>>>(pf, wfin, fused2, fusedb2);
    // 4b. out_w transpose (pf region now dead)
    transpose_cast_kernel<<<dim3(16, 8, 2), 256, 0, stream>>>(f_out_w, b_out_w, out_wt, 512, 256);
    // 5. zg = fused @ in_w  (MFMA)
    mfma_nt<<<dim3(22, 16, 2), 256, 0, stream>>>(
        fusedb2, (long)kN * kCO, in_wt, (long)2 * kDI * kCO,
        zg2, (long)kN * 2 * kDI, kN, 2 * kDI, kCO);
    // 6. causal dwconv + silu -> z2 f32 + z2b bf16
    dwconv_kernel<<<dim3(2738, 2), 256, 0, stream>>>(zg2, f_conv_w, f_conv_b,
                                                     b_conv_w, b_conv_b, z2, z2b);
    // 7. xp = z @ xp_w  (MFMA)
    mfma_nt<<<dim3(22, 9, 2), 256, 0, stream>>>(
        z2b, (long)kN * kDI, xp_wt, (long)kXPW * kDI,
        xp2, kXPS, kN, kXPW, kDI);
    // 8. delta
    delta_kernel<<<dim3(2738, 2), 256, 0, stream>>>(xp2, delta2);
    // 9. chunk-parallel selective scan
    scan_partA<<<dim3(64, kNC), 256, 0, stream>>>(delta2, z2, xp2, f_Alog, b_Alog,
                                                  chunkP, chunkH);
    scan_partB<<<dim3(64), 256, 0, stream>>>(chunkP, chunkH, hin);
    scan_partC<<<dim3(64, kNC), 256, 0, stream>>>(delta2, z2, xp2, f_D, b_D,
                                                  f_Alog, b_Alog, hin, ybuf2);
    // 10. ygb = bf16(y * silu(gate))
    mulgate_kernel<<<dim3(2738, 2), 256, 0, stream>>>(zg2, ybuf2, ygb);
    // 11. gt = yg @ out_w  (MFMA)
    mfma_nt<<<dim3(22, 4, 2), 256, 0, stream>>>(
        ygb, (long)kN * kDI, out_wt, (long)kCO * kDI,
        gt2, (long)kN * kCO, kN, kCO, kDI);
    // 12. residual + LN + cat (bf16)
    resid_ln_cat_kernel<<<dim3(1369, 2), 256, 0, stream>>>(gt2, fused2, f_ln_g, f_ln_b,
                                                           b_ln_g, b_ln_b, catb);
    // 13. merged = cat @ merge_w  (MFMA)
    mfma_nt<<<dim3(22, 4, 1), 256, 0, stream>>>(
        catb, 0, mrg_wt, 0,
        merged, 0, kN, kCO, 2 * kCO);
    // 14. conv weight cast (z2 region dead)
    castw_conv_kernel<<<dim3(2304), 256, 0, stream>>>(co1_w, wconvb);
    // 15. zero padded bf16 upsample buffer
    hipMemsetAsync(upb, 0, (size_t)150 * 150 * 256 * sizeof(short), stream);
    // 16. bilinear upsample -> bf16 padded interior
    upsample_kernel<<<dim3(kNP), 256, 0, stream>>>(merged, upb);
    // 17. 3x3 conv via bf16 MFMA, NCHW output + bias
    conv_mfma_kernel<<<dim3(343, 2), 256, 0, stream>>>(upb, wconvb, co1_b, outp);
}

// Round 4
// 457.865 us; speedup vs baseline: 3.8617x; 1.0797x over previous
//
#include <hip/hip_runtime.h>
#include <math.h>

// ---------------------------------------------------------------------------
// Upnet_v3 pipeline, round 3:
//  - k-loop unrolling in all register-only MFMA GEMMs (latency-bound fix:
//    12-24 loads in flight per wave before each MFMA batch)
//  - attention MLP split into 12-block partial GEMM + 1-block finisher
//  - conv weight cast via coalesced LDS transpose
// ---------------------------------------------------------------------------

namespace {
constexpr int kS   = 6;
constexpr int kHP  = 37;
constexpr int kWP  = 37;
constexpr int kN   = 1369;      // HP*WP
constexpr int kCIN = 1536;
constexpr int kCO  = 256;
constexpr int kDS  = 16;
constexpr int kDI  = 512;
constexpr int kHID = 384;
constexpr int kOH  = 148;
constexpr int kOW  = 148;
constexpr int kNP  = kOH * kOW; // 21904
constexpr int kXPW = 545;       // 2*DS + DI + 1
constexpr long kXPS = 746112;   // padded kN*kXPW per dir
constexpr int kNC  = 24;        // scan chunks
constexpr int kCH  = 58;        // chunk length (24*58 = 1392 >= 1369)

// ---- workspace ledger (f32 units, total <= 13,911,040 = 55.6 MB) ----------
constexpr long OFF_PF      = 0;         // pf: 6*1369*256 = 2,102,784 (dead after fuse)
constexpr long OFF_Z2B     = 0;         // z2b bf16 (steps 6-9)
constexpr long OFF_YGB     = 0;         // ygb bf16 (steps 12-13)
constexpr long OFF_UPB     = 0;         // up_pad bf16 5,760,000 sh (steps 16+)
constexpr long OFF_SCANP   = 700928;    // chunkP 393,216
constexpr long OFF_SCANH   = 1094144;   // chunkH 393,216
constexpr long OFF_HIN     = 1487360;   // hin    393,216
constexpr long OFF_OUTWT   = 1880576;   // out_wt bf16 (ends 2,011,648)
constexpr long OFF_COLPART = 2102784;   // 16,896
constexpr long OFF_WFIN    = 2119680;   // 16
constexpr long OFF_ATTNP   = 2119696;   // attn partial 12*384 = 4,608 (ends 2,124,304)
constexpr long OFF_PROJWB  = 2200000;   // bf16 proj_w (proj only)
constexpr long OFF_INWT    = 2200000;   // in_wt bf16 (after proj)
constexpr long OFF_FUSEDB  = 2462144;   // fusedb bf16 (ends 2,812,608)
constexpr long OFF_ZG      = 2820624;   // zg2 f32 (ends 5,624,336)
constexpr long OFF_Z       = 5760000;   // z2 f32 (ends 7,161,856)
constexpr long OFF_WCONVB  = 6000000;   // conv w^T bf16 (step 14+, z2 dead)
constexpr long OFF_FEATB   = 7161856;   // featb bf16 (steps 0-1 only)
constexpr long OFF_XP      = 7161856;   // xp2 f32 (after featb dead)
constexpr long OFF_DELTA   = 8654080;   // delta2 f32
constexpr long OFF_Y       = 10055936;  // ybuf2 f32
constexpr long OFF_GT      = 11457792;  // gt2 f32 (ends 12,158,720)
constexpr long OFF_XPWT    = 11457792;  // xp_wt bf16 (dead before gt2)
constexpr long OFF_FUSED2  = 12158720;  // fused2 f32 fwd+rev (ends 12,859,648)
constexpr long OFF_CAT     = 12859648;  // catb bf16 (ends 13,210,112)
constexpr long OFF_MERGEWT = 13210112;  // merge_wt bf16 (ends 13,275,648)
constexpr long OFF_MERGED  = 13560576;  // merged f32 (ends 13,911,040)
} // namespace

typedef __attribute__((ext_vector_type(8))) short bf16x8;
typedef __attribute__((ext_vector_type(4))) float f32x4;

__device__ __forceinline__ short f2bf(float x) {
    unsigned u = __builtin_bit_cast(unsigned, x);
    unsigned r = u + 0x7fffu + ((u >> 16) & 1u);
    return (short)(r >> 16);
}

// cast 8 consecutive f32 -> bf16x8 per thread
__global__ __launch_bounds__(256)
void cast8_kernel(const float* __restrict__ in, short* __restrict__ out, long n8)
{
    long i = (long)blockIdx.x * 256 + threadIdx.x;
    if (i >= n8) return;
    const float4* p = (const float4*)(in + i * 8);
    float4 x = p[0], y = p[1];
    union { short s[8]; bf16x8 v; } u;
    u.s[0] = f2bf(x.x); u.s[1] = f2bf(x.y); u.s[2] = f2bf(x.z); u.s[3] = f2bf(x.w);
    u.s[4] = f2bf(y.x); u.s[5] = f2bf(y.y); u.s[6] = f2bf(y.z); u.s[7] = f2bf(y.w);
    *(bf16x8*)(out + i * 8) = u.v;
}

// tiled transpose+cast: w (K x N f32, row-major) -> wt (N x K bf16, row-major)
__global__ __launch_bounds__(256)
void transpose_cast_kernel(const float* __restrict__ w0, const float* __restrict__ w1,
                           short* __restrict__ wt, int K, int N)
{
    __shared__ float tile[32][33];
    int dir = blockIdx.z;
    const float* w = dir ? w1 : w0;
    short* o = wt + (long)dir * K * N;
    int k0 = blockIdx.x * 32, n0 = blockIdx.y * 32;
    int tx = threadIdx.x & 31, ty = threadIdx.x >> 5; // 32 x 8
    #pragma unroll
    for (int r = 0; r < 32; r += 8) {
        int k = k0 + ty + r, n = n0 + tx;
        tile[ty + r][tx] = (k < K && n < N) ? w[(long)k * N + n] : 0.f;
    }
    __syncthreads();
    #pragma unroll
    for (int r = 0; r < 32; r += 8) {
        int n = n0 + ty + r, k = k0 + tx;
        if (n < N && k < K) o[(long)n * K + k] = f2bf(tile[tx][ty + r]);
    }
}

// ---------------------------------------------------------------------------
// generic register-only bf16 MFMA GEMM, NT form, k-unrolled x4
// ---------------------------------------------------------------------------
__global__ __launch_bounds__(256)
void mfma_nt(const short* __restrict__ A, long sA,
             const short* __restrict__ B, long sB,
             float* __restrict__ C, long sC,
             int M, int N, int K)
{
    const int bz = blockIdx.z;
    const short* Ab = A + (long)bz * sA;
    const short* Bb = B + (long)bz * sB;
    float* Cb = C + (long)bz * sC;
    const int t = threadIdx.x, w = t >> 6, l = t & 63;
    const int lr = l & 15, lk = (l >> 4) * 8;
    const int m0 = blockIdx.x * 64 + (w >> 1) * 32;
    const int n0 = blockIdx.y * 64 + (w & 1) * 32;
    long arow[2], brow[2];
    #pragma unroll
    for (int mi = 0; mi < 2; ++mi) {
        int m = m0 + mi * 16 + lr; if (m >= M) m = M - 1;
        arow[mi] = (long)m * K;
    }
    #pragma unroll
    for (int ni = 0; ni < 2; ++ni) {
        int n = n0 + ni * 16 + lr; if (n >= N) n = N - 1;
        brow[ni] = (long)n * K;
    }
    f32x4 acc[2][2] = {};
    #pragma unroll 4
    for (int k0 = 0; k0 < K; k0 += 32) {
        bf16x8 a[2], b[2];
        #pragma unroll
        for (int mi = 0; mi < 2; ++mi)
            a[mi] = *(const bf16x8*)(Ab + arow[mi] + k0 + lk);
        #pragma unroll
        for (int ni = 0; ni < 2; ++ni)
            b[ni] = *(const bf16x8*)(Bb + brow[ni] + k0 + lk);
        #pragma unroll
        for (int mi = 0; mi < 2; ++mi)
            #pragma unroll
            for (int ni = 0; ni < 2; ++ni)
                acc[mi][ni] = __builtin_amdgcn_mfma_f32_16x16x32_bf16(a[mi], b[ni], acc[mi][ni], 0, 0, 0);
    }
    const int q = l >> 4;
    #pragma unroll
    for (int mi = 0; mi < 2; ++mi)
        #pragma unroll
        for (int ni = 0; ni < 2; ++ni)
            #pragma unroll
            for (int r = 0; r < 4; ++r) {
                int m = m0 + mi * 16 + q * 4 + r;
                int n = n0 + ni * 16 + lr;
                if (m < M && n < N)
                    Cb[(long)m * N + n] = acc[mi][ni][r];
            }
}

// ---------------------------------------------------------------------------
// proj MFMA, k-unrolled x4
// ---------------------------------------------------------------------------
__global__ __launch_bounds__(256)
void proj_mfma_kernel(const short* __restrict__ featb, const short* __restrict__ pwb,
                      float* __restrict__ pf)
{
    const int s = blockIdx.z;
    const short* A = featb + (long)s * kN * kCIN;
    const short* B = pwb   + (long)s * kCO * kCIN;
    float* C = pf + (long)s * kN * kCO;
    const int t = threadIdx.x, w = t >> 6, l = t & 63;
    const int lr = l & 15, lk = (l >> 4) * 8;
    const int m0 = blockIdx.x * 64 + (w >> 1) * 32;
    const int n0 = blockIdx.y * 64 + (w & 1) * 32;
    long arow[2], brow[2];
    #pragma unroll
    for (int mi = 0; mi < 2; ++mi) {
        int m = m0 + mi * 16 + lr; if (m >= kN) m = kN - 1;
        arow[mi] = (long)m * kCIN;
    }
    #pragma unroll
    for (int ni = 0; ni < 2; ++ni)
        brow[ni] = (long)(n0 + ni * 16 + lr) * kCIN;
    f32x4 acc[2][2] = {};
    #pragma unroll 4
    for (int k0 = 0; k0 < kCIN; k0 += 32) {
        bf16x8 a[2], b[2];
        #pragma unroll
        for (int mi = 0; mi < 2; ++mi)
            a[mi] = *(const bf16x8*)(A + arow[mi] + k0 + lk);
        #pragma unroll
        for (int ni = 0; ni < 2; ++ni)
            b[ni] = *(const bf16x8*)(B + brow[ni] + k0 + lk);
        #pragma unroll
        for (int mi = 0; mi < 2; ++mi)
            #pragma unroll
            for (int ni = 0; ni < 2; ++ni)
                acc[mi][ni] = __builtin_amdgcn_mfma_f32_16x16x32_bf16(a[mi], b[ni], acc[mi][ni], 0, 0, 0);
    }
    const int q = l >> 4;
    #pragma unroll
    for (int mi = 0; mi < 2; ++mi)
        #pragma unroll
        for (int ni = 0; ni < 2; ++ni)
            #pragma unroll
            for (int r = 0; r < 4; ++r) {
                int m = m0 + mi * 16 + q * 4 + r;
                if (m < kN)
                    C[(long)m * kCO + n0 + ni * 16 + lr] = acc[mi][ni][r];
            }
}

// ---------------------------------------------------------------------------
// conv3x3 MFMA, c0-loop unrolled x2 (12 loads in flight per batch)
// ---------------------------------------------------------------------------
__global__ __launch_bounds__(256)
void conv_mfma_kernel(const short* __restrict__ up, const short* __restrict__ wt,
                      const float* __restrict__ bias, float* __restrict__ out)
{
    const int t = threadIdx.x, w = t >> 6, l = t & 63;
    const int lr = l & 15, lk = (l >> 4) * 8;
    const int m0 = blockIdx.x * 64 + (w >> 1) * 32;
    const int n0 = blockIdx.y * 128 + (w & 1) * 64;
    long abase[2], brow[4];
    #pragma unroll
    for (int mi = 0; mi < 2; ++mi) {
        int p = m0 + mi * 16 + lr; if (p >= kNP) p = kNP - 1;
        int oy = p / kOW, ox = p - oy * kOW;
        abase[mi] = ((long)oy * 150 + ox) * kCO;
    }
    #pragma unroll
    for (int ni = 0; ni < 4; ++ni)
        brow[ni] = (long)(n0 + ni * 16 + lr) * 2304;
    f32x4 acc[2][4] = {};
    for (int tap = 0; tap < 9; ++tap) {
        const int ky = tap / 3, kx = tap - ky * 3;
        const long toff = ((long)ky * 150 + kx) * kCO;
        const long woff = (long)tap * kCO;
        #pragma unroll 2
        for (int c0 = 0; c0 < kCO; c0 += 32) {
            bf16x8 a[2], b[4];
            #pragma unroll
            for (int mi = 0; mi < 2; ++mi)
                a[mi] = *(const bf16x8*)(up + abase[mi] + toff + c0 + lk);
            #pragma unroll
            for (int ni = 0; ni < 4; ++ni)
                b[ni] = *(const bf16x8*)(wt + brow[ni] + woff + c0 + lk);
            #pragma unroll
            for (int mi = 0; mi < 2; ++mi)
                #pragma unroll
                for (int ni = 0; ni < 4; ++ni)
                    acc[mi][ni] = __builtin_amdgcn_mfma_f32_16x16x32_bf16(a[mi], b[ni], acc[mi][ni], 0, 0, 0);
        }
    }
    const int q = l >> 4;
    #pragma unroll
    for (int mi = 0; mi < 2; ++mi)
        #pragma unroll
        for (int ni = 0; ni < 4; ++ni) {
            const int co = n0 + ni * 16 + lr;
            const float bv = bias[co];
            #pragma unroll
            for (int r = 0; r < 4; ++r) {
                int p = m0 + mi * 16 + q * 4 + r;
                if (p < kNP)
                    out[(long)co * kNP + p] = acc[mi][ni][r] + bv;
            }
        }
}

// partial column sums of pf over n
__global__ __launch_bounds__(256)
void colmean_kernel(const float* __restrict__ pf, float* __restrict__ colpart)
{
    int s = blockIdx.x, ch = blockIdx.y, o = threadIdx.x;
    int n0 = ch * 128, n1 = n0 + 128 > kN ? kN : n0 + 128;
    float a = 0.f;
    for (int n = n0; n < n1; ++n) a += pf[((long)s * kN + n) * kCO + o];
    colpart[ch * kS * kCO + s * kCO + o] = a;
}

// attn stage 1: partial[b][t] = sum_{c in 128b..128b+127} cm[c] * w1[c][t]
__global__ __launch_bounds__(384)
void attn_part1(const float* __restrict__ colpart, const float* __restrict__ w1,
                float* __restrict__ partial)
{
    __shared__ float cm[128];
    int b = blockIdx.x, t = threadIdx.x;
    int c0 = b * 128;
    if (t < 128) {
        float a = 0.f;
        #pragma unroll
        for (int ch = 0; ch < 11; ++ch) a += colpart[ch * kS * kCO + c0 + t];
        cm[t] = a * (1.f / kN);
    }
    __syncthreads();
    float acc = 0.f;
    #pragma unroll 4
    for (int c = 0; c < 128; ++c) acc += cm[c] * w1[(long)(c0 + c) * kHID + t];
    partial[b * kHID + t] = acc;
}

// attn stage 2: h = relu(sum partial + b1); logits; double softmax -> wfin[6]
__global__ __launch_bounds__(384)
void attn_part2(const float* __restrict__ partial, const float* __restrict__ b1,
                const float* __restrict__ w2, const float* __restrict__ b2,
                const float* __restrict__ ss, float* __restrict__ wfin)
{
    __shared__ float h[kHID];
    __shared__ float logits[8];
    int t = threadIdx.x;
    float acc = b1[t];
    #pragma unroll
    for (int b = 0; b < 12; ++b) acc += partial[b * kHID + t];
    h[t] = fmaxf(acc, 0.f);
    __syncthreads();
    if (t < kS) {
        float lg = b2[t];
        for (int j = 0; j < kHID; ++j) lg += h[j] * w2[j * kS + t];
        logits[t] = lg;
    }
    __syncthreads();
    if (t == 0) {
        float w[kS], mx = -1e30f, sum = 0.f;
        for (int s = 0; s < kS; ++s) mx = fmaxf(mx, logits[s]);
        for (int s = 0; s < kS; ++s) { w[s] = expf(logits[s] - mx); sum += w[s]; }
        for (int s = 0; s < kS; ++s) w[s] /= sum;
        mx = -1e30f;
        for (int s = 0; s < kS; ++s) { w[s] *= ss[s]; mx = fmaxf(mx, w[s]); }
        sum = 0.f;
        float e[kS];
        for (int s = 0; s < kS; ++s) { e[s] = expf(w[s] - mx); sum += e[s]; }
        for (int s = 0; s < kS; ++s) wfin[s] = e[s] / sum;
    }
}

// fused = sum_s wfin[s]*pf[s]; writes f32 fwd+rev and bf16 fwd+rev
__global__ __launch_bounds__(256)
void fuse_kernel(const float* __restrict__ pf, const float* __restrict__ wfin,
                 float* __restrict__ fused2, short* __restrict__ fusedb2)
{
    long idx = (long)blockIdx.x * 256 + threadIdx.x;
    if (idx >= (long)kN * kCO) return;
    float acc = 0.f;
    #pragma unroll
    for (int s = 0; s < kS; ++s) acc += wfin[s] * pf[(long)s * kN * kCO + idx];
    long n = idx / kCO; int c = (int)(idx % kCO);
    long ridx = (long)kN * kCO + (kN - 1 - n) * kCO + c;
    short bv = f2bf(acc);
    fused2[idx] = acc;
    fused2[ridx] = acc;
    fusedb2[idx] = bv;
    fusedb2[ridx] = bv;
}

// causal depthwise conv (K=4) + silu; writes f32 z2 and bf16 z2b
__global__ __launch_bounds__(256)
void dwconv_kernel(const float* __restrict__ zg2,
                   const float* __restrict__ wf, const float* __restrict__ bf,
                   const float* __restrict__ wb, const float* __restrict__ bb,
                   float* __restrict__ z2, short* __restrict__ z2b)
{
    long idx = (long)blockIdx.x * 256 + threadIdx.x;
    int dir = blockIdx.y;
    if (idx >= (long)kN * kDI) return;
    long n = idx >> 9; int i = (int)(idx & (kDI - 1));
    const float* zg = zg2 + (long)dir * kN * 2 * kDI;
    const float* w  = dir ? wb : wf;
    const float* b  = dir ? bb : bf;
    float acc = b[i];
    #pragma unroll
    for (int k = 0; k < 4; ++k) {
        long m = n - 3 + k;
        if (m >= 0) acc += w[k * kDI + i] * zg[m * 2 * kDI + i];
    }
    float sg = 1.f / (1.f + expf(-acc));
    float v = acc * sg;
    z2 [(long)dir * kN * kDI + idx] = v;
    z2b[(long)dir * kN * kDI + idx] = f2bf(v);
}

// delta = softplus(xp[:,32+i] + xp[:,544])
__global__ __launch_bounds__(256)
void delta_kernel(const float* __restrict__ xp2, float* __restrict__ delta2)
{
    long idx = (long)blockIdx.x * 256 + threadIdx.x;
    int dir = blockIdx.y;
    if (idx >= (long)kN * kDI) return;
    long n = idx >> 9; int i = (int)(idx & (kDI - 1));
    const float* xp = xp2 + (long)dir * kXPS + n * kXPW;
    float x = xp[2 * kDS + i] + xp[kXPW - 1];
    float sp = fmaxf(x, 0.f) + log1pf(expf(-fabsf(x)));
    delta2[(long)dir * kN * kDI + idx] = sp;
}

// ---- chunk-parallel scan: pass A (local scan, h_in = 0) -------------------
__global__ __launch_bounds__(256)
void scan_partA(const float* __restrict__ delta2, const float* __restrict__ z2,
                const float* __restrict__ xp2,
                const float* __restrict__ Alogf, const float* __restrict__ Alogb,
                float* __restrict__ chunkP, float* __restrict__ chunkH)
{
    int bx = blockIdx.x;            // dir*32 + iblk
    int c  = blockIdx.y;            // chunk
    int dir = bx >> 5, iblk = bx & 31;
    int t = threadIdx.x;
    int s = t & 15, il = t >> 4;
    int i = iblk * 16 + il;
    int gid = dir * 8192 + iblk * 256 + t;
    const float* delta = delta2 + (long)dir * kN * kDI;
    const float* z     = z2     + (long)dir * kN * kDI;
    const float* xp    = xp2    + (long)dir * kXPS;
    const float* Alog  = dir ? Alogb : Alogf;
    float A = expf(Alog[i * kDS + s]);
    int n0 = c * kCH, n1 = n0 + kCH; if (n1 > kN) n1 = kN;
    float h = 0.f, P = 1.f;
    for (int n = n0; n < n1; ++n) {
        float dlt = delta[(long)n * kDI + i];
        float zv  = z[(long)n * kDI + i];
        float Bv  = xp[(long)n * kXPW + s];
        float dA  = __expf(-dlt * A);
        h = dA * h + dlt * Bv * zv;
        P *= dA;
    }
    chunkP[(long)c * 16384 + gid] = P;
    chunkH[(long)c * 16384 + gid] = h;
}

// ---- pass B: serial combine over chunks -> h_in per chunk -----------------
__global__ __launch_bounds__(256)
void scan_partB(const float* __restrict__ chunkP, const float* __restrict__ chunkH,
                float* __restrict__ hin)
{
    int gid = blockIdx.x * 256 + threadIdx.x; // 16384 threads
    float H = 0.f;
    for (int c = 0; c < kNC; ++c) {
        hin[(long)c * 16384 + gid] = H;
        H = chunkP[(long)c * 16384 + gid] * H + chunkH[(long)c * 16384 + gid];
    }
}

// ---- pass C: re-scan with true h_in, emit y -------------------------------
__global__ __launch_bounds__(256)
void scan_partC(const float* __restrict__ delta2, const float* __restrict__ z2,
                const float* __restrict__ xp2,
                const float* __restrict__ Df, const float* __restrict__ Db,
                const float* __restrict__ Alogf, const float* __restrict__ Alogb,
                const float* __restrict__ hin, float* __restrict__ ybuf2)
{
    int bx = blockIdx.x;
    int c  = blockIdx.y;
    int dir = bx >> 5, iblk = bx & 31;
    int t = threadIdx.x;
    int s = t & 15, il = t >> 4;
    int i = iblk * 16 + il;
    int gid = dir * 8192 + iblk * 256 + t;
    const float* delta = delta2 + (long)dir * kN * kDI;
    const float* z     = z2     + (long)dir * kN * kDI;
    const float* xp    = xp2    + (long)dir * kXPS;
    const float* D     = dir ? Db : Df;
    const float* Alog  = dir ? Alogb : Alogf;
    float* y           = ybuf2  + (long)dir * kN * kDI;
    float A  = expf(Alog[i * kDS + s]);
    float Dv = D[i];
    int n0 = c * kCH, n1 = n0 + kCH; if (n1 > kN) n1 = kN;
    float h = hin[(long)c * 16384 + gid];
    for (int n = n0; n < n1; ++n) {
        float dlt = delta[(long)n * kDI + i];
        float zv  = z[(long)n * kDI + i];
        float Bv  = xp[(long)n * kXPW + s];
        float Cv  = xp[(long)n * kXPW + kDS + s];
        float dA  = __expf(-dlt * A);
        h = dA * h + dlt * Bv * zv;
        float cc = h * Cv;
        cc += __shfl_xor(cc, 1, 16);
        cc += __shfl_xor(cc, 2, 16);
        cc += __shfl_xor(cc, 4, 16);
        cc += __shfl_xor(cc, 8, 16);
        if (s == 0) y[(long)n * kDI + i] = cc + Dv * zv;
    }
}

// ygb = bf16( y * silu(gate) )
__global__ __launch_bounds__(256)
void mulgate_kernel(const float* __restrict__ zg2, const float* __restrict__ ybuf2,
                    short* __restrict__ ygb)
{
    long idx = (long)blockIdx.x * 256 + threadIdx.x;
    int dir = blockIdx.y;
    if (idx >= (long)kN * kDI) return;
    long n = idx >> 9; int i = (int)(idx & (kDI - 1));
    float g = zg2[(long)dir * kN * 2 * kDI + n * 2 * kDI + kDI + i];
    float sg = 1.f / (1.f + expf(-g));
    float v = ybuf2[(long)dir * kN * kDI + idx] * g * sg;
    ygb[(long)dir * kN * kDI + idx] = f2bf(v);
}

// r = gemm_out + x; layernorm; write bf16 cat (fwd 0:256, reversed-bwd 256:512)
__global__ __launch_bounds__(256)
void resid_ln_cat_kernel(const float* __restrict__ gt2, const float* __restrict__ x2,
                         const float* __restrict__ gf, const float* __restrict__ betf,
                         const float* __restrict__ gb, const float* __restrict__ betb,
                         short* __restrict__ catb)
{
    int n = blockIdx.x, dir = blockIdx.y, t = threadIdx.x;
    const float* gt = gt2 + ((long)dir * kN + n) * kCO;
    const float* x  = x2  + ((long)dir * kN + n) * kCO;
    const float* g  = dir ? gb : gf;
    const float* be = dir ? betb : betf;
    float r = gt[t] + x[t];
    float s1 = r, s2 = r * r;
    #pragma unroll
    for (int m = 32; m >= 1; m >>= 1) {
        s1 += __shfl_xor(s1, m, 64);
        s2 += __shfl_xor(s2, m, 64);
    }
    __shared__ float red[8];
    int w = t >> 6;
    if ((t & 63) == 0) { red[w] = s1; red[4 + w] = s2; }
    __syncthreads();
    float S1 = red[0] + red[1] + red[2] + red[3];
    float S2 = red[4] + red[5] + red[6] + red[7];
    float mu  = S1 * (1.f / kCO);
    float var = S2 * (1.f / kCO) - mu * mu;
    float inv = rsqrtf(var + 1e-5f);
    float v = g[t] * (r - mu) * inv + be[t];
    int row = dir ? (kN - 1 - n) : n;
    catb[(long)row * (2 * kCO) + dir * kCO + t] = f2bf(v);
}

// bilinear 4x upsample -> bf16 into zero-padded (150,150,256) interior
__global__ __launch_bounds__(256)
void upsample_kernel(const float* __restrict__ merged, short* __restrict__ up)
{
    int p = blockIdx.x;
    int oy = p / kOW, ox = p - oy * kOW;
    int c = threadIdx.x;
    float sy = (oy + 0.5f) * ((float)kHP / (float)kOH) - 0.5f;
    float sx = (ox + 0.5f) * ((float)kWP / (float)kOW) - 0.5f;
    int iy0 = (int)floorf(sy); float fy = sy - (float)iy0;
    int ix0 = (int)floorf(sx); float fx = sx - (float)ix0;
    float wy0 = 1.f - fy, wy1 = fy, wx0 = 1.f - fx, wx1 = fx;
    int iy1 = iy0 + 1, ix1 = ix0 + 1;
    if (iy0 < 0)       { iy0 = 0;       wy0 = 0.f; }
    if (iy1 > kHP - 1) { iy1 = kHP - 1; wy1 = 0.f; }
    if (ix0 < 0)       { ix0 = 0;       wx0 = 0.f; }
    if (ix1 > kWP - 1) { ix1 = kWP - 1; wx1 = 0.f; }
    float wys = wy0 + wy1; wy0 /= wys; wy1 /= wys;
    float wxs = wx0 + wx1; wx0 /= wxs; wx1 /= wxs;
    const float* M00 = merged + (long)(iy0 * kWP + ix0) * kCO;
    const float* M01 = merged + (long)(iy0 * kWP + ix1) * kCO;
    const float* M10 = merged + (long)(iy1 * kWP + ix0) * kCO;
    const float* M11 = merged + (long)(iy1 * kWP + ix1) * kCO;
    float v = wy0 * (wx0 * M00[c] + wx1 * M01[c]) + wy1 * (wx0 * M10[c] + wx1 * M11[c]);
    up[((long)(oy + 1) * 150 + (ox + 1)) * kCO + c] = f2bf(v);
}

extern "C" void kernel_launch(void* const* d_in, const int* in_sizes, int n_in,
                              void* d_out, int out_size, void* d_ws, size_t ws_size,
                              hipStream_t stream)
{
    (void)in_sizes; (void)n_in; (void)out_size; (void)ws_size;
    const float* features  = (const float*)d_in[0];
    const float* proj_w    = (const float*)d_in[1];
    const float* attn_w1   = (const float*)d_in[2];
    const float* attn_b1   = (const float*)d_in[3];
    const float* attn_w2   = (const float*)d_in[4];
    const float* attn_b2   = (const float*)d_in[5];
    const float* src_scale = (const float*)d_in[6];
    const float* f_in_w    = (const float*)d_in[7];
    const float* f_conv_w  = (const float*)d_in[8];
    const float* f_conv_b  = (const float*)d_in[9];
    const float* f_xp_w    = (const float*)d_in[10];
    const float* f_Alog    = (const float*)d_in[11];
    const float* f_D       = (const float*)d_in[12];
    const float* f_out_w   = (const float*)d_in[13];
    const float* f_ln_g    = (const float*)d_in[14];
    const float* f_ln_b    = (const float*)d_in[15];
    const float* b_in_w    = (const float*)d_in[16];
    const float* b_conv_w  = (const float*)d_in[17];
    const float* b_conv_b  = (const float*)d_in[18];
    const float* b_xp_w    = (const float*)d_in[19];
    const float* b_Alog    = (const float*)d_in[20];
    const float* b_D       = (const float*)d_in[21];
    const float* b_out_w   = (const float*)d_in[22];
    const float* b_ln_g    = (const float*)d_in[23];
    const float* b_ln_b    = (const float*)d_in[24];
    const float* merge_w   = (const float*)d_in[25];
    const float* co1_w     = (const float*)d_in[26];
    const float* co1_b     = (const float*)d_in[27];

    float* ws      = (float*)d_ws;
    float* outp    = (float*)d_out;
    float* pf      = ws + OFF_PF;
    float* colpart = ws + OFF_COLPART;
    float* wfin    = ws + OFF_WFIN;
    float* attnp   = ws + OFF_ATTNP;
    float* fused2  = ws + OFF_FUSED2;
    float* zg2     = ws + OFF_ZG;
    float* z2      = ws + OFF_Z;
    float* xp2     = ws + OFF_XP;
    float* delta2  = ws + OFF_DELTA;
    float* ybuf2   = ws + OFF_Y;
    float* gt2     = ws + OFF_GT;
    float* merged  = ws + OFF_MERGED;
    float* chunkP  = ws + OFF_SCANP;
    float* chunkH  = ws + OFF_SCANH;
    float* hin     = ws + OFF_HIN;
    short* featb   = (short*)(ws + OFF_FEATB);
    short* projwb  = (short*)(ws + OFF_PROJWB);
    short* in_wt   = (short*)(ws + OFF_INWT);
    short* xp_wt   = (short*)(ws + OFF_XPWT);
    short* out_wt  = (short*)(ws + OFF_OUTWT);
    short* mrg_wt  = (short*)(ws + OFF_MERGEWT);
    short* fusedb2 = (short*)(ws + OFF_FUSEDB);
    short* z2b     = (short*)(ws + OFF_Z2B);
    short* ygb     = (short*)(ws + OFF_YGB);
    short* catb    = (short*)(ws + OFF_CAT);
    short* upb     = (short*)(ws + OFF_UPB);
    short* wconvb  = (short*)(ws + OFF_WCONVB);

    // 0. bf16 casts for proj
    cast8_kernel<<<dim3(6161), 256, 0, stream>>>(features, featb, 1577088L);
    cast8_kernel<<<dim3(1152), 256, 0, stream>>>(proj_w, projwb, 294912L);
    // 1. pf[s] = feats[s] @ proj_w[s]^T   (bf16 MFMA)
    proj_mfma_kernel<<<dim3(22, 4, 6), 256, 0, stream>>>(featb, projwb, pf);
    // 2. weight transposes (featb/projwb dead after proj)
    transpose_cast_kernel<<<dim3(8, 32, 2), 256, 0, stream>>>(f_in_w, b_in_w, in_wt, 256, 1024);
    transpose_cast_kernel<<<dim3(16, 18, 2), 256, 0, stream>>>(f_xp_w, b_xp_w, xp_wt, 512, 545);
    transpose_cast_kernel<<<dim3(16, 8, 1), 256, 0, stream>>>(merge_w, merge_w, mrg_wt, 512, 256);
    // 3. column sums + attention weights (3-stage, deterministic)
    colmean_kernel<<<dim3(6, 11), 256, 0, stream>>>(pf, colpart);
    attn_part1<<<dim3(12), 384, 0, stream>>>(colpart, attn_w1, attnp);
    attn_part2<<<1, 384, 0, stream>>>(attnp, attn_b1, attn_w2, attn_b2, src_scale, wfin);
    // 4. fuse sources (+ reversed), f32 + bf16
    fuse_kernel<<<dim3(1369), 256, 0, stream>>>(pf, wfin, fused2, fusedb2);
    // 4b. out_w transpose (pf region now dead)
    transpose_cast_kernel<<<dim3(16, 8, 2), 256, 0, stream>>>(f_out_w, b_out_w, out_wt, 512, 256);
    // 5. zg = fused @ in_w  (MFMA)
    mfma_nt<<<dim3(22, 16, 2), 256, 0, stream>>>(
        fusedb2, (long)kN * kCO, in_wt, (long)2 * kDI * kCO,
        zg2, (long)kN * 2 * kDI, kN, 2 * kDI, kCO);
    // 6. causal dwconv + silu -> z2 f32 + z2b bf16
    dwconv_kernel<<<dim3(2738, 2), 256, 0, stream>>>(zg2, f_conv_w, f_conv_b,
                                                     b_conv_w, b_conv_b, z2, z2b);
    // 7. xp = z @ xp_w  (MFMA)
    mfma_nt<<<dim3(22, 9, 2), 256, 0, stream>>>(
        z2b, (long)kN * kDI, xp_wt, (long)kXPW * kDI,
        xp2, kXPS, kN, kXPW, kDI);
    // 8. delta
    delta_kernel<<<dim3(2738, 2), 256, 0, stream>>>(xp2, delta2);
    // 9. chunk-parallel selective scan
    scan_partA<<<dim3(64, kNC), 256, 0, stream>>>(delta2, z2, xp2, f_Alog, b_Alog,
                                                  chunkP, chunkH);
    scan_partB<<<dim3(64), 256, 0, stream>>>(chunkP, chunkH, hin);
    scan_partC<<<dim3(64, kNC), 256, 0, stream>>>(delta2, z2, xp2, f_D, b_D,
                                                  f_Alog, b_Alog, hin, ybuf2);
    // 10. ygb = bf16(y * silu(gate))
    mulgate_kernel<<<dim3(2738, 2), 256, 0, stream>>>(zg2, ybuf2, ygb);
    // 11. gt = yg @ out_w  (MFMA)
    mfma_nt<<<dim3(22, 4, 2), 256, 0, stream>>>(
        ygb, (long)kN * kDI, out_wt, (long)kCO * kDI,
        gt2, (long)kN * kCO, kN, kCO, kDI);
    // 12. residual + LN + cat (bf16)
    resid_ln_cat_kernel<<<dim3(1369, 2), 256, 0, stream>>>(gt2, fused2, f_ln_g, f_ln_b,
                                                           b_ln_g, b_ln_b, catb);
    // 13. merged = cat @ merge_w  (MFMA)
    mfma_nt<<<dim3(22, 4, 1), 256, 0, stream>>>(
        catb, 0, mrg_wt, 0,
        merged, 0, kN, kCO, 2 * kCO);
    // 14. conv weight -> bf16 transposed [cout][2304] (z2 region dead)
    transpose_cast_kernel<<<dim3(72, 8, 1), 256, 0, stream>>>(co1_w, co1_w, wconvb, 2304, 256);
    // 15. zero padded bf16 upsample buffer
    hipMemsetAsync(upb, 0, (size_t)150 * 150 * 256 * sizeof(short), stream);
    // 16. bilinear upsample -> bf16 padded interior
    upsample_kernel<<<dim3(kNP), 256, 0, stream>>>(merged, upb);
    // 17. 3x3 conv via bf16 MFMA, NCHW output + bias
    conv_mfma_kernel<<<dim3(343, 2), 256, 0, stream>>>(upb, wconvb, co1_b, outp);
}

// Round 5
// 363.117 us; speedup vs baseline: 4.8693x; 1.2609x over previous
//
#include <hip/hip_runtime.h>
#include <math.h>

// ---------------------------------------------------------------------------
// Upnet_v3 pipeline, round 4:
//  - conv3x3: LDS-staged double-buffered MFMA GEMM (2-barrier loop, reg-staged
//    async prefetch, XOR-swizzled LDS reads)
//  - proj / mfma_nt: explicit ping-pong register prefetch (forced ILP)
// ---------------------------------------------------------------------------

namespace {
constexpr int kS   = 6;
constexpr int kHP  = 37;
constexpr int kWP  = 37;
constexpr int kN   = 1369;      // HP*WP
constexpr int kCIN = 1536;
constexpr int kCO  = 256;
constexpr int kDS  = 16;
constexpr int kDI  = 512;
constexpr int kHID = 384;
constexpr int kOH  = 148;
constexpr int kOW  = 148;
constexpr int kNP  = kOH * kOW; // 21904
constexpr int kXPW = 545;       // 2*DS + DI + 1
constexpr long kXPS = 746112;   // padded kN*kXPW per dir
constexpr int kNC  = 24;        // scan chunks
constexpr int kCH  = 58;        // chunk length (24*58 = 1392 >= 1369)

// ---- workspace ledger (f32 units, total <= 13,911,040 = 55.6 MB) ----------
constexpr long OFF_PF      = 0;         // pf (dead after fuse)
constexpr long OFF_Z2B     = 0;         // z2b bf16 (steps 6-9)
constexpr long OFF_YGB     = 0;         // ygb bf16 (steps 12-13)
constexpr long OFF_UPB     = 0;         // up_pad bf16 (steps 16+)
constexpr long OFF_SCANP   = 700928;
constexpr long OFF_SCANH   = 1094144;
constexpr long OFF_HIN     = 1487360;
constexpr long OFF_OUTWT   = 1880576;
constexpr long OFF_COLPART = 2102784;
constexpr long OFF_WFIN    = 2119680;
constexpr long OFF_ATTNP   = 2119696;
constexpr long OFF_PROJWB  = 2200000;
constexpr long OFF_INWT    = 2200000;
constexpr long OFF_FUSEDB  = 2462144;
constexpr long OFF_ZG      = 2820624;
constexpr long OFF_Z       = 5760000;
constexpr long OFF_WCONVB  = 6000000;
constexpr long OFF_FEATB   = 7161856;
constexpr long OFF_XP      = 7161856;
constexpr long OFF_DELTA   = 8654080;
constexpr long OFF_Y       = 10055936;
constexpr long OFF_GT      = 11457792;
constexpr long OFF_XPWT    = 11457792;
constexpr long OFF_FUSED2  = 12158720;
constexpr long OFF_CAT     = 12859648;
constexpr long OFF_MERGEWT = 13210112;
constexpr long OFF_MERGED  = 13560576;
} // namespace

typedef __attribute__((ext_vector_type(8))) short bf16x8;
typedef __attribute__((ext_vector_type(4))) float f32x4;

__device__ __forceinline__ short f2bf(float x) {
    unsigned u = __builtin_bit_cast(unsigned, x);
    unsigned r = u + 0x7fffu + ((u >> 16) & 1u);
    return (short)(r >> 16);
}

// cast 8 consecutive f32 -> bf16x8 per thread
__global__ __launch_bounds__(256)
void cast8_kernel(const float* __restrict__ in, short* __restrict__ out, long n8)
{
    long i = (long)blockIdx.x * 256 + threadIdx.x;
    if (i >= n8) return;
    const float4* p = (const float4*)(in + i * 8);
    float4 x = p[0], y = p[1];
    union { short s[8]; bf16x8 v; } u;
    u.s[0] = f2bf(x.x); u.s[1] = f2bf(x.y); u.s[2] = f2bf(x.z); u.s[3] = f2bf(x.w);
    u.s[4] = f2bf(y.x); u.s[5] = f2bf(y.y); u.s[6] = f2bf(y.z); u.s[7] = f2bf(y.w);
    *(bf16x8*)(out + i * 8) = u.v;
}

// tiled transpose+cast: w (K x N f32) -> wt (N x K bf16)
__global__ __launch_bounds__(256)
void transpose_cast_kernel(const float* __restrict__ w0, const float* __restrict__ w1,
                           short* __restrict__ wt, int K, int N)
{
    __shared__ float tile[32][33];
    int dir = blockIdx.z;
    const float* w = dir ? w1 : w0;
    short* o = wt + (long)dir * K * N;
    int k0 = blockIdx.x * 32, n0 = blockIdx.y * 32;
    int tx = threadIdx.x & 31, ty = threadIdx.x >> 5; // 32 x 8
    #pragma unroll
    for (int r = 0; r < 32; r += 8) {
        int k = k0 + ty + r, n = n0 + tx;
        tile[ty + r][tx] = (k < K && n < N) ? w[(long)k * N + n] : 0.f;
    }
    __syncthreads();
    #pragma unroll
    for (int r = 0; r < 32; r += 8) {
        int n = n0 + ty + r, k = k0 + tx;
        if (n < N && k < K) o[(long)n * K + k] = f2bf(tile[tx][ty + r]);
    }
}

// ---------------------------------------------------------------------------
// generic register-only bf16 MFMA GEMM, NT form, explicit ping-pong prefetch
// ---------------------------------------------------------------------------
__global__ __launch_bounds__(256)
void mfma_nt(const short* __restrict__ A, long sA,
             const short* __restrict__ B, long sB,
             float* __restrict__ C, long sC,
             int M, int N, int K)
{
    const int bz = blockIdx.z;
    const short* Ab = A + (long)bz * sA;
    const short* Bb = B + (long)bz * sB;
    float* Cb = C + (long)bz * sC;
    const int t = threadIdx.x, w = t >> 6, l = t & 63;
    const int lr = l & 15, lk = (l >> 4) * 8;
    const int m0 = blockIdx.x * 64 + (w >> 1) * 32;
    const int n0 = blockIdx.y * 64 + (w & 1) * 32;
    long arow[2], brow[2];
    #pragma unroll
    for (int mi = 0; mi < 2; ++mi) {
        int m = m0 + mi * 16 + lr; if (m >= M) m = M - 1;
        arow[mi] = (long)m * K;
    }
    #pragma unroll
    for (int ni = 0; ni < 2; ++ni) {
        int n = n0 + ni * 16 + lr; if (n >= N) n = N - 1;
        brow[ni] = (long)n * K;
    }
    f32x4 acc[2][2] = {};
    bf16x8 aA[2], bA[2], aB[2], bB[2];
    #pragma unroll
    for (int mi = 0; mi < 2; ++mi) aA[mi] = *(const bf16x8*)(Ab + arow[mi] + lk);
    #pragma unroll
    for (int ni = 0; ni < 2; ++ni) bA[ni] = *(const bf16x8*)(Bb + brow[ni] + lk);
    for (int k0 = 0; k0 < K; k0 += 64) {
        #pragma unroll
        for (int mi = 0; mi < 2; ++mi) aB[mi] = *(const bf16x8*)(Ab + arow[mi] + k0 + 32 + lk);
        #pragma unroll
        for (int ni = 0; ni < 2; ++ni) bB[ni] = *(const bf16x8*)(Bb + brow[ni] + k0 + 32 + lk);
        #pragma unroll
        for (int mi = 0; mi < 2; ++mi)
            #pragma unroll
            for (int ni = 0; ni < 2; ++ni)
                acc[mi][ni] = __builtin_amdgcn_mfma_f32_16x16x32_bf16(aA[mi], bA[ni], acc[mi][ni], 0, 0, 0);
        if (k0 + 64 < K) {
            #pragma unroll
            for (int mi = 0; mi < 2; ++mi) aA[mi] = *(const bf16x8*)(Ab + arow[mi] + k0 + 64 + lk);
            #pragma unroll
            for (int ni = 0; ni < 2; ++ni) bA[ni] = *(const bf16x8*)(Bb + brow[ni] + k0 + 64 + lk);
        }
        #pragma unroll
        for (int mi = 0; mi < 2; ++mi)
            #pragma unroll
            for (int ni = 0; ni < 2; ++ni)
                acc[mi][ni] = __builtin_amdgcn_mfma_f32_16x16x32_bf16(aB[mi], bB[ni], acc[mi][ni], 0, 0, 0);
    }
    const int q = l >> 4;
    #pragma unroll
    for (int mi = 0; mi < 2; ++mi)
        #pragma unroll
        for (int ni = 0; ni < 2; ++ni)
            #pragma unroll
            for (int r = 0; r < 4; ++r) {
                int m = m0 + mi * 16 + q * 4 + r;
                int n = n0 + ni * 16 + lr;
                if (m < M && n < N)
                    Cb[(long)m * N + n] = acc[mi][ni][r];
            }
}

// ---------------------------------------------------------------------------
// proj MFMA, explicit ping-pong prefetch (K=1536, multiple of 64)
// ---------------------------------------------------------------------------
__global__ __launch_bounds__(256)
void proj_mfma_kernel(const short* __restrict__ featb, const short* __restrict__ pwb,
                      float* __restrict__ pf)
{
    const int s = blockIdx.z;
    const short* A = featb + (long)s * kN * kCIN;
    const short* B = pwb   + (long)s * kCO * kCIN;
    float* C = pf + (long)s * kN * kCO;
    const int t = threadIdx.x, w = t >> 6, l = t & 63;
    const int lr = l & 15, lk = (l >> 4) * 8;
    const int m0 = blockIdx.x * 64 + (w >> 1) * 32;
    const int n0 = blockIdx.y * 64 + (w & 1) * 32;
    long arow[2], brow[2];
    #pragma unroll
    for (int mi = 0; mi < 2; ++mi) {
        int m = m0 + mi * 16 + lr; if (m >= kN) m = kN - 1;
        arow[mi] = (long)m * kCIN;
    }
    #pragma unroll
    for (int ni = 0; ni < 2; ++ni)
        brow[ni] = (long)(n0 + ni * 16 + lr) * kCIN;
    f32x4 acc[2][2] = {};
    bf16x8 aA[2], bA[2], aB[2], bB[2];
    #pragma unroll
    for (int mi = 0; mi < 2; ++mi) aA[mi] = *(const bf16x8*)(A + arow[mi] + lk);
    #pragma unroll
    for (int ni = 0; ni < 2; ++ni) bA[ni] = *(const bf16x8*)(B + brow[ni] + lk);
    for (int k0 = 0; k0 < kCIN; k0 += 64) {
        #pragma unroll
        for (int mi = 0; mi < 2; ++mi) aB[mi] = *(const bf16x8*)(A + arow[mi] + k0 + 32 + lk);
        #pragma unroll
        for (int ni = 0; ni < 2; ++ni) bB[ni] = *(const bf16x8*)(B + brow[ni] + k0 + 32 + lk);
        #pragma unroll
        for (int mi = 0; mi < 2; ++mi)
            #pragma unroll
            for (int ni = 0; ni < 2; ++ni)
                acc[mi][ni] = __builtin_amdgcn_mfma_f32_16x16x32_bf16(aA[mi], bA[ni], acc[mi][ni], 0, 0, 0);
        if (k0 + 64 < kCIN) {
            #pragma unroll
            for (int mi = 0; mi < 2; ++mi) aA[mi] = *(const bf16x8*)(A + arow[mi] + k0 + 64 + lk);
            #pragma unroll
            for (int ni = 0; ni < 2; ++ni) bA[ni] = *(const bf16x8*)(B + brow[ni] + k0 + 64 + lk);
        }
        #pragma unroll
        for (int mi = 0; mi < 2; ++mi)
            #pragma unroll
            for (int ni = 0; ni < 2; ++ni)
                acc[mi][ni] = __builtin_amdgcn_mfma_f32_16x16x32_bf16(aB[mi], bB[ni], acc[mi][ni], 0, 0, 0);
    }
    const int q = l >> 4;
    #pragma unroll
    for (int mi = 0; mi < 2; ++mi)
        #pragma unroll
        for (int ni = 0; ni < 2; ++ni)
            #pragma unroll
            for (int r = 0; r < 4; ++r) {
                int m = m0 + mi * 16 + q * 4 + r;
                if (m < kN)
                    C[(long)m * kCO + n0 + ni * 16 + lr] = acc[mi][ni][r];
            }
}

// ---------------------------------------------------------------------------
// conv3x3 MFMA, LDS-staged double-buffered 2-barrier loop.
// Block: 64 px x 128 co, 4 waves (wave 32 px x 64 co). K-step = 32 (72 steps).
// LDS: A[64][32] (4KB) + B[128][32] (8KB), x2 buffers = 24KB.
// Per k-step: each wave reg-loads 3x16B of the NEXT tile (issued before MFMA),
// ds_writes after MFMA, one barrier per step. XOR swizzle seg^=(row>>1)&3 on
// both write and read -> 2-way bank aliasing (free).
// ---------------------------------------------------------------------------
__global__ __launch_bounds__(256)
void conv_mfma_kernel(const short* __restrict__ up, const short* __restrict__ wt,
                      const float* __restrict__ bias, float* __restrict__ out)
{
    __shared__ short smem[2][6144];   // 12KB per buffer: A at bytes [0,4096), B at [4096,12288)
    const int t = threadIdx.x, w = t >> 6, l = t & 63;
    const int lr = l & 15, sg = l >> 4;
    const int pm0 = blockIdx.x * 64;
    const int bn0 = blockIdx.y * 128;

    // staging precompute: 12 issues of 16 rows x 64B, 3 per wave
    long gb[3]; int ldsoff[3]; int isA[3];
    #pragma unroll
    for (int i = 0; i < 3; ++i) {
        int j = w * 3 + i;
        int qa = l & 3;                 // global k-seg fetched by this lane
        if (j < 4) {
            int row = j * 16 + (l >> 2);
            isA[i] = 1;
            int p = pm0 + row; if (p >= kNP) p = kNP - 1;
            int oy = p / kOW, ox = p - oy * kOW;
            gb[i] = ((long)oy * 150 + ox) * kCO + qa * 8;
            ldsoff[i] = row * 64 + ((qa ^ ((row >> 1) & 3)) << 4);
        } else {
            int row = (j - 4) * 16 + (l >> 2);
            isA[i] = 0;
            gb[i] = (long)(bn0 + row) * 2304 + qa * 8;
            ldsoff[i] = 4096 + row * 64 + ((qa ^ ((row >> 1) & 3)) << 4);
        }
    }
    // fragment read offsets (swizzled)
    int aoff[2], boff[4];
    #pragma unroll
    for (int mi = 0; mi < 2; ++mi) {
        int r = (w >> 1) * 32 + mi * 16 + lr;
        aoff[mi] = r * 64 + ((sg ^ ((r >> 1) & 3)) << 4);
    }
    #pragma unroll
    for (int ni = 0; ni < 4; ++ni) {
        int r = (w & 1) * 64 + ni * 16 + lr;
        boff[ni] = 4096 + r * 64 + ((sg ^ ((r >> 1) & 3)) << 4);
    }

    f32x4 acc[2][4] = {};
    const int NT = 72;                  // 9 taps x 8 k-chunks of 32
    // prologue: stage step 0 (tap 0, c0 0) into buf 0
    {
        bf16x8 stg[3];
        #pragma unroll
        for (int i = 0; i < 3; ++i)
            stg[i] = isA[i] ? *(const bf16x8*)(up + gb[i])
                            : *(const bf16x8*)(wt + gb[i]);
        char* lb = (char*)&smem[0][0];
        #pragma unroll
        for (int i = 0; i < 3; ++i) *(bf16x8*)(lb + ldsoff[i]) = stg[i];
    }
    __syncthreads();

    for (int tt = 0; tt < NT; ++tt) {
        // issue next-step global loads FIRST (latency hides under MFMA below)
        bf16x8 nstg[3];
        if (tt + 1 < NT) {
            int tn = tt + 1;
            int tap = tn >> 3, c0 = (tn & 7) << 5;
            int ky = tap / 3, kx = tap - ky * 3;
            long ta = ((long)ky * 150 + kx) * kCO + c0;
            long tb = (long)tn * 32;
            #pragma unroll
            for (int i = 0; i < 3; ++i)
                nstg[i] = isA[i] ? *(const bf16x8*)(up + gb[i] + ta)
                                 : *(const bf16x8*)(wt + gb[i] + tb);
        }
        // compute current tile
        char* lb = (char*)&smem[tt & 1][0];
        bf16x8 a[2], b[4];
        #pragma unroll
        for (int mi = 0; mi < 2; ++mi) a[mi] = *(const bf16x8*)(lb + aoff[mi]);
        #pragma unroll
        for (int ni = 0; ni < 4; ++ni) b[ni] = *(const bf16x8*)(lb + boff[ni]);
        #pragma unroll
        for (int mi = 0; mi < 2; ++mi)
            #pragma unroll
            for (int ni = 0; ni < 4; ++ni)
                acc[mi][ni] = __builtin_amdgcn_mfma_f32_16x16x32_bf16(a[mi], b[ni], acc[mi][ni], 0, 0, 0);
        // write next tile into the other buffer
        if (tt + 1 < NT) {
            char* nb = (char*)&smem[(tt + 1) & 1][0];
            #pragma unroll
            for (int i = 0; i < 3; ++i) *(bf16x8*)(nb + ldsoff[i]) = nstg[i];
        }
        __syncthreads();
    }

    const int q = l >> 4;
    const int m0 = pm0 + (w >> 1) * 32;
    const int n0 = bn0 + (w & 1) * 64;
    #pragma unroll
    for (int mi = 0; mi < 2; ++mi)
        #pragma unroll
        for (int ni = 0; ni < 4; ++ni) {
            const int co = n0 + ni * 16 + lr;
            const float bv = bias[co];
            #pragma unroll
            for (int r = 0; r < 4; ++r) {
                int p = m0 + mi * 16 + q * 4 + r;
                if (p < kNP)
                    out[(long)co * kNP + p] = acc[mi][ni][r] + bv;
            }
        }
}

// partial column sums of pf over n
__global__ __launch_bounds__(256)
void colmean_kernel(const float* __restrict__ pf, float* __restrict__ colpart)
{
    int s = blockIdx.x, ch = blockIdx.y, o = threadIdx.x;
    int n0 = ch * 128, n1 = n0 + 128 > kN ? kN : n0 + 128;
    float a = 0.f;
    for (int n = n0; n < n1; ++n) a += pf[((long)s * kN + n) * kCO + o];
    colpart[ch * kS * kCO + s * kCO + o] = a;
}

// attn stage 1
__global__ __launch_bounds__(384)
void attn_part1(const float* __restrict__ colpart, const float* __restrict__ w1,
                float* __restrict__ partial)
{
    __shared__ float cm[128];
    int b = blockIdx.x, t = threadIdx.x;
    int c0 = b * 128;
    if (t < 128) {
        float a = 0.f;
        #pragma unroll
        for (int ch = 0; ch < 11; ++ch) a += colpart[ch * kS * kCO + c0 + t];
        cm[t] = a * (1.f / kN);
    }
    __syncthreads();
    float acc = 0.f;
    #pragma unroll 4
    for (int c = 0; c < 128; ++c) acc += cm[c] * w1[(long)(c0 + c) * kHID + t];
    partial[b * kHID + t] = acc;
}

// attn stage 2
__global__ __launch_bounds__(384)
void attn_part2(const float* __restrict__ partial, const float* __restrict__ b1,
                const float* __restrict__ w2, const float* __restrict__ b2,
                const float* __restrict__ ss, float* __restrict__ wfin)
{
    __shared__ float h[kHID];
    __shared__ float logits[8];
    int t = threadIdx.x;
    float acc = b1[t];
    #pragma unroll
    for (int b = 0; b < 12; ++b) acc += partial[b * kHID + t];
    h[t] = fmaxf(acc, 0.f);
    __syncthreads();
    if (t < kS) {
        float lg = b2[t];
        for (int j = 0; j < kHID; ++j) lg += h[j] * w2[j * kS + t];
        logits[t] = lg;
    }
    __syncthreads();
    if (t == 0) {
        float w[kS], mx = -1e30f, sum = 0.f;
        for (int s = 0; s < kS; ++s) mx = fmaxf(mx, logits[s]);
        for (int s = 0; s < kS; ++s) { w[s] = expf(logits[s] - mx); sum += w[s]; }
        for (int s = 0; s < kS; ++s) w[s] /= sum;
        mx = -1e30f;
        for (int s = 0; s < kS; ++s) { w[s] *= ss[s]; mx = fmaxf(mx, w[s]); }
        sum = 0.f;
        float e[kS];
        for (int s = 0; s < kS; ++s) { e[s] = expf(w[s] - mx); sum += e[s]; }
        for (int s = 0; s < kS; ++s) wfin[s] = e[s] / sum;
    }
}

// fused = sum_s wfin[s]*pf[s]; writes f32 fwd+rev and bf16 fwd+rev
__global__ __launch_bounds__(256)
void fuse_kernel(const float* __restrict__ pf, const float* __restrict__ wfin,
                 float* __restrict__ fused2, short* __restrict__ fusedb2)
{
    long idx = (long)blockIdx.x * 256 + threadIdx.x;
    if (idx >= (long)kN * kCO) return;
    float acc = 0.f;
    #pragma unroll
    for (int s = 0; s < kS; ++s) acc += wfin[s] * pf[(long)s * kN * kCO + idx];
    long n = idx / kCO; int c = (int)(idx % kCO);
    long ridx = (long)kN * kCO + (kN - 1 - n) * kCO + c;
    short bv = f2bf(acc);
    fused2[idx] = acc;
    fused2[ridx] = acc;
    fusedb2[idx] = bv;
    fusedb2[ridx] = bv;
}

// causal depthwise conv (K=4) + silu; writes f32 z2 and bf16 z2b
__global__ __launch_bounds__(256)
void dwconv_kernel(const float* __restrict__ zg2,
                   const float* __restrict__ wf, const float* __restrict__ bf,
                   const float* __restrict__ wb, const float* __restrict__ bb,
                   float* __restrict__ z2, short* __restrict__ z2b)
{
    long idx = (long)blockIdx.x * 256 + threadIdx.x;
    int dir = blockIdx.y;
    if (idx >= (long)kN * kDI) return;
    long n = idx >> 9; int i = (int)(idx & (kDI - 1));
    const float* zg = zg2 + (long)dir * kN * 2 * kDI;
    const float* w  = dir ? wb : wf;
    const float* b  = dir ? bb : bf;
    float acc = b[i];
    #pragma unroll
    for (int k = 0; k < 4; ++k) {
        long m = n - 3 + k;
        if (m >= 0) acc += w[k * kDI + i] * zg[m * 2 * kDI + i];
    }
    float sg = 1.f / (1.f + expf(-acc));
    float v = acc * sg;
    z2 [(long)dir * kN * kDI + idx] = v;
    z2b[(long)dir * kN * kDI + idx] = f2bf(v);
}

// delta = softplus(xp[:,32+i] + xp[:,544])
__global__ __launch_bounds__(256)
void delta_kernel(const float* __restrict__ xp2, float* __restrict__ delta2)
{
    long idx = (long)blockIdx.x * 256 + threadIdx.x;
    int dir = blockIdx.y;
    if (idx >= (long)kN * kDI) return;
    long n = idx >> 9; int i = (int)(idx & (kDI - 1));
    const float* xp = xp2 + (long)dir * kXPS + n * kXPW;
    float x = xp[2 * kDS + i] + xp[kXPW - 1];
    float sp = fmaxf(x, 0.f) + log1pf(expf(-fabsf(x)));
    delta2[(long)dir * kN * kDI + idx] = sp;
}

// ---- chunk-parallel scan: pass A ------------------------------------------
__global__ __launch_bounds__(256)
void scan_partA(const float* __restrict__ delta2, const float* __restrict__ z2,
                const float* __restrict__ xp2,
                const float* __restrict__ Alogf, const float* __restrict__ Alogb,
                float* __restrict__ chunkP, float* __restrict__ chunkH)
{
    int bx = blockIdx.x;
    int c  = blockIdx.y;
    int dir = bx >> 5, iblk = bx & 31;
    int t = threadIdx.x;
    int s = t & 15, il = t >> 4;
    int i = iblk * 16 + il;
    int gid = dir * 8192 + iblk * 256 + t;
    const float* delta = delta2 + (long)dir * kN * kDI;
    const float* z     = z2     + (long)dir * kN * kDI;
    const float* xp    = xp2    + (long)dir * kXPS;
    const float* Alog  = dir ? Alogb : Alogf;
    float A = expf(Alog[i * kDS + s]);
    int n0 = c * kCH, n1 = n0 + kCH; if (n1 > kN) n1 = kN;
    float h = 0.f, P = 1.f;
    for (int n = n0; n < n1; ++n) {
        float dlt = delta[(long)n * kDI + i];
        float zv  = z[(long)n * kDI + i];
        float Bv  = xp[(long)n * kXPW + s];
        float dA  = __expf(-dlt * A);
        h = dA * h + dlt * Bv * zv;
        P *= dA;
    }
    chunkP[(long)c * 16384 + gid] = P;
    chunkH[(long)c * 16384 + gid] = h;
}

// ---- pass B ----------------------------------------------------------------
__global__ __launch_bounds__(256)
void scan_partB(const float* __restrict__ chunkP, const float* __restrict__ chunkH,
                float* __restrict__ hin)
{
    int gid = blockIdx.x * 256 + threadIdx.x;
    float H = 0.f;
    for (int c = 0; c < kNC; ++c) {
        hin[(long)c * 16384 + gid] = H;
        H = chunkP[(long)c * 16384 + gid] * H + chunkH[(long)c * 16384 + gid];
    }
}

// ---- pass C ----------------------------------------------------------------
__global__ __launch_bounds__(256)
void scan_partC(const float* __restrict__ delta2, const float* __restrict__ z2,
                const float* __restrict__ xp2,
                const float* __restrict__ Df, const float* __restrict__ Db,
                const float* __restrict__ Alogf, const float* __restrict__ Alogb,
                const float* __restrict__ hin, float* __restrict__ ybuf2)
{
    int bx = blockIdx.x;
    int c  = blockIdx.y;
    int dir = bx >> 5, iblk = bx & 31;
    int t = threadIdx.x;
    int s = t & 15, il = t >> 4;
    int i = iblk * 16 + il;
    int gid = dir * 8192 + iblk * 256 + t;
    const float* delta = delta2 + (long)dir * kN * kDI;
    const float* z     = z2     + (long)dir * kN * kDI;
    const float* xp    = xp2    + (long)dir * kXPS;
    const float* D     = dir ? Db : Df;
    const float* Alog  = dir ? Alogb : Alogf;
    float* y           = ybuf2  + (long)dir * kN * kDI;
    float A  = expf(Alog[i * kDS + s]);
    float Dv = D[i];
    int n0 = c * kCH, n1 = n0 + kCH; if (n1 > kN) n1 = kN;
    float h = hin[(long)c * 16384 + gid];
    for (int n = n0; n < n1; ++n) {
        float dlt = delta[(long)n * kDI + i];
        float zv  = z[(long)n * kDI + i];
        float Bv  = xp[(long)n * kXPW + s];
        float Cv  = xp[(long)n * kXPW + kDS + s];
        float dA  = __expf(-dlt * A);
        h = dA * h + dlt * Bv * zv;
        float cc = h * Cv;
        cc += __shfl_xor(cc, 1, 16);
        cc += __shfl_xor(cc, 2, 16);
        cc += __shfl_xor(cc, 4, 16);
        cc += __shfl_xor(cc, 8, 16);
        if (s == 0) y[(long)n * kDI + i] = cc + Dv * zv;
    }
}

// ygb = bf16( y * silu(gate) )
__global__ __launch_bounds__(256)
void mulgate_kernel(const float* __restrict__ zg2, const float* __restrict__ ybuf2,
                    short* __restrict__ ygb)
{
    long idx = (long)blockIdx.x * 256 + threadIdx.x;
    int dir = blockIdx.y;
    if (idx >= (long)kN * kDI) return;
    long n = idx >> 9; int i = (int)(idx & (kDI - 1));
    float g = zg2[(long)dir * kN * 2 * kDI + n * 2 * kDI + kDI + i];
    float sg = 1.f / (1.f + expf(-g));
    float v = ybuf2[(long)dir * kN * kDI + idx] * g * sg;
    ygb[(long)dir * kN * kDI + idx] = f2bf(v);
}

// r = gemm_out + x; layernorm; write bf16 cat
__global__ __launch_bounds__(256)
void resid_ln_cat_kernel(const float* __restrict__ gt2, const float* __restrict__ x2,
                         const float* __restrict__ gf, const float* __restrict__ betf,
                         const float* __restrict__ gb, const float* __restrict__ betb,
                         short* __restrict__ catb)
{
    int n = blockIdx.x, dir = blockIdx.y, t = threadIdx.x;
    const float* gt = gt2 + ((long)dir * kN + n) * kCO;
    const float* x  = x2  + ((long)dir * kN + n) * kCO;
    const float* g  = dir ? gb : gf;
    const float* be = dir ? betb : betf;
    float r = gt[t] + x[t];
    float s1 = r, s2 = r * r;
    #pragma unroll
    for (int m = 32; m >= 1; m >>= 1) {
        s1 += __shfl_xor(s1, m, 64);
        s2 += __shfl_xor(s2, m, 64);
    }
    __shared__ float red[8];
    int w = t >> 6;
    if ((t & 63) == 0) { red[w] = s1; red[4 + w] = s2; }
    __syncthreads();
    float S1 = red[0] + red[1] + red[2] + red[3];
    float S2 = red[4] + red[5] + red[6] + red[7];
    float mu  = S1 * (1.f / kCO);
    float var = S2 * (1.f / kCO) - mu * mu;
    float inv = rsqrtf(var + 1e-5f);
    float v = g[t] * (r - mu) * inv + be[t];
    int row = dir ? (kN - 1 - n) : n;
    catb[(long)row * (2 * kCO) + dir * kCO + t] = f2bf(v);
}

// bilinear 4x upsample -> bf16 into zero-padded (150,150,256) interior
__global__ __launch_bounds__(256)
void upsample_kernel(const float* __restrict__ merged, short* __restrict__ up)
{
    int p = blockIdx.x;
    int oy = p / kOW, ox = p - oy * kOW;
    int c = threadIdx.x;
    float sy = (oy + 0.5f) * ((float)kHP / (float)kOH) - 0.5f;
    float sx = (ox + 0.5f) * ((float)kWP / (float)kOW) - 0.5f;
    int iy0 = (int)floorf(sy); float fy = sy - (float)iy0;
    int ix0 = (int)floorf(sx); float fx = sx - (float)ix0;
    float wy0 = 1.f - fy, wy1 = fy, wx0 = 1.f - fx, wx1 = fx;
    int iy1 = iy0 + 1, ix1 = ix0 + 1;
    if (iy0 < 0)       { iy0 = 0;       wy0 = 0.f; }
    if (iy1 > kHP - 1) { iy1 = kHP - 1; wy1 = 0.f; }
    if (ix0 < 0)       { ix0 = 0;       wx0 = 0.f; }
    if (ix1 > kWP - 1) { ix1 = kWP - 1; wx1 = 0.f; }
    float wys = wy0 + wy1; wy0 /= wys; wy1 /= wys;
    float wxs = wx0 + wx1; wx0 /= wxs; wx1 /= wxs;
    const float* M00 = merged + (long)(iy0 * kWP + ix0) * kCO;
    const float* M01 = merged + (long)(iy0 * kWP + ix1) * kCO;
    const float* M10 = merged + (long)(iy1 * kWP + ix0) * kCO;
    const float* M11 = merged + (long)(iy1 * kWP + ix1) * kCO;
    float v = wy0 * (wx0 * M00[c] + wx1 * M01[c]) + wy1 * (wx0 * M10[c] + wx1 * M11[c]);
    up[((long)(oy + 1) * 150 + (ox + 1)) * kCO + c] = f2bf(v);
}

extern "C" void kernel_launch(void* const* d_in, const int* in_sizes, int n_in,
                              void* d_out, int out_size, void* d_ws, size_t ws_size,
                              hipStream_t stream)
{
    (void)in_sizes; (void)n_in; (void)out_size; (void)ws_size;
    const float* features  = (const float*)d_in[0];
    const float* proj_w    = (const float*)d_in[1];
    const float* attn_w1   = (const float*)d_in[2];
    const float* attn_b1   = (const float*)d_in[3];
    const float* attn_w2   = (const float*)d_in[4];
    const float* attn_b2   = (const float*)d_in[5];
    const float* src_scale = (const float*)d_in[6];
    const float* f_in_w    = (const float*)d_in[7];
    const float* f_conv_w  = (const float*)d_in[8];
    const float* f_conv_b  = (const float*)d_in[9];
    const float* f_xp_w    = (const float*)d_in[10];
    const float* f_Alog    = (const float*)d_in[11];
    const float* f_D       = (const float*)d_in[12];
    const float* f_out_w   = (const float*)d_in[13];
    const float* f_ln_g    = (const float*)d_in[14];
    const float* f_ln_b    = (const float*)d_in[15];
    const float* b_in_w    = (const float*)d_in[16];
    const float* b_conv_w  = (const float*)d_in[17];
    const float* b_conv_b  = (const float*)d_in[18];
    const float* b_xp_w    = (const float*)d_in[19];
    const float* b_Alog    = (const float*)d_in[20];
    const float* b_D       = (const float*)d_in[21];
    const float* b_out_w   = (const float*)d_in[22];
    const float* b_ln_g    = (const float*)d_in[23];
    const float* b_ln_b    = (const float*)d_in[24];
    const float* merge_w   = (const float*)d_in[25];
    const float* co1_w     = (const float*)d_in[26];
    const float* co1_b     = (const float*)d_in[27];

    float* ws      = (float*)d_ws;
    float* outp    = (float*)d_out;
    float* pf      = ws + OFF_PF;
    float* colpart = ws + OFF_COLPART;
    float* wfin    = ws + OFF_WFIN;
    float* attnp   = ws + OFF_ATTNP;
    float* fused2  = ws + OFF_FUSED2;
    float* zg2     = ws + OFF_ZG;
    float* z2      = ws + OFF_Z;
    float* xp2     = ws + OFF_XP;
    float* delta2  = ws + OFF_DELTA;
    float* ybuf2   = ws + OFF_Y;
    float* gt2     = ws + OFF_GT;
    float* merged  = ws + OFF_MERGED;
    float* chunkP  = ws + OFF_SCANP;
    float* chunkH  = ws + OFF_SCANH;
    float* hin     = ws + OFF_HIN;
    short* featb   = (short*)(ws + OFF_FEATB);
    short* projwb  = (short*)(ws + OFF_PROJWB);
    short* in_wt   = (short*)(ws + OFF_INWT);
    short* xp_wt   = (short*)(ws + OFF_XPWT);
    short* out_wt  = (short*)(ws + OFF_OUTWT);
    short* mrg_wt  = (short*)(ws + OFF_MERGEWT);
    short* fusedb2 = (short*)(ws + OFF_FUSEDB);
    short* z2b     = (short*)(ws + OFF_Z2B);
    short* ygb     = (short*)(ws + OFF_YGB);
    short* catb    = (short*)(ws + OFF_CAT);
    short* upb     = (short*)(ws + OFF_UPB);
    short* wconvb  = (short*)(ws + OFF_WCONVB);

    // 0. bf16 casts for proj
    cast8_kernel<<<dim3(6161), 256, 0, stream>>>(features, featb, 1577088L);
    cast8_kernel<<<dim3(1152), 256, 0, stream>>>(proj_w, projwb, 294912L);
    // 1. pf[s] = feats[s] @ proj_w[s]^T   (bf16 MFMA)
    proj_mfma_kernel<<<dim3(22, 4, 6), 256, 0, stream>>>(featb, projwb, pf);
    // 2. weight transposes
    transpose_cast_kernel<<<dim3(8, 32, 2), 256, 0, stream>>>(f_in_w, b_in_w, in_wt, 256, 1024);
    transpose_cast_kernel<<<dim3(16, 18, 2), 256, 0, stream>>>(f_xp_w, b_xp_w, xp_wt, 512, 545);
    transpose_cast_kernel<<<dim3(16, 8, 1), 256, 0, stream>>>(merge_w, merge_w, mrg_wt, 512, 256);
    // 3. column sums + attention weights
    colmean_kernel<<<dim3(6, 11), 256, 0, stream>>>(pf, colpart);
    attn_part1<<<dim3(12), 384, 0, stream>>>(colpart, attn_w1, attnp);
    attn_part2<<<1, 384, 0, stream>>>(attnp, attn_b1, attn_w2, attn_b2, src_scale, wfin);
    // 4. fuse sources (+ reversed), f32 + bf16
    fuse_kernel<<<dim3(1369), 256, 0, stream>>>(pf, wfin, fused2, fusedb2);
    // 4b. out_w transpose (pf region now dead)
    transpose_cast_kernel<<<dim3(16, 8, 2), 256, 0, stream>>>(f_out_w, b_out_w, out_wt, 512, 256);
    // 5. zg = fused @ in_w  (MFMA)
    mfma_nt<<<dim3(22, 16, 2), 256, 0, stream>>>(
        fusedb2, (long)kN * kCO, in_wt, (long)2 * kDI * kCO,
        zg2, (long)kN * 2 * kDI, kN, 2 * kDI, kCO);
    // 6. causal dwconv + silu -> z2 f32 + z2b bf16
    dwconv_kernel<<<dim3(2738, 2), 256, 0, stream>>>(zg2, f_conv_w, f_conv_b,
                                                     b_conv_w, b_conv_b, z2, z2b);
    // 7. xp = z @ xp_w  (MFMA)
    mfma_nt<<<dim3(22, 9, 2), 256, 0, stream>>>(
        z2b, (long)kN * kDI, xp_wt, (long)kXPW * kDI,
        xp2, kXPS, kN, kXPW, kDI);
    // 8. delta
    delta_kernel<<<dim3(2738, 2), 256, 0, stream>>>(xp2, delta2);
    // 9. chunk-parallel selective scan
    scan_partA<<<dim3(64, kNC), 256, 0, stream>>>(delta2, z2, xp2, f_Alog, b_Alog,
                                                  chunkP, chunkH);
    scan_partB<<<dim3(64), 256, 0, stream>>>(chunkP, chunkH, hin);
    scan_partC<<<dim3(64, kNC), 256, 0, stream>>>(delta2, z2, xp2, f_D, b_D,
                                                  f_Alog, b_Alog, hin, ybuf2);
    // 10. ygb = bf16(y * silu(gate))
    mulgate_kernel<<<dim3(2738, 2), 256, 0, stream>>>(zg2, ybuf2, ygb);
    // 11. gt = yg @ out_w  (MFMA)
    mfma_nt<<<dim3(22, 4, 2), 256, 0, stream>>>(
        ygb, (long)kN * kDI, out_wt, (long)kCO * kDI,
        gt2, (long)kN * kCO, kN, kCO, kDI);
    // 12. residual + LN + cat (bf16)
    resid_ln_cat_kernel<<<dim3(1369, 2), 256, 0, stream>>>(gt2, fused2, f_ln_g, f_ln_b,
                                                           b_ln_g, b_ln_b, catb);
    // 13. merged = cat @ merge_w  (MFMA)
    mfma_nt<<<dim3(22, 4, 1), 256, 0, stream>>>(
        catb, 0, mrg_wt, 0,
        merged, 0, kN, kCO, 2 * kCO);
    // 14. conv weight -> bf16 transposed [cout][2304]
    transpose_cast_kernel<<<dim3(72, 8, 1), 256, 0, stream>>>(co1_w, co1_w, wconvb, 2304, 256);
    // 15. zero padded bf16 upsample buffer
    hipMemsetAsync(upb, 0, (size_t)150 * 150 * 256 * sizeof(short), stream);
    // 16. bilinear upsample -> bf16 padded interior
    upsample_kernel<<<dim3(kNP), 256, 0, stream>>>(merged, upb);
    // 17. 3x3 conv via bf16 MFMA (LDS dbuf), NCHW output + bias
    conv_mfma_kernel<<<dim3(343, 2), 256, 0, stream>>>(upb, wconvb, co1_b, outp);
}

// Round 6
// 316.052 us; speedup vs baseline: 5.5944x; 1.1489x over previous
//
#include <hip/hip_runtime.h>
#include <math.h>

// ---------------------------------------------------------------------------
// Upnet_v3 pipeline, round 5:
//  - proj: LDS-staged double-buffered MFMA GEMM staging DIRECTLY from f32
//    (cast fused into staging; cast8 passes deleted)
//  - mfma_nt (in/xp/out/merge): same LDS-dbuf template (bf16 sources)
//  - conv3x3 LDS-dbuf kernel unchanged (proven round 4)
// ---------------------------------------------------------------------------

namespace {
constexpr int kS   = 6;
constexpr int kHP  = 37;
constexpr int kWP  = 37;
constexpr int kN   = 1369;      // HP*WP
constexpr int kCIN = 1536;
constexpr int kCO  = 256;
constexpr int kDS  = 16;
constexpr int kDI  = 512;
constexpr int kHID = 384;
constexpr int kOH  = 148;
constexpr int kOW  = 148;
constexpr int kNP  = kOH * kOW; // 21904
constexpr int kXPW = 545;       // 2*DS + DI + 1
constexpr long kXPS = 746112;   // padded kN*kXPW per dir
constexpr int kNC  = 24;        // scan chunks
constexpr int kCH  = 58;        // chunk length (24*58 = 1392 >= 1369)

// ---- workspace ledger (f32 units, total <= 13,911,040 = 55.6 MB) ----------
constexpr long OFF_PF      = 0;         // pf (dead after fuse)
constexpr long OFF_Z2B     = 0;         // z2b bf16 (steps 6-9)
constexpr long OFF_YGB     = 0;         // ygb bf16 (steps 12-13)
constexpr long OFF_UPB     = 0;         // up_pad bf16 (steps 16+)
constexpr long OFF_SCANP   = 700928;
constexpr long OFF_SCANH   = 1094144;
constexpr long OFF_HIN     = 1487360;
constexpr long OFF_OUTWT   = 1880576;
constexpr long OFF_COLPART = 2102784;
constexpr long OFF_WFIN    = 2119680;
constexpr long OFF_ATTNP   = 2119696;
constexpr long OFF_INWT    = 2200000;
constexpr long OFF_FUSEDB  = 2462144;
constexpr long OFF_ZG      = 2820624;
constexpr long OFF_Z       = 5760000;
constexpr long OFF_WCONVB  = 6000000;
constexpr long OFF_XP      = 7161856;
constexpr long OFF_DELTA   = 8654080;
constexpr long OFF_Y       = 10055936;
constexpr long OFF_GT      = 11457792;
constexpr long OFF_XPWT    = 11457792;  // dead before gt2 is written
constexpr long OFF_FUSED2  = 12158720;
constexpr long OFF_CAT     = 12859648;
constexpr long OFF_MERGEWT = 13210112;
constexpr long OFF_MERGED  = 13560576;
} // namespace

typedef __attribute__((ext_vector_type(8))) short bf16x8;
typedef __attribute__((ext_vector_type(4))) float f32x4;

__device__ __forceinline__ short f2bf(float x) {
    unsigned u = __builtin_bit_cast(unsigned, x);
    unsigned r = u + 0x7fffu + ((u >> 16) & 1u);
    return (short)(r >> 16);
}

__device__ __forceinline__ bf16x8 cvt8(float4 x, float4 y) {
    union { short s[8]; bf16x8 v; } u;
    u.s[0] = f2bf(x.x); u.s[1] = f2bf(x.y); u.s[2] = f2bf(x.z); u.s[3] = f2bf(x.w);
    u.s[4] = f2bf(y.x); u.s[5] = f2bf(y.y); u.s[6] = f2bf(y.z); u.s[7] = f2bf(y.w);
    return u.v;
}

// tiled transpose+cast: w (K x N f32) -> wt (N x K bf16)
__global__ __launch_bounds__(256)
void transpose_cast_kernel(const float* __restrict__ w0, const float* __restrict__ w1,
                           short* __restrict__ wt, int K, int N)
{
    __shared__ float tile[32][33];
    int dir = blockIdx.z;
    const float* w = dir ? w1 : w0;
    short* o = wt + (long)dir * K * N;
    int k0 = blockIdx.x * 32, n0 = blockIdx.y * 32;
    int tx = threadIdx.x & 31, ty = threadIdx.x >> 5; // 32 x 8
    #pragma unroll
    for (int r = 0; r < 32; r += 8) {
        int k = k0 + ty + r, n = n0 + tx;
        tile[ty + r][tx] = (k < K && n < N) ? w[(long)k * N + n] : 0.f;
    }
    __syncthreads();
    #pragma unroll
    for (int r = 0; r < 32; r += 8) {
        int n = n0 + ty + r, k = k0 + tx;
        if (n < N && k < K) o[(long)n * K + k] = f2bf(tile[tx][ty + r]);
    }
}

// ---------------------------------------------------------------------------
// generic bf16 MFMA GEMM, NT form, LDS double-buffered (conv-proven template).
// Block 64M x 64N, 4 waves (wave 32x32). K-step 32. LDS 2 x 8KB.
// Per step: thread stages 1 A-seg + 1 B-seg (16B each), issued BEFORE the
// MFMAs of the current step, ds_written after. XOR swizzle on write+read.
// ---------------------------------------------------------------------------
__global__ __launch_bounds__(256)
void mfma_nt(const short* __restrict__ A, long sA,
             const short* __restrict__ B, long sB,
             float* __restrict__ C, long sC,
             int M, int N, int K)
{
    __shared__ short smem[2][4096];  // per buf: A bytes [0,4096), B [4096,8192)
    const int bz = blockIdx.z;
    const short* Ab = A + (long)bz * sA;
    const short* Bb = B + (long)bz * sB;
    float* Cb = C + (long)bz * sC;
    const int t = threadIdx.x, w = t >> 6, l = t & 63;
    const int lr = l & 15, sg = l >> 4;
    const int m0 = blockIdx.x * 64, n0 = blockIdx.y * 64;

    const int row = t >> 2, qa = t & 3;
    int am = m0 + row; if (am >= M) am = M - 1;
    int bn = n0 + row; if (bn >= N) bn = N - 1;
    const long ga = (long)am * K + qa * 8;
    const long gb = (long)bn * K + qa * 8;
    const int woffA = row * 64 + ((qa ^ ((row >> 1) & 3)) << 4);
    const int woffB = 4096 + woffA;

    int aoff[2], boff[2];
    #pragma unroll
    for (int mi = 0; mi < 2; ++mi) {
        int r = (w >> 1) * 32 + mi * 16 + lr;
        aoff[mi] = r * 64 + ((sg ^ ((r >> 1) & 3)) << 4);
    }
    #pragma unroll
    for (int ni = 0; ni < 2; ++ni) {
        int r = (w & 1) * 32 + ni * 16 + lr;
        boff[ni] = 4096 + r * 64 + ((sg ^ ((r >> 1) & 3)) << 4);
    }

    f32x4 acc[2][2] = {};
    const int NT = K >> 5;
    {
        bf16x8 sa = *(const bf16x8*)(Ab + ga);
        bf16x8 sb = *(const bf16x8*)(Bb + gb);
        char* lb = (char*)&smem[0][0];
        *(bf16x8*)(lb + woffA) = sa;
        *(bf16x8*)(lb + woffB) = sb;
    }
    __syncthreads();
    for (int tt = 0; tt < NT; ++tt) {
        bf16x8 nsa, nsb;
        if (tt + 1 < NT) {
            long o = (long)(tt + 1) * 32;
            nsa = *(const bf16x8*)(Ab + ga + o);
            nsb = *(const bf16x8*)(Bb + gb + o);
        }
        char* lb = (char*)&smem[tt & 1][0];
        bf16x8 a[2], b[2];
        #pragma unroll
        for (int mi = 0; mi < 2; ++mi) a[mi] = *(const bf16x8*)(lb + aoff[mi]);
        #pragma unroll
        for (int ni = 0; ni < 2; ++ni) b[ni] = *(const bf16x8*)(lb + boff[ni]);
        #pragma unroll
        for (int mi = 0; mi < 2; ++mi)
            #pragma unroll
            for (int ni = 0; ni < 2; ++ni)
                acc[mi][ni] = __builtin_amdgcn_mfma_f32_16x16x32_bf16(a[mi], b[ni], acc[mi][ni], 0, 0, 0);
        if (tt + 1 < NT) {
            char* nb = (char*)&smem[(tt + 1) & 1][0];
            *(bf16x8*)(nb + woffA) = nsa;
            *(bf16x8*)(nb + woffB) = nsb;
        }
        __syncthreads();
    }
    const int q = l >> 4;
    const int wm0 = m0 + (w >> 1) * 32, wn0 = n0 + (w & 1) * 32;
    #pragma unroll
    for (int mi = 0; mi < 2; ++mi)
        #pragma unroll
        for (int ni = 0; ni < 2; ++ni)
            #pragma unroll
            for (int r = 0; r < 4; ++r) {
                int m = wm0 + mi * 16 + q * 4 + r;
                int n = wn0 + ni * 16 + lr;
                if (m < M && n < N)
                    Cb[(long)m * N + n] = acc[mi][ni][r];
            }
}

// ---------------------------------------------------------------------------
// proj MFMA: LDS-dbuf, staging DIRECTLY from f32 features/proj_w (cast fused).
// pf[s][m][n] = sum_k feat[s][m][k] * proj_w[s][n][k]. Block 64x64, 4 waves.
// ---------------------------------------------------------------------------
__global__ __launch_bounds__(256)
void proj_mfma_kernel(const float* __restrict__ Af, const float* __restrict__ Bf,
                      float* __restrict__ pf)
{
    __shared__ short smem[2][4096];
    const int s = blockIdx.z;
    const float* A = Af + (long)s * kN * kCIN;
    const float* B = Bf + (long)s * kCO * kCIN;
    float* C = pf + (long)s * kN * kCO;
    const int t = threadIdx.x, w = t >> 6, l = t & 63;
    const int lr = l & 15, sg = l >> 4;
    const int m0 = blockIdx.x * 64, n0 = blockIdx.y * 64;

    const int row = t >> 2, qa = t & 3;
    int am = m0 + row; if (am >= kN) am = kN - 1;
    const long ga = (long)am * kCIN + qa * 8;
    const long gb = (long)(n0 + row) * kCIN + qa * 8;
    const int woffA = row * 64 + ((qa ^ ((row >> 1) & 3)) << 4);
    const int woffB = 4096 + woffA;

    int aoff[2], boff[2];
    #pragma unroll
    for (int mi = 0; mi < 2; ++mi) {
        int r = (w >> 1) * 32 + mi * 16 + lr;
        aoff[mi] = r * 64 + ((sg ^ ((r >> 1) & 3)) << 4);
    }
    #pragma unroll
    for (int ni = 0; ni < 2; ++ni) {
        int r = (w & 1) * 32 + ni * 16 + lr;
        boff[ni] = 4096 + r * 64 + ((sg ^ ((r >> 1) & 3)) << 4);
    }

    f32x4 acc[2][2] = {};
    const int NT = kCIN >> 5;   // 48
    {
        float4 a0 = *(const float4*)(A + ga), a1 = *(const float4*)(A + ga + 4);
        float4 b0 = *(const float4*)(B + gb), b1 = *(const float4*)(B + gb + 4);
        char* lb = (char*)&smem[0][0];
        *(bf16x8*)(lb + woffA) = cvt8(a0, a1);
        *(bf16x8*)(lb + woffB) = cvt8(b0, b1);
    }
    __syncthreads();
    for (int tt = 0; tt < NT; ++tt) {
        float4 a0, a1, b0, b1;
        if (tt + 1 < NT) {
            long o = (long)(tt + 1) * 32;
            a0 = *(const float4*)(A + ga + o);     a1 = *(const float4*)(A + ga + o + 4);
            b0 = *(const float4*)(B + gb + o);     b1 = *(const float4*)(B + gb + o + 4);
        }
        char* lb = (char*)&smem[tt & 1][0];
        bf16x8 a[2], b[2];
        #pragma unroll
        for (int mi = 0; mi < 2; ++mi) a[mi] = *(const bf16x8*)(lb + aoff[mi]);
        #pragma unroll
        for (int ni = 0; ni < 2; ++ni) b[ni] = *(const bf16x8*)(lb + boff[ni]);
        #pragma unroll
        for (int mi = 0; mi < 2; ++mi)
            #pragma unroll
            for (int ni = 0; ni < 2; ++ni)
                acc[mi][ni] = __builtin_amdgcn_mfma_f32_16x16x32_bf16(a[mi], b[ni], acc[mi][ni], 0, 0, 0);
        if (tt + 1 < NT) {
            char* nb = (char*)&smem[(tt + 1) & 1][0];
            *(bf16x8*)(nb + woffA) = cvt8(a0, a1);
            *(bf16x8*)(nb + woffB) = cvt8(b0, b1);
        }
        __syncthreads();
    }
    const int q = l >> 4;
    const int wm0 = m0 + (w >> 1) * 32, wn0 = n0 + (w & 1) * 32;
    #pragma unroll
    for (int mi = 0; mi < 2; ++mi)
        #pragma unroll
        for (int ni = 0; ni < 2; ++ni)
            #pragma unroll
            for (int r = 0; r < 4; ++r) {
                int m = wm0 + mi * 16 + q * 4 + r;
                if (m < kN)
                    C[(long)m * kCO + wn0 + ni * 16 + lr] = acc[mi][ni][r];
            }
}

// ---------------------------------------------------------------------------
// conv3x3 MFMA, LDS-staged double-buffered (unchanged from round 4)
// ---------------------------------------------------------------------------
__global__ __launch_bounds__(256)
void conv_mfma_kernel(const short* __restrict__ up, const short* __restrict__ wt,
                      const float* __restrict__ bias, float* __restrict__ out)
{
    __shared__ short smem[2][6144];   // 12KB per buffer: A [0,4096), B [4096,12288)
    const int t = threadIdx.x, w = t >> 6, l = t & 63;
    const int lr = l & 15, sg = l >> 4;
    const int pm0 = blockIdx.x * 64;
    const int bn0 = blockIdx.y * 128;

    long gb[3]; int ldsoff[3]; int isA[3];
    #pragma unroll
    for (int i = 0; i < 3; ++i) {
        int j = w * 3 + i;
        int qa = l & 3;
        if (j < 4) {
            int row = j * 16 + (l >> 2);
            isA[i] = 1;
            int p = pm0 + row; if (p >= kNP) p = kNP - 1;
            int oy = p / kOW, ox = p - oy * kOW;
            gb[i] = ((long)oy * 150 + ox) * kCO + qa * 8;
            ldsoff[i] = row * 64 + ((qa ^ ((row >> 1) & 3)) << 4);
        } else {
            int row = (j - 4) * 16 + (l >> 2);
            isA[i] = 0;
            gb[i] = (long)(bn0 + row) * 2304 + qa * 8;
            ldsoff[i] = 4096 + row * 64 + ((qa ^ ((row >> 1) & 3)) << 4);
        }
    }
    int aoff[2], boff[4];
    #pragma unroll
    for (int mi = 0; mi < 2; ++mi) {
        int r = (w >> 1) * 32 + mi * 16 + lr;
        aoff[mi] = r * 64 + ((sg ^ ((r >> 1) & 3)) << 4);
    }
    #pragma unroll
    for (int ni = 0; ni < 4; ++ni) {
        int r = (w & 1) * 64 + ni * 16 + lr;
        boff[ni] = 4096 + r * 64 + ((sg ^ ((r >> 1) & 3)) << 4);
    }

    f32x4 acc[2][4] = {};
    const int NT = 72;
    {
        bf16x8 stg[3];
        #pragma unroll
        for (int i = 0; i < 3; ++i)
            stg[i] = isA[i] ? *(const bf16x8*)(up + gb[i])
                            : *(const bf16x8*)(wt + gb[i]);
        char* lb = (char*)&smem[0][0];
        #pragma unroll
        for (int i = 0; i < 3; ++i) *(bf16x8*)(lb + ldsoff[i]) = stg[i];
    }
    __syncthreads();

    for (int tt = 0; tt < NT; ++tt) {
        bf16x8 nstg[3];
        if (tt + 1 < NT) {
            int tn = tt + 1;
            int tap = tn >> 3, c0 = (tn & 7) << 5;
            int ky = tap / 3, kx = tap - ky * 3;
            long ta = ((long)ky * 150 + kx) * kCO + c0;
            long tb = (long)tn * 32;
            #pragma unroll
            for (int i = 0; i < 3; ++i)
                nstg[i] = isA[i] ? *(const bf16x8*)(up + gb[i] + ta)
                                 : *(const bf16x8*)(wt + gb[i] + tb);
        }
        char* lb = (char*)&smem[tt & 1][0];
        bf16x8 a[2], b[4];
        #pragma unroll
        for (int mi = 0; mi < 2; ++mi) a[mi] = *(const bf16x8*)(lb + aoff[mi]);
        #pragma unroll
        for (int ni = 0; ni < 4; ++ni) b[ni] = *(const bf16x8*)(lb + boff[ni]);
        #pragma unroll
        for (int mi = 0; mi < 2; ++mi)
            #pragma unroll
            for (int ni = 0; ni < 4; ++ni)
                acc[mi][ni] = __builtin_amdgcn_mfma_f32_16x16x32_bf16(a[mi], b[ni], acc[mi][ni], 0, 0, 0);
        if (tt + 1 < NT) {
            char* nb = (char*)&smem[(tt + 1) & 1][0];
            #pragma unroll
            for (int i = 0; i < 3; ++i) *(bf16x8*)(nb + ldsoff[i]) = nstg[i];
        }
        __syncthreads();
    }

    const int q = l >> 4;
    const int m0 = pm0 + (w >> 1) * 32;
    const int n0 = bn0 + (w & 1) * 64;
    #pragma unroll
    for (int mi = 0; mi < 2; ++mi)
        #pragma unroll
        for (int ni = 0; ni < 4; ++ni) {
            const int co = n0 + ni * 16 + lr;
            const float bv = bias[co];
            #pragma unroll
            for (int r = 0; r < 4; ++r) {
                int p = m0 + mi * 16 + q * 4 + r;
                if (p < kNP)
                    out[(long)co * kNP + p] = acc[mi][ni][r] + bv;
            }
        }
}

// partial column sums of pf over n
__global__ __launch_bounds__(256)
void colmean_kernel(const float* __restrict__ pf, float* __restrict__ colpart)
{
    int s = blockIdx.x, ch = blockIdx.y, o = threadIdx.x;
    int n0 = ch * 128, n1 = n0 + 128 > kN ? kN : n0 + 128;
    float a = 0.f;
    for (int n = n0; n < n1; ++n) a += pf[((long)s * kN + n) * kCO + o];
    colpart[ch * kS * kCO + s * kCO + o] = a;
}

// attn stage 1
__global__ __launch_bounds__(384)
void attn_part1(const float* __restrict__ colpart, const float* __restrict__ w1,
                float* __restrict__ partial)
{
    __shared__ float cm[128];
    int b = blockIdx.x, t = threadIdx.x;
    int c0 = b * 128;
    if (t < 128) {
        float a = 0.f;
        #pragma unroll
        for (int ch = 0; ch < 11; ++ch) a += colpart[ch * kS * kCO + c0 + t];
        cm[t] = a * (1.f / kN);
    }
    __syncthreads();
    float acc = 0.f;
    #pragma unroll 4
    for (int c = 0; c < 128; ++c) acc += cm[c] * w1[(long)(c0 + c) * kHID + t];
    partial[b * kHID + t] = acc;
}

// attn stage 2
__global__ __launch_bounds__(384)
void attn_part2(const float* __restrict__ partial, const float* __restrict__ b1,
                const float* __restrict__ w2, const float* __restrict__ b2,
                const float* __restrict__ ss, float* __restrict__ wfin)
{
    __shared__ float h[kHID];
    __shared__ float logits[8];
    int t = threadIdx.x;
    float acc = b1[t];
    #pragma unroll
    for (int b = 0; b < 12; ++b) acc += partial[b * kHID + t];
    h[t] = fmaxf(acc, 0.f);
    __syncthreads();
    if (t < kS) {
        float lg = b2[t];
        for (int j = 0; j < kHID; ++j) lg += h[j] * w2[j * kS + t];
        logits[t] = lg;
    }
    __syncthreads();
    if (t == 0) {
        float w[kS], mx = -1e30f, sum = 0.f;
        for (int s = 0; s < kS; ++s) mx = fmaxf(mx, logits[s]);
        for (int s = 0; s < kS; ++s) { w[s] = expf(logits[s] - mx); sum += w[s]; }
        for (int s = 0; s < kS; ++s) w[s] /= sum;
        mx = -1e30f;
        for (int s = 0; s < kS; ++s) { w[s] *= ss[s]; mx = fmaxf(mx, w[s]); }
        sum = 0.f;
        float e[kS];
        for (int s = 0; s < kS; ++s) { e[s] = expf(w[s] - mx); sum += e[s]; }
        for (int s = 0; s < kS; ++s) wfin[s] = e[s] / sum;
    }
}

// fused = sum_s wfin[s]*pf[s]; writes f32 fwd+rev and bf16 fwd+rev
__global__ __launch_bounds__(256)
void fuse_kernel(const float* __restrict__ pf, const float* __restrict__ wfin,
                 float* __restrict__ fused2, short* __restrict__ fusedb2)
{
    long idx = (long)blockIdx.x * 256 + threadIdx.x;
    if (idx >= (long)kN * kCO) return;
    float acc = 0.f;
    #pragma unroll
    for (int s = 0; s < kS; ++s) acc += wfin[s] * pf[(long)s * kN * kCO + idx];
    long n = idx / kCO; int c = (int)(idx % kCO);
    long ridx = (long)kN * kCO + (kN - 1 - n) * kCO + c;
    short bv = f2bf(acc);
    fused2[idx] = acc;
    fused2[ridx] = acc;
    fusedb2[idx] = bv;
    fusedb2[ridx] = bv;
}

// causal depthwise conv (K=4) + silu; writes f32 z2 and bf16 z2b
__global__ __launch_bounds__(256)
void dwconv_kernel(const float* __restrict__ zg2,
                   const float* __restrict__ wf, const float* __restrict__ bf,
                   const float* __restrict__ wb, const float* __restrict__ bb,
                   float* __restrict__ z2, short* __restrict__ z2b)
{
    long idx = (long)blockIdx.x * 256 + threadIdx.x;
    int dir = blockIdx.y;
    if (idx >= (long)kN * kDI) return;
    long n = idx >> 9; int i = (int)(idx & (kDI - 1));
    const float* zg = zg2 + (long)dir * kN * 2 * kDI;
    const float* w  = dir ? wb : wf;
    const float* b  = dir ? bb : bf;
    float acc = b[i];
    #pragma unroll
    for (int k = 0; k < 4; ++k) {
        long m = n - 3 + k;
        if (m >= 0) acc += w[k * kDI + i] * zg[m * 2 * kDI + i];
    }
    float sg = 1.f / (1.f + expf(-acc));
    float v = acc * sg;
    z2 [(long)dir * kN * kDI + idx] = v;
    z2b[(long)dir * kN * kDI + idx] = f2bf(v);
}

// delta = softplus(xp[:,32+i] + xp[:,544])
__global__ __launch_bounds__(256)
void delta_kernel(const float* __restrict__ xp2, float* __restrict__ delta2)
{
    long idx = (long)blockIdx.x * 256 + threadIdx.x;
    int dir = blockIdx.y;
    if (idx >= (long)kN * kDI) return;
    long n = idx >> 9; int i = (int)(idx & (kDI - 1));
    const float* xp = xp2 + (long)dir * kXPS + n * kXPW;
    float x = xp[2 * kDS + i] + xp[kXPW - 1];
    float sp = fmaxf(x, 0.f) + log1pf(expf(-fabsf(x)));
    delta2[(long)dir * kN * kDI + idx] = sp;
}

// ---- chunk-parallel scan: pass A ------------------------------------------
__global__ __launch_bounds__(256)
void scan_partA(const float* __restrict__ delta2, const float* __restrict__ z2,
                const float* __restrict__ xp2,
                const float* __restrict__ Alogf, const float* __restrict__ Alogb,
                float* __restrict__ chunkP, float* __restrict__ chunkH)
{
    int bx = blockIdx.x;
    int c  = blockIdx.y;
    int dir = bx >> 5, iblk = bx & 31;
    int t = threadIdx.x;
    int s = t & 15, il = t >> 4;
    int i = iblk * 16 + il;
    int gid = dir * 8192 + iblk * 256 + t;
    const float* delta = delta2 + (long)dir * kN * kDI;
    const float* z     = z2     + (long)dir * kN * kDI;
    const float* xp    = xp2    + (long)dir * kXPS;
    const float* Alog  = dir ? Alogb : Alogf;
    float A = expf(Alog[i * kDS + s]);
    int n0 = c * kCH, n1 = n0 + kCH; if (n1 > kN) n1 = kN;
    float h = 0.f, P = 1.f;
    for (int n = n0; n < n1; ++n) {
        float dlt = delta[(long)n * kDI + i];
        float zv  = z[(long)n * kDI + i];
        float Bv  = xp[(long)n * kXPW + s];
        float dA  = __expf(-dlt * A);
        h = dA * h + dlt * Bv * zv;
        P *= dA;
    }
    chunkP[(long)c * 16384 + gid] = P;
    chunkH[(long)c * 16384 + gid] = h;
}

// ---- pass B ----------------------------------------------------------------
__global__ __launch_bounds__(256)
void scan_partB(const float* __restrict__ chunkP, const float* __restrict__ chunkH,
                float* __restrict__ hin)
{
    int gid = blockIdx.x * 256 + threadIdx.x;
    float H = 0.f;
    for (int c = 0; c < kNC; ++c) {
        hin[(long)c * 16384 + gid] = H;
        H = chunkP[(long)c * 16384 + gid] * H + chunkH[(long)c * 16384 + gid];
    }
}

// ---- pass C ----------------------------------------------------------------
__global__ __launch_bounds__(256)
void scan_partC(const float* __restrict__ delta2, const float* __restrict__ z2,
                const float* __restrict__ xp2,
                const float* __restrict__ Df, const float* __restrict__ Db,
                const float* __restrict__ Alogf, const float* __restrict__ Alogb,
                const float* __restrict__ hin, float* __restrict__ ybuf2)
{
    int bx = blockIdx.x;
    int c  = blockIdx.y;
    int dir = bx >> 5, iblk = bx & 31;
    int t = threadIdx.x;
    int s = t & 15, il = t >> 4;
    int i = iblk * 16 + il;
    int gid = dir * 8192 + iblk * 256 + t;
    const float* delta = delta2 + (long)dir * kN * kDI;
    const float* z     = z2     + (long)dir * kN * kDI;
    const float* xp    = xp2    + (long)dir * kXPS;
    const float* D     = dir ? Db : Df;
    const float* Alog  = dir ? Alogb : Alogf;
    float* y           = ybuf2  + (long)dir * kN * kDI;
    float A  = expf(Alog[i * kDS + s]);
    float Dv = D[i];
    int n0 = c * kCH, n1 = n0 + kCH; if (n1 > kN) n1 = kN;
    float h = hin[(long)c * 16384 + gid];
    for (int n = n0; n < n1; ++n) {
        float dlt = delta[(long)n * kDI + i];
        float zv  = z[(long)n * kDI + i];
        float Bv  = xp[(long)n * kXPW + s];
        float Cv  = xp[(long)n * kXPW + kDS + s];
        float dA  = __expf(-dlt * A);
        h = dA * h + dlt * Bv * zv;
        float cc = h * Cv;
        cc += __shfl_xor(cc, 1, 16);
        cc += __shfl_xor(cc, 2, 16);
        cc += __shfl_xor(cc, 4, 16);
        cc += __shfl_xor(cc, 8, 16);
        if (s == 0) y[(long)n * kDI + i] = cc + Dv * zv;
    }
}

// ygb = bf16( y * silu(gate) )
__global__ __launch_bounds__(256)
void mulgate_kernel(const float* __restrict__ zg2, const float* __restrict__ ybuf2,
                    short* __restrict__ ygb)
{
    long idx = (long)blockIdx.x * 256 + threadIdx.x;
    int dir = blockIdx.y;
    if (idx >= (long)kN * kDI) return;
    long n = idx >> 9; int i = (int)(idx & (kDI - 1));
    float g = zg2[(long)dir * kN * 2 * kDI + n * 2 * kDI + kDI + i];
    float sg = 1.f / (1.f + expf(-g));
    float v = ybuf2[(long)dir * kN * kDI + idx] * g * sg;
    ygb[(long)dir * kN * kDI + idx] = f2bf(v);
}

// r = gemm_out + x; layernorm; write bf16 cat
__global__ __launch_bounds__(256)
void resid_ln_cat_kernel(const float* __restrict__ gt2, const float* __restrict__ x2,
                         const float* __restrict__ gf, const float* __restrict__ betf,
                         const float* __restrict__ gb, const float* __restrict__ betb,
                         short* __restrict__ catb)
{
    int n = blockIdx.x, dir = blockIdx.y, t = threadIdx.x;
    const float* gt = gt2 + ((long)dir * kN + n) * kCO;
    const float* x  = x2  + ((long)dir * kN + n) * kCO;
    const float* g  = dir ? gb : gf;
    const float* be = dir ? betb : betf;
    float r = gt[t] + x[t];
    float s1 = r, s2 = r * r;
    #pragma unroll
    for (int m = 32; m >= 1; m >>= 1) {
        s1 += __shfl_xor(s1, m, 64);
        s2 += __shfl_xor(s2, m, 64);
    }
    __shared__ float red[8];
    int w = t >> 6;
    if ((t & 63) == 0) { red[w] = s1; red[4 + w] = s2; }
    __syncthreads();
    float S1 = red[0] + red[1] + red[2] + red[3];
    float S2 = red[4] + red[5] + red[6] + red[7];
    float mu  = S1 * (1.f / kCO);
    float var = S2 * (1.f / kCO) - mu * mu;
    float inv = rsqrtf(var + 1e-5f);
    float v = g[t] * (r - mu) * inv + be[t];
    int row = dir ? (kN - 1 - n) : n;
    catb[(long)row * (2 * kCO) + dir * kCO + t] = f2bf(v);
}

// bilinear 4x upsample -> bf16 into zero-padded (150,150,256) interior
__global__ __launch_bounds__(256)
void upsample_kernel(const float* __restrict__ merged, short* __restrict__ up)
{
    int p = blockIdx.x;
    int oy = p / kOW, ox = p - oy * kOW;
    int c = threadIdx.x;
    float sy = (oy + 0.5f) * ((float)kHP / (float)kOH) - 0.5f;
    float sx = (ox + 0.5f) * ((float)kWP / (float)kOW) - 0.5f;
    int iy0 = (int)floorf(sy); float fy = sy - (float)iy0;
    int ix0 = (int)floorf(sx); float fx = sx - (float)ix0;
    float wy0 = 1.f - fy, wy1 = fy, wx0 = 1.f - fx, wx1 = fx;
    int iy1 = iy0 + 1, ix1 = ix0 + 1;
    if (iy0 < 0)       { iy0 = 0;       wy0 = 0.f; }
    if (iy1 > kHP - 1) { iy1 = kHP - 1; wy1 = 0.f; }
    if (ix0 < 0)       { ix0 = 0;       wx0 = 0.f; }
    if (ix1 > kWP - 1) { ix1 = kWP - 1; wx1 = 0.f; }
    float wys = wy0 + wy1; wy0 /= wys; wy1 /= wys;
    float wxs = wx0 + wx1; wx0 /= wxs; wx1 /= wxs;
    const float* M00 = merged + (long)(iy0 * kWP + ix0) * kCO;
    const float* M01 = merged + (long)(iy0 * kWP + ix1) * kCO;
    const float* M10 = merged + (long)(iy1 * kWP + ix0) * kCO;
    const float* M11 = merged + (long)(iy1 * kWP + ix1) * kCO;
    float v = wy0 * (wx0 * M00[c] + wx1 * M01[c]) + wy1 * (wx0 * M10[c] + wx1 * M11[c]);
    up[((long)(oy + 1) * 150 + (ox + 1)) * kCO + c] = f2bf(v);
}

extern "C" void kernel_launch(void* const* d_in, const int* in_sizes, int n_in,
                              void* d_out, int out_size, void* d_ws, size_t ws_size,
                              hipStream_t stream)
{
    (void)in_sizes; (void)n_in; (void)out_size; (void)ws_size;
    const float* features  = (const float*)d_in[0];
    const float* proj_w    = (const float*)d_in[1];
    const float* attn_w1   = (const float*)d_in[2];
    const float* attn_b1   = (const float*)d_in[3];
    const float* attn_w2   = (const float*)d_in[4];
    const float* attn_b2   = (const float*)d_in[5];
    const float* src_scale = (const float*)d_in[6];
    const float* f_in_w    = (const float*)d_in[7];
    const float* f_conv_w  = (const float*)d_in[8];
    const float* f_conv_b  = (const float*)d_in[9];
    const float* f_xp_w    = (const float*)d_in[10];
    const float* f_Alog    = (const float*)d_in[11];
    const float* f_D       = (const float*)d_in[12];
    const float* f_out_w   = (const float*)d_in[13];
    const float* f_ln_g    = (const float*)d_in[14];
    const float* f_ln_b    = (const float*)d_in[15];
    const float* b_in_w    = (const float*)d_in[16];
    const float* b_conv_w  = (const float*)d_in[17];
    const float* b_conv_b  = (const float*)d_in[18];
    const float* b_xp_w    = (const float*)d_in[19];
    const float* b_Alog    = (const float*)d_in[20];
    const float* b_D       = (const float*)d_in[21];
    const float* b_out_w   = (const float*)d_in[22];
    const float* b_ln_g    = (const float*)d_in[23];
    const float* b_ln_b    = (const float*)d_in[24];
    const float* merge_w   = (const float*)d_in[25];
    const float* co1_w     = (const float*)d_in[26];
    const float* co1_b     = (const float*)d_in[27];

    float* ws      = (float*)d_ws;
    float* outp    = (float*)d_out;
    float* pf      = ws + OFF_PF;
    float* colpart = ws + OFF_COLPART;
    float* wfin    = ws + OFF_WFIN;
    float* attnp   = ws + OFF_ATTNP;
    float* fused2  = ws + OFF_FUSED2;
    float* zg2     = ws + OFF_ZG;
    float* z2      = ws + OFF_Z;
    float* xp2     = ws + OFF_XP;
    float* delta2  = ws + OFF_DELTA;
    float* ybuf2   = ws + OFF_Y;
    float* gt2     = ws + OFF_GT;
    float* merged  = ws + OFF_MERGED;
    float* chunkP  = ws + OFF_SCANP;
    float* chunkH  = ws + OFF_SCANH;
    float* hin     = ws + OFF_HIN;
    short* in_wt   = (short*)(ws + OFF_INWT);
    short* xp_wt   = (short*)(ws + OFF_XPWT);
    short* out_wt  = (short*)(ws + OFF_OUTWT);
    short* mrg_wt  = (short*)(ws + OFF_MERGEWT);
    short* fusedb2 = (short*)(ws + OFF_FUSEDB);
    short* z2b     = (short*)(ws + OFF_Z2B);
    short* ygb     = (short*)(ws + OFF_YGB);
    short* catb    = (short*)(ws + OFF_CAT);
    short* upb     = (short*)(ws + OFF_UPB);
    short* wconvb  = (short*)(ws + OFF_WCONVB);

    // 1. pf[s] = feats[s] @ proj_w[s]^T  (LDS-dbuf MFMA, f32-direct staging)
    proj_mfma_kernel<<<dim3(22, 4, 6), 256, 0, stream>>>(features, proj_w, pf);
    // 2. weight transposes
    transpose_cast_kernel<<<dim3(8, 32, 2), 256, 0, stream>>>(f_in_w, b_in_w, in_wt, 256, 1024);
    transpose_cast_kernel<<<dim3(16, 18, 2), 256, 0, stream>>>(f_xp_w, b_xp_w, xp_wt, 512, 545);
    transpose_cast_kernel<<<dim3(16, 8, 1), 256, 0, stream>>>(merge_w, merge_w, mrg_wt, 512, 256);
    // 3. column sums + attention weights
    colmean_kernel<<<dim3(6, 11), 256, 0, stream>>>(pf, colpart);
    attn_part1<<<dim3(12), 384, 0, stream>>>(colpart, attn_w1, attnp);
    attn_part2<<<1, 384, 0, stream>>>(attnp, attn_b1, attn_w2, attn_b2, src_scale, wfin);
    // 4. fuse sources (+ reversed), f32 + bf16
    fuse_kernel<<<dim3(1369), 256, 0, stream>>>(pf, wfin, fused2, fusedb2);
    // 4b. out_w transpose (pf region now dead)
    transpose_cast_kernel<<<dim3(16, 8, 2), 256, 0, stream>>>(f_out_w, b_out_w, out_wt, 512, 256);
    // 5. zg = fused @ in_w  (LDS-dbuf MFMA)
    mfma_nt<<<dim3(22, 16, 2), 256, 0, stream>>>(
        fusedb2, (long)kN * kCO, in_wt, (long)2 * kDI * kCO,
        zg2, (long)kN * 2 * kDI, kN, 2 * kDI, kCO);
    // 6. causal dwconv + silu -> z2 f32 + z2b bf16
    dwconv_kernel<<<dim3(2738, 2), 256, 0, stream>>>(zg2, f_conv_w, f_conv_b,
                                                     b_conv_w, b_conv_b, z2, z2b);
    // 7. xp = z @ xp_w  (LDS-dbuf MFMA)
    mfma_nt<<<dim3(22, 9, 2), 256, 0, stream>>>(
        z2b, (long)kN * kDI, xp_wt, (long)kXPW * kDI,
        xp2, kXPS, kN, kXPW, kDI);
    // 8. delta
    delta_kernel<<<dim3(2738, 2), 256, 0, stream>>>(xp2, delta2);
    // 9. chunk-parallel selective scan
    scan_partA<<<dim3(64, kNC), 256, 0, stream>>>(delta2, z2, xp2, f_Alog, b_Alog,
                                                  chunkP, chunkH);
    scan_partB<<<dim3(64), 256, 0, stream>>>(chunkP, chunkH, hin);
    scan_partC<<<dim3(64, kNC), 256, 0, stream>>>(delta2, z2, xp2, f_D, b_D,
                                                  f_Alog, b_Alog, hin, ybuf2);
    // 10. ygb = bf16(y * silu(gate))
    mulgate_kernel<<<dim3(2738, 2), 256, 0, stream>>>(zg2, ybuf2, ygb);
    // 11. gt = yg @ out_w  (LDS-dbuf MFMA)
    mfma_nt<<<dim3(22, 4, 2), 256, 0, stream>>>(
        ygb, (long)kN * kDI, out_wt, (long)kCO * kDI,
        gt2, (long)kN * kCO, kN, kCO, kDI);
    // 12. residual + LN + cat (bf16)
    resid_ln_cat_kernel<<<dim3(1369, 2), 256, 0, stream>>>(gt2, fused2, f_ln_g, f_ln_b,
                                                           b_ln_g, b_ln_b, catb);
    // 13. merged = cat @ merge_w  (LDS-dbuf MFMA)
    mfma_nt<<<dim3(22, 4, 1), 256, 0, stream>>>(
        catb, 0, mrg_wt, 0,
        merged, 0, kN, kCO, 2 * kCO);
    // 14. conv weight -> bf16 transposed [cout][2304]
    transpose_cast_kernel<<<dim3(72, 8, 1), 256, 0, stream>>>(co1_w, co1_w, wconvb, 2304, 256);
    // 15. zero padded bf16 upsample buffer
    hipMemsetAsync(upb, 0, (size_t)150 * 150 * 256 * sizeof(short), stream);
    // 16. bilinear upsample -> bf16 padded interior
    upsample_kernel<<<dim3(kNP), 256, 0, stream>>>(merged, upb);
    // 17. 3x3 conv via bf16 MFMA (LDS dbuf), NCHW output + bias
    conv_mfma_kernel<<<dim3(343, 2), 256, 0, stream>>>(upb, wconvb, co1_b, outp);
}

// Round 7
// 310.853 us; speedup vs baseline: 5.6880x; 1.0167x over previous
//
#include <hip/hip_runtime.h>
#include <math.h>

// ---------------------------------------------------------------------------
// Upnet_v3 pipeline, round 6:
//  - proj: 64x256 block tile (features read ONCE), chunked-bijective XCD
//    swizzle so each XCD's L2 holds its B panels; f32-direct staging
//  - conv3x3: K-step 64 (half the barriers, 16 MFMA/wave/step), full 8-seg
//    XOR swizzle on 128B LDS rows
// ---------------------------------------------------------------------------

namespace {
constexpr int kS   = 6;
constexpr int kHP  = 37;
constexpr int kWP  = 37;
constexpr int kN   = 1369;      // HP*WP
constexpr int kCIN = 1536;
constexpr int kCO  = 256;
constexpr int kDS  = 16;
constexpr int kDI  = 512;
constexpr int kHID = 384;
constexpr int kOH  = 148;
constexpr int kOW  = 148;
constexpr int kNP  = kOH * kOW; // 21904
constexpr int kXPW = 545;       // 2*DS + DI + 1
constexpr long kXPS = 746112;   // padded kN*kXPW per dir
constexpr int kNC  = 24;        // scan chunks
constexpr int kCH  = 58;        // chunk length (24*58 = 1392 >= 1369)

// ---- workspace ledger (f32 units, total <= 13,911,040 = 55.6 MB) ----------
constexpr long OFF_PF      = 0;         // pf (dead after fuse)
constexpr long OFF_Z2B     = 0;         // z2b bf16 (steps 6-9)
constexpr long OFF_YGB     = 0;         // ygb bf16 (steps 12-13)
constexpr long OFF_UPB     = 0;         // up_pad bf16 (steps 16+)
constexpr long OFF_SCANP   = 700928;
constexpr long OFF_SCANH   = 1094144;
constexpr long OFF_HIN     = 1487360;
constexpr long OFF_OUTWT   = 1880576;
constexpr long OFF_COLPART = 2102784;
constexpr long OFF_WFIN    = 2119680;
constexpr long OFF_ATTNP   = 2119696;
constexpr long OFF_INWT    = 2200000;
constexpr long OFF_FUSEDB  = 2462144;
constexpr long OFF_ZG      = 2820624;
constexpr long OFF_Z       = 5760000;
constexpr long OFF_WCONVB  = 6000000;
constexpr long OFF_XP      = 7161856;
constexpr long OFF_DELTA   = 8654080;
constexpr long OFF_Y       = 10055936;
constexpr long OFF_GT      = 11457792;
constexpr long OFF_XPWT    = 11457792;  // dead before gt2 is written
constexpr long OFF_FUSED2  = 12158720;
constexpr long OFF_CAT     = 12859648;
constexpr long OFF_MERGEWT = 13210112;
constexpr long OFF_MERGED  = 13560576;
} // namespace

typedef __attribute__((ext_vector_type(8))) short bf16x8;
typedef __attribute__((ext_vector_type(4))) float f32x4;

__device__ __forceinline__ short f2bf(float x) {
    unsigned u = __builtin_bit_cast(unsigned, x);
    unsigned r = u + 0x7fffu + ((u >> 16) & 1u);
    return (short)(r >> 16);
}

__device__ __forceinline__ bf16x8 cvt8(float4 x, float4 y) {
    union { short s[8]; bf16x8 v; } u;
    u.s[0] = f2bf(x.x); u.s[1] = f2bf(x.y); u.s[2] = f2bf(x.z); u.s[3] = f2bf(x.w);
    u.s[4] = f2bf(y.x); u.s[5] = f2bf(y.y); u.s[6] = f2bf(y.z); u.s[7] = f2bf(y.w);
    return u.v;
}

// tiled transpose+cast: w (K x N f32) -> wt (N x K bf16)
__global__ __launch_bounds__(256)
void transpose_cast_kernel(const float* __restrict__ w0, const float* __restrict__ w1,
                           short* __restrict__ wt, int K, int N)
{
    __shared__ float tile[32][33];
    int dir = blockIdx.z;
    const float* w = dir ? w1 : w0;
    short* o = wt + (long)dir * K * N;
    int k0 = blockIdx.x * 32, n0 = blockIdx.y * 32;
    int tx = threadIdx.x & 31, ty = threadIdx.x >> 5; // 32 x 8
    #pragma unroll
    for (int r = 0; r < 32; r += 8) {
        int k = k0 + ty + r, n = n0 + tx;
        tile[ty + r][tx] = (k < K && n < N) ? w[(long)k * N + n] : 0.f;
    }
    __syncthreads();
    #pragma unroll
    for (int r = 0; r < 32; r += 8) {
        int n = n0 + ty + r, k = k0 + tx;
        if (n < N && k < K) o[(long)n * K + k] = f2bf(tile[tx][ty + r]);
    }
}

// ---------------------------------------------------------------------------
// generic bf16 MFMA GEMM, NT form, LDS double-buffered (unchanged template)
// ---------------------------------------------------------------------------
__global__ __launch_bounds__(256)
void mfma_nt(const short* __restrict__ A, long sA,
             const short* __restrict__ B, long sB,
             float* __restrict__ C, long sC,
             int M, int N, int K)
{
    __shared__ short smem[2][4096];  // per buf: A bytes [0,4096), B [4096,8192)
    const int bz = blockIdx.z;
    const short* Ab = A + (long)bz * sA;
    const short* Bb = B + (long)bz * sB;
    float* Cb = C + (long)bz * sC;
    const int t = threadIdx.x, w = t >> 6, l = t & 63;
    const int lr = l & 15, sg = l >> 4;
    const int m0 = blockIdx.x * 64, n0 = blockIdx.y * 64;

    const int row = t >> 2, qa = t & 3;
    int am = m0 + row; if (am >= M) am = M - 1;
    int bn = n0 + row; if (bn >= N) bn = N - 1;
    const long ga = (long)am * K + qa * 8;
    const long gb = (long)bn * K + qa * 8;
    const int woffA = row * 64 + ((qa ^ ((row >> 1) & 3)) << 4);
    const int woffB = 4096 + woffA;

    int aoff[2], boff[2];
    #pragma unroll
    for (int mi = 0; mi < 2; ++mi) {
        int r = (w >> 1) * 32 + mi * 16 + lr;
        aoff[mi] = r * 64 + ((sg ^ ((r >> 1) & 3)) << 4);
    }
    #pragma unroll
    for (int ni = 0; ni < 2; ++ni) {
        int r = (w & 1) * 32 + ni * 16 + lr;
        boff[ni] = 4096 + r * 64 + ((sg ^ ((r >> 1) & 3)) << 4);
    }

    f32x4 acc[2][2] = {};
    const int NT = K >> 5;
    {
        bf16x8 sa = *(const bf16x8*)(Ab + ga);
        bf16x8 sb = *(const bf16x8*)(Bb + gb);
        char* lb = (char*)&smem[0][0];
        *(bf16x8*)(lb + woffA) = sa;
        *(bf16x8*)(lb + woffB) = sb;
    }
    __syncthreads();
    for (int tt = 0; tt < NT; ++tt) {
        bf16x8 nsa, nsb;
        if (tt + 1 < NT) {
            long o = (long)(tt + 1) * 32;
            nsa = *(const bf16x8*)(Ab + ga + o);
            nsb = *(const bf16x8*)(Bb + gb + o);
        }
        char* lb = (char*)&smem[tt & 1][0];
        bf16x8 a[2], b[2];
        #pragma unroll
        for (int mi = 0; mi < 2; ++mi) a[mi] = *(const bf16x8*)(lb + aoff[mi]);
        #pragma unroll
        for (int ni = 0; ni < 2; ++ni) b[ni] = *(const bf16x8*)(lb + boff[ni]);
        #pragma unroll
        for (int mi = 0; mi < 2; ++mi)
            #pragma unroll
            for (int ni = 0; ni < 2; ++ni)
                acc[mi][ni] = __builtin_amdgcn_mfma_f32_16x16x32_bf16(a[mi], b[ni], acc[mi][ni], 0, 0, 0);
        if (tt + 1 < NT) {
            char* nb = (char*)&smem[(tt + 1) & 1][0];
            *(bf16x8*)(nb + woffA) = nsa;
            *(bf16x8*)(nb + woffB) = nsb;
        }
        __syncthreads();
    }
    const int q = l >> 4;
    const int wm0 = m0 + (w >> 1) * 32, wn0 = n0 + (w & 1) * 32;
    #pragma unroll
    for (int mi = 0; mi < 2; ++mi)
        #pragma unroll
        for (int ni = 0; ni < 2; ++ni)
            #pragma unroll
            for (int r = 0; r < 4; ++r) {
                int m = wm0 + mi * 16 + q * 4 + r;
                int n = wn0 + ni * 16 + lr;
                if (m < M && n < N)
                    Cb[(long)m * N + n] = acc[mi][ni][r];
            }
}

// ---------------------------------------------------------------------------
// proj MFMA: 64m x 256n block (features read ONCE), f32-direct staging,
// chunked-bijective XCD swizzle over 132 blocks (each XCD sees <=2 s values
// so its B panels stay L2-resident). LDS 2 x 20KB, 4 waves each 64x64.
// ---------------------------------------------------------------------------
__global__ __launch_bounds__(256)
void proj_mfma_kernel(const float* __restrict__ Af, const float* __restrict__ Bf,
                      float* __restrict__ pf)
{
    __shared__ short smem[2][10240];  // per buf: A bytes [0,4096), B [4096,20480)
    // bijective chunked XCD swizzle: 132 blocks, 8 XCDs -> q=16, r=4
    const int bid = blockIdx.x;
    const int xcd = bid & 7, slot = bid >> 3;
    const int wid = (xcd < 4) ? xcd * 17 + slot : 68 + (xcd - 4) * 16 + slot;
    const int s = wid / 22, mblk = wid - s * 22;
    const float* A = Af + (long)s * kN * kCIN;
    const float* B = Bf + (long)s * kCO * kCIN;
    float* C = pf + (long)s * kN * kCO;
    const int m0 = mblk * 64;

    const int t = threadIdx.x, w = t >> 6, l = t & 63;
    const int lr = l & 15, sg = l >> 4;

    // staging: A 1 seg/thread (64 rows x 4 k-quarters), B 4 segs/thread
    const int row = t >> 2, qa = t & 3;
    int am = m0 + row; if (am >= kN) am = kN - 1;
    const long ga = (long)am * kCIN + qa * 8;
    const int woffA = row * 64 + ((qa ^ ((row >> 1) & 3)) << 4);
    long gb[4]; int woffB[4];
    #pragma unroll
    for (int j = 0; j < 4; ++j) {
        int br = row + j * 64;
        gb[j] = (long)br * kCIN + qa * 8;
        woffB[j] = 4096 + br * 64 + ((qa ^ ((br >> 1) & 3)) << 4);
    }

    // frag read offsets: wave w covers n in [w*64, w*64+64), all 64 m rows
    int aoff[4], boff[4];
    #pragma unroll
    for (int mi = 0; mi < 4; ++mi) {
        int r = mi * 16 + lr;
        aoff[mi] = r * 64 + ((sg ^ ((r >> 1) & 3)) << 4);
    }
    #pragma unroll
    for (int ni = 0; ni < 4; ++ni) {
        int r = w * 64 + ni * 16 + lr;
        boff[ni] = 4096 + r * 64 + ((sg ^ ((r >> 1) & 3)) << 4);
    }

    f32x4 acc[4][4] = {};
    const int NT = kCIN >> 5;   // 48
    {
        char* lb = (char*)&smem[0][0];
        float4 a0 = *(const float4*)(A + ga), a1 = *(const float4*)(A + ga + 4);
        *(bf16x8*)(lb + woffA) = cvt8(a0, a1);
        #pragma unroll
        for (int j = 0; j < 4; ++j) {
            float4 b0 = *(const float4*)(B + gb[j]), b1 = *(const float4*)(B + gb[j] + 4);
            *(bf16x8*)(lb + woffB[j]) = cvt8(b0, b1);
        }
    }
    __syncthreads();
    for (int tt = 0; tt < NT; ++tt) {
        float4 na0, na1, nb0[4], nb1[4];
        if (tt + 1 < NT) {
            long o = (long)(tt + 1) * 32;
            na0 = *(const float4*)(A + ga + o);
            na1 = *(const float4*)(A + ga + o + 4);
            #pragma unroll
            for (int j = 0; j < 4; ++j) {
                nb0[j] = *(const float4*)(B + gb[j] + o);
                nb1[j] = *(const float4*)(B + gb[j] + o + 4);
            }
        }
        char* lb = (char*)&smem[tt & 1][0];
        bf16x8 a[4], b[4];
        #pragma unroll
        for (int mi = 0; mi < 4; ++mi) a[mi] = *(const bf16x8*)(lb + aoff[mi]);
        #pragma unroll
        for (int ni = 0; ni < 4; ++ni) b[ni] = *(const bf16x8*)(lb + boff[ni]);
        #pragma unroll
        for (int mi = 0; mi < 4; ++mi)
            #pragma unroll
            for (int ni = 0; ni < 4; ++ni)
                acc[mi][ni] = __builtin_amdgcn_mfma_f32_16x16x32_bf16(a[mi], b[ni], acc[mi][ni], 0, 0, 0);
        if (tt + 1 < NT) {
            char* nb = (char*)&smem[(tt + 1) & 1][0];
            *(bf16x8*)(nb + woffA) = cvt8(na0, na1);
            #pragma unroll
            for (int j = 0; j < 4; ++j)
                *(bf16x8*)(nb + woffB[j]) = cvt8(nb0[j], nb1[j]);
        }
        __syncthreads();
    }
    const int q = l >> 4;
    const int wn0 = w * 64;
    #pragma unroll
    for (int mi = 0; mi < 4; ++mi)
        #pragma unroll
        for (int ni = 0; ni < 4; ++ni)
            #pragma unroll
            for (int r = 0; r < 4; ++r) {
                int m = m0 + mi * 16 + q * 4 + r;
                if (m < kN)
                    C[(long)m * kCO + wn0 + ni * 16 + lr] = acc[mi][ni][r];
            }
}

// ---------------------------------------------------------------------------
// conv3x3 MFMA, LDS dbuf, K-step 64 (36 steps). Block 64px x 128co, 4 waves
// (wave 32x64). LDS per buf: A[64][64] 8KB + B[128][64] 16KB = 24KB, x2=48KB.
// Staging 6 x 16B per thread per step; 8-seg XOR swizzle qa^(row&7).
// ---------------------------------------------------------------------------
__global__ __launch_bounds__(256)
void conv_mfma_kernel(const short* __restrict__ up, const short* __restrict__ wt,
                      const float* __restrict__ bias, float* __restrict__ out)
{
    __shared__ short smem[2][12288];   // per buf: A bytes [0,8192), B [8192,24576)
    const int t = threadIdx.x, w = t >> 6, l = t & 63;
    const int lr = l & 15, sg = l >> 4;
    const int pm0 = blockIdx.x * 64;
    const int bn0 = blockIdx.y * 128;

    const int srow = t >> 3, qa = t & 7;   // 32 base rows x 8 k-segs
    long gA[2]; int woffA[2];
    #pragma unroll
    for (int j = 0; j < 2; ++j) {
        int ar = srow + j * 32;
        int p = pm0 + ar; if (p >= kNP) p = kNP - 1;
        int oy = p / kOW, ox = p - oy * kOW;
        gA[j] = ((long)oy * 150 + ox) * kCO + qa * 8;
        woffA[j] = ar * 128 + ((qa ^ (ar & 7)) << 4);
    }
    long gB[4]; int woffB[4];
    #pragma unroll
    for (int j = 0; j < 4; ++j) {
        int br = srow + j * 32;
        gB[j] = (long)(bn0 + br) * 2304 + qa * 8;
        woffB[j] = 8192 + br * 128 + ((qa ^ (br & 7)) << 4);
    }

    int aoff[2][2], boff[4][2];
    #pragma unroll
    for (int mi = 0; mi < 2; ++mi) {
        int r = (w >> 1) * 32 + mi * 16 + lr;
        #pragma unroll
        for (int kk = 0; kk < 2; ++kk)
            aoff[mi][kk] = r * 128 + (((kk * 4 + sg) ^ (r & 7)) << 4);
    }
    #pragma unroll
    for (int ni = 0; ni < 4; ++ni) {
        int r = (w & 1) * 64 + ni * 16 + lr;
        #pragma unroll
        for (int kk = 0; kk < 2; ++kk)
            boff[ni][kk] = 8192 + r * 128 + (((kk * 4 + sg) ^ (r & 7)) << 4);
    }

    f32x4 acc[2][4] = {};
    const int NT = 36;  // 9 taps x 4 k-chunks of 64
    {
        char* lb = (char*)&smem[0][0];
        #pragma unroll
        for (int j = 0; j < 2; ++j)
            *(bf16x8*)(lb + woffA[j]) = *(const bf16x8*)(up + gA[j]);
        #pragma unroll
        for (int j = 0; j < 4; ++j)
            *(bf16x8*)(lb + woffB[j]) = *(const bf16x8*)(wt + gB[j]);
    }
    __syncthreads();

    for (int tt = 0; tt < NT; ++tt) {
        bf16x8 sa[2], sb[4];
        if (tt + 1 < NT) {
            int tn = tt + 1;
            int tap = tn >> 2, c0 = (tn & 3) << 6;
            int ky = tap / 3, kx = tap - ky * 3;
            long ta = ((long)ky * 150 + kx) * kCO + c0;
            long tb = (long)tn * 64;
            #pragma unroll
            for (int j = 0; j < 2; ++j) sa[j] = *(const bf16x8*)(up + gA[j] + ta);
            #pragma unroll
            for (int j = 0; j < 4; ++j) sb[j] = *(const bf16x8*)(wt + gB[j] + tb);
        }
        char* lb = (char*)&smem[tt & 1][0];
        #pragma unroll
        for (int kk = 0; kk < 2; ++kk) {
            bf16x8 a[2], b[4];
            #pragma unroll
            for (int mi = 0; mi < 2; ++mi) a[mi] = *(const bf16x8*)(lb + aoff[mi][kk]);
            #pragma unroll
            for (int ni = 0; ni < 4; ++ni) b[ni] = *(const bf16x8*)(lb + boff[ni][kk]);
            #pragma unroll
            for (int mi = 0; mi < 2; ++mi)
                #pragma unroll
                for (int ni = 0; ni < 4; ++ni)
                    acc[mi][ni] = __builtin_amdgcn_mfma_f32_16x16x32_bf16(a[mi], b[ni], acc[mi][ni], 0, 0, 0);
        }
        if (tt + 1 < NT) {
            char* nb = (char*)&smem[(tt + 1) & 1][0];
            #pragma unroll
            for (int j = 0; j < 2; ++j) *(bf16x8*)(nb + woffA[j]) = sa[j];
            #pragma unroll
            for (int j = 0; j < 4; ++j) *(bf16x8*)(nb + woffB[j]) = sb[j];
        }
        __syncthreads();
    }

    const int q = l >> 4;
    const int m0 = pm0 + (w >> 1) * 32;
    const int n0 = bn0 + (w & 1) * 64;
    #pragma unroll
    for (int mi = 0; mi < 2; ++mi)
        #pragma unroll
        for (int ni = 0; ni < 4; ++ni) {
            const int co = n0 + ni * 16 + lr;
            const float bv = bias[co];
            #pragma unroll
            for (int r = 0; r < 4; ++r) {
                int p = m0 + mi * 16 + q * 4 + r;
                if (p < kNP)
                    out[(long)co * kNP + p] = acc[mi][ni][r] + bv;
            }
        }
}

// partial column sums of pf over n
__global__ __launch_bounds__(256)
void colmean_kernel(const float* __restrict__ pf, float* __restrict__ colpart)
{
    int s = blockIdx.x, ch = blockIdx.y, o = threadIdx.x;
    int n0 = ch * 128, n1 = n0 + 128 > kN ? kN : n0 + 128;
    float a = 0.f;
    for (int n = n0; n < n1; ++n) a += pf[((long)s * kN + n) * kCO + o];
    colpart[ch * kS * kCO + s * kCO + o] = a;
}

// attn stage 1
__global__ __launch_bounds__(384)
void attn_part1(const float* __restrict__ colpart, const float* __restrict__ w1,
                float* __restrict__ partial)
{
    __shared__ float cm[128];
    int b = blockIdx.x, t = threadIdx.x;
    int c0 = b * 128;
    if (t < 128) {
        float a = 0.f;
        #pragma unroll
        for (int ch = 0; ch < 11; ++ch) a += colpart[ch * kS * kCO + c0 + t];
        cm[t] = a * (1.f / kN);
    }
    __syncthreads();
    float acc = 0.f;
    #pragma unroll 4
    for (int c = 0; c < 128; ++c) acc += cm[c] * w1[(long)(c0 + c) * kHID + t];
    partial[b * kHID + t] = acc;
}

// attn stage 2
__global__ __launch_bounds__(384)
void attn_part2(const float* __restrict__ partial, const float* __restrict__ b1,
                const float* __restrict__ w2, const float* __restrict__ b2,
                const float* __restrict__ ss, float* __restrict__ wfin)
{
    __shared__ float h[kHID];
    __shared__ float logits[8];
    int t = threadIdx.x;
    float acc = b1[t];
    #pragma unroll
    for (int b = 0; b < 12; ++b) acc += partial[b * kHID + t];
    h[t] = fmaxf(acc, 0.f);
    __syncthreads();
    if (t < kS) {
        float lg = b2[t];
        for (int j = 0; j < kHID; ++j) lg += h[j] * w2[j * kS + t];
        logits[t] = lg;
    }
    __syncthreads();
    if (t == 0) {
        float w[kS], mx = -1e30f, sum = 0.f;
        for (int s = 0; s < kS; ++s) mx = fmaxf(mx, logits[s]);
        for (int s = 0; s < kS; ++s) { w[s] = expf(logits[s] - mx); sum += w[s]; }
        for (int s = 0; s < kS; ++s) w[s] /= sum;
        mx = -1e30f;
        for (int s = 0; s < kS; ++s) { w[s] *= ss[s]; mx = fmaxf(mx, w[s]); }
        sum = 0.f;
        float e[kS];
        for (int s = 0; s < kS; ++s) { e[s] = expf(w[s] - mx); sum += e[s]; }
        for (int s = 0; s < kS; ++s) wfin[s] = e[s] / sum;
    }
}

// fused = sum_s wfin[s]*pf[s]; writes f32 fwd+rev and bf16 fwd+rev
__global__ __launch_bounds__(256)
void fuse_kernel(const float* __restrict__ pf, const float* __restrict__ wfin,
                 float* __restrict__ fused2, short* __restrict__ fusedb2)
{
    long idx = (long)blockIdx.x * 256 + threadIdx.x;
    if (idx >= (long)kN * kCO) return;
    float acc = 0.f;
    #pragma unroll
    for (int s = 0; s < kS; ++s) acc += wfin[s] * pf[(long)s * kN * kCO + idx];
    long n = idx / kCO; int c = (int)(idx % kCO);
    long ridx = (long)kN * kCO + (kN - 1 - n) * kCO + c;
    short bv = f2bf(acc);
    fused2[idx] = acc;
    fused2[ridx] = acc;
    fusedb2[idx] = bv;
    fusedb2[ridx] = bv;
}

// causal depthwise conv (K=4) + silu; writes f32 z2 and bf16 z2b
__global__ __launch_bounds__(256)
void dwconv_kernel(const float* __restrict__ zg2,
                   const float* __restrict__ wf, const float* __restrict__ bf,
                   const float* __restrict__ wb, const float* __restrict__ bb,
                   float* __restrict__ z2, short* __restrict__ z2b)
{
    long idx = (long)blockIdx.x * 256 + threadIdx.x;
    int dir = blockIdx.y;
    if (idx >= (long)kN * kDI) return;
    long n = idx >> 9; int i = (int)(idx & (kDI - 1));
    const float* zg = zg2 + (long)dir * kN * 2 * kDI;
    const float* w  = dir ? wb : wf;
    const float* b  = dir ? bb : bf;
    float acc = b[i];
    #pragma unroll
    for (int k = 0; k < 4; ++k) {
        long m = n - 3 + k;
        if (m >= 0) acc += w[k * kDI + i] * zg[m * 2 * kDI + i];
    }
    float sg = 1.f / (1.f + expf(-acc));
    float v = acc * sg;
    z2 [(long)dir * kN * kDI + idx] = v;
    z2b[(long)dir * kN * kDI + idx] = f2bf(v);
}

// delta = softplus(xp[:,32+i] + xp[:,544])
__global__ __launch_bounds__(256)
void delta_kernel(const float* __restrict__ xp2, float* __restrict__ delta2)
{
    long idx = (long)blockIdx.x * 256 + threadIdx.x;
    int dir = blockIdx.y;
    if (idx >= (long)kN * kDI) return;
    long n = idx >> 9; int i = (int)(idx & (kDI - 1));
    const float* xp = xp2 + (long)dir * kXPS + n * kXPW;
    float x = xp[2 * kDS + i] + xp[kXPW - 1];
    float sp = fmaxf(x, 0.f) + log1pf(expf(-fabsf(x)));
    delta2[(long)dir * kN * kDI + idx] = sp;
}

// ---- chunk-parallel scan: pass A ------------------------------------------
__global__ __launch_bounds__(256)
void scan_partA(const float* __restrict__ delta2, const float* __restrict__ z2,
                const float* __restrict__ xp2,
                const float* __restrict__ Alogf, const float* __restrict__ Alogb,
                float* __restrict__ chunkP, float* __restrict__ chunkH)
{
    int bx = blockIdx.x;
    int c  = blockIdx.y;
    int dir = bx >> 5, iblk = bx & 31;
    int t = threadIdx.x;
    int s = t & 15, il = t >> 4;
    int i = iblk * 16 + il;
    int gid = dir * 8192 + iblk * 256 + t;
    const float* delta = delta2 + (long)dir * kN * kDI;
    const float* z     = z2     + (long)dir * kN * kDI;
    const float* xp    = xp2    + (long)dir * kXPS;
    const float* Alog  = dir ? Alogb : Alogf;
    float A = expf(Alog[i * kDS + s]);
    int n0 = c * kCH, n1 = n0 + kCH; if (n1 > kN) n1 = kN;
    float h = 0.f, P = 1.f;
    for (int n = n0; n < n1; ++n) {
        float dlt = delta[(long)n * kDI + i];
        float zv  = z[(long)n * kDI + i];
        float Bv  = xp[(long)n * kXPW + s];
        float dA  = __expf(-dlt * A);
        h = dA * h + dlt * Bv * zv;
        P *= dA;
    }
    chunkP[(long)c * 16384 + gid] = P;
    chunkH[(long)c * 16384 + gid] = h;
}

// ---- pass B ----------------------------------------------------------------
__global__ __launch_bounds__(256)
void scan_partB(const float* __restrict__ chunkP, const float* __restrict__ chunkH,
                float* __restrict__ hin)
{
    int gid = blockIdx.x * 256 + threadIdx.x;
    float H = 0.f;
    for (int c = 0; c < kNC; ++c) {
        hin[(long)c * 16384 + gid] = H;
        H = chunkP[(long)c * 16384 + gid] * H + chunkH[(long)c * 16384 + gid];
    }
}

// ---- pass C ----------------------------------------------------------------
__global__ __launch_bounds__(256)
void scan_partC(const float* __restrict__ delta2, const float* __restrict__ z2,
                const float* __restrict__ xp2,
                const float* __restrict__ Df, const float* __restrict__ Db,
                const float* __restrict__ Alogf, const float* __restrict__ Alogb,
                const float* __restrict__ hin, float* __restrict__ ybuf2)
{
    int bx = blockIdx.x;
    int c  = blockIdx.y;
    int dir = bx >> 5, iblk = bx & 31;
    int t = threadIdx.x;
    int s = t & 15, il = t >> 4;
    int i = iblk * 16 + il;
    int gid = dir * 8192 + iblk * 256 + t;
    const float* delta = delta2 + (long)dir * kN * kDI;
    const float* z     = z2     + (long)dir * kN * kDI;
    const float* xp    = xp2    + (long)dir * kXPS;
    const float* D     = dir ? Db : Df;
    const float* Alog  = dir ? Alogb : Alogf;
    float* y           = ybuf2  + (long)dir * kN * kDI;
    float A  = expf(Alog[i * kDS + s]);
    float Dv = D[i];
    int n0 = c * kCH, n1 = n0 + kCH; if (n1 > kN) n1 = kN;
    float h = hin[(long)c * 16384 + gid];
    for (int n = n0; n < n1; ++n) {
        float dlt = delta[(long)n * kDI + i];
        float zv  = z[(long)n * kDI + i];
        float Bv  = xp[(long)n * kXPW + s];
        float Cv  = xp[(long)n * kXPW + kDS + s];
        float dA  = __expf(-dlt * A);
        h = dA * h + dlt * Bv * zv;
        float cc = h * Cv;
        cc += __shfl_xor(cc, 1, 16);
        cc += __shfl_xor(cc, 2, 16);
        cc += __shfl_xor(cc, 4, 16);
        cc += __shfl_xor(cc, 8, 16);
        if (s == 0) y[(long)n * kDI + i] = cc + Dv * zv;
    }
}

// ygb = bf16( y * silu(gate) )
__global__ __launch_bounds__(256)
void mulgate_kernel(const float* __restrict__ zg2, const float* __restrict__ ybuf2,
                    short* __restrict__ ygb)
{
    long idx = (long)blockIdx.x * 256 + threadIdx.x;
    int dir = blockIdx.y;
    if (idx >= (long)kN * kDI) return;
    long n = idx >> 9; int i = (int)(idx & (kDI - 1));
    float g = zg2[(long)dir * kN * 2 * kDI + n * 2 * kDI + kDI + i];
    float sg = 1.f / (1.f + expf(-g));
    float v = ybuf2[(long)dir * kN * kDI + idx] * g * sg;
    ygb[(long)dir * kN * kDI + idx] = f2bf(v);
}

// r = gemm_out + x; layernorm; write bf16 cat
__global__ __launch_bounds__(256)
void resid_ln_cat_kernel(const float* __restrict__ gt2, const float* __restrict__ x2,
                         const float* __restrict__ gf, const float* __restrict__ betf,
                         const float* __restrict__ gb, const float* __restrict__ betb,
                         short* __restrict__ catb)
{
    int n = blockIdx.x, dir = blockIdx.y, t = threadIdx.x;
    const float* gt = gt2 + ((long)dir * kN + n) * kCO;
    const float* x  = x2  + ((long)dir * kN + n) * kCO;
    const float* g  = dir ? gb : gf;
    const float* be = dir ? betb : betf;
    float r = gt[t] + x[t];
    float s1 = r, s2 = r * r;
    #pragma unroll
    for (int m = 32; m >= 1; m >>= 1) {
        s1 += __shfl_xor(s1, m, 64);
        s2 += __shfl_xor(s2, m, 64);
    }
    __shared__ float red[8];
    int w = t >> 6;
    if ((t & 63) == 0) { red[w] = s1; red[4 + w] = s2; }
    __syncthreads();
    float S1 = red[0] + red[1] + red[2] + red[3];
    float S2 = red[4] + red[5] + red[6] + red[7];
    float mu  = S1 * (1.f / kCO);
    float var = S2 * (1.f / kCO) - mu * mu;
    float inv = rsqrtf(var + 1e-5f);
    float v = g[t] * (r - mu) * inv + be[t];
    int row = dir ? (kN - 1 - n) : n;
    catb[(long)row * (2 * kCO) + dir * kCO + t] = f2bf(v);
}

// bilinear 4x upsample -> bf16 into zero-padded (150,150,256) interior
__global__ __launch_bounds__(256)
void upsample_kernel(const float* __restrict__ merged, short* __restrict__ up)
{
    int p = blockIdx.x;
    int oy = p / kOW, ox = p - oy * kOW;
    int c = threadIdx.x;
    float sy = (oy + 0.5f) * ((float)kHP / (float)kOH) - 0.5f;
    float sx = (ox + 0.5f) * ((float)kWP / (float)kOW) - 0.5f;
    int iy0 = (int)floorf(sy); float fy = sy - (float)iy0;
    int ix0 = (int)floorf(sx); float fx = sx - (float)ix0;
    float wy0 = 1.f - fy, wy1 = fy, wx0 = 1.f - fx, wx1 = fx;
    int iy1 = iy0 + 1, ix1 = ix0 + 1;
    if (iy0 < 0)       { iy0 = 0;       wy0 = 0.f; }
    if (iy1 > kHP - 1) { iy1 = kHP - 1; wy1 = 0.f; }
    if (ix0 < 0)       { ix0 = 0;       wx0 = 0.f; }
    if (ix1 > kWP - 1) { ix1 = kWP - 1; wx1 = 0.f; }
    float wys = wy0 + wy1; wy0 /= wys; wy1 /= wys;
    float wxs = wx0 + wx1; wx0 /= wxs; wx1 /= wxs;
    const float* M00 = merged + (long)(iy0 * kWP + ix0) * kCO;
    const float* M01 = merged + (long)(iy0 * kWP + ix1) * kCO;
    const float* M10 = merged + (long)(iy1 * kWP + ix0) * kCO;
    const float* M11 = merged + (long)(iy1 * kWP + ix1) * kCO;
    float v = wy0 * (wx0 * M00[c] + wx1 * M01[c]) + wy1 * (wx0 * M10[c] + wx1 * M11[c]);
    up[((long)(oy + 1) * 150 + (ox + 1)) * kCO + c] = f2bf(v);
}

extern "C" void kernel_launch(void* const* d_in, const int* in_sizes, int n_in,
                              void* d_out, int out_size, void* d_ws, size_t ws_size,
                              hipStream_t stream)
{
    (void)in_sizes; (void)n_in; (void)out_size; (void)ws_size;
    const float* features  = (const float*)d_in[0];
    const float* proj_w    = (const float*)d_in[1];
    const float* attn_w1   = (const float*)d_in[2];
    const float* attn_b1   = (const float*)d_in[3];
    const float* attn_w2   = (const float*)d_in[4];
    const float* attn_b2   = (const float*)d_in[5];
    const float* src_scale = (const float*)d_in[6];
    const float* f_in_w    = (const float*)d_in[7];
    const float* f_conv_w  = (const float*)d_in[8];
    const float* f_conv_b  = (const float*)d_in[9];
    const float* f_xp_w    = (const float*)d_in[10];
    const float* f_Alog    = (const float*)d_in[11];
    const float* f_D       = (const float*)d_in[12];
    const float* f_out_w   = (const float*)d_in[13];
    const float* f_ln_g    = (const float*)d_in[14];
    const float* f_ln_b    = (const float*)d_in[15];
    const float* b_in_w    = (const float*)d_in[16];
    const float* b_conv_w  = (const float*)d_in[17];
    const float* b_conv_b  = (const float*)d_in[18];
    const float* b_xp_w    = (const float*)d_in[19];
    const float* b_Alog    = (const float*)d_in[20];
    const float* b_D       = (const float*)d_in[21];
    const float* b_out_w   = (const float*)d_in[22];
    const float* b_ln_g    = (const float*)d_in[23];
    const float* b_ln_b    = (const float*)d_in[24];
    const float* merge_w   = (const float*)d_in[25];
    const float* co1_w     = (const float*)d_in[26];
    const float* co1_b     = (const float*)d_in[27];

    float* ws      = (float*)d_ws;
    float* outp    = (float*)d_out;
    float* pf      = ws + OFF_PF;
    float* colpart = ws + OFF_COLPART;
    float* wfin    = ws + OFF_WFIN;
    float* attnp   = ws + OFF_ATTNP;
    float* fused2  = ws + OFF_FUSED2;
    float* zg2     = ws + OFF_ZG;
    float* z2      = ws + OFF_Z;
    float* xp2     = ws + OFF_XP;
    float* delta2  = ws + OFF_DELTA;
    float* ybuf2   = ws + OFF_Y;
    float* gt2     = ws + OFF_GT;
    float* merged  = ws + OFF_MERGED;
    float* chunkP  = ws + OFF_SCANP;
    float* chunkH  = ws + OFF_SCANH;
    float* hin     = ws + OFF_HIN;
    short* in_wt   = (short*)(ws + OFF_INWT);
    short* xp_wt   = (short*)(ws + OFF_XPWT);
    short* out_wt  = (short*)(ws + OFF_OUTWT);
    short* mrg_wt  = (short*)(ws + OFF_MERGEWT);
    short* fusedb2 = (short*)(ws + OFF_FUSEDB);
    short* z2b     = (short*)(ws + OFF_Z2B);
    short* ygb     = (short*)(ws + OFF_YGB);
    short* catb    = (short*)(ws + OFF_CAT);
    short* upb     = (short*)(ws + OFF_UPB);
    short* wconvb  = (short*)(ws + OFF_WCONVB);

    // 1. pf[s] = feats[s] @ proj_w[s]^T  (64x256 tile, XCD-chunked swizzle)
    proj_mfma_kernel<<<dim3(132), 256, 0, stream>>>(features, proj_w, pf);
    // 2. weight transposes
    transpose_cast_kernel<<<dim3(8, 32, 2), 256, 0, stream>>>(f_in_w, b_in_w, in_wt, 256, 1024);
    transpose_cast_kernel<<<dim3(16, 18, 2), 256, 0, stream>>>(f_xp_w, b_xp_w, xp_wt, 512, 545);
    transpose_cast_kernel<<<dim3(16, 8, 1), 256, 0, stream>>>(merge_w, merge_w, mrg_wt, 512, 256);
    // 3. column sums + attention weights
    colmean_kernel<<<dim3(6, 11), 256, 0, stream>>>(pf, colpart);
    attn_part1<<<dim3(12), 384, 0, stream>>>(colpart, attn_w1, attnp);
    attn_part2<<<1, 384, 0, stream>>>(attnp, attn_b1, attn_w2, attn_b2, src_scale, wfin);
    // 4. fuse sources (+ reversed), f32 + bf16
    fuse_kernel<<<dim3(1369), 256, 0, stream>>>(pf, wfin, fused2, fusedb2);
    // 4b. out_w transpose (pf region now dead)
    transpose_cast_kernel<<<dim3(16, 8, 2), 256, 0, stream>>>(f_out_w, b_out_w, out_wt, 512, 256);
    // 5. zg = fused @ in_w  (LDS-dbuf MFMA)
    mfma_nt<<<dim3(22, 16, 2), 256, 0, stream>>>(
        fusedb2, (long)kN * kCO, in_wt, (long)2 * kDI * kCO,
        zg2, (long)kN * 2 * kDI, kN, 2 * kDI, kCO);
    // 6. causal dwconv + silu -> z2 f32 + z2b bf16
    dwconv_kernel<<<dim3(2738, 2), 256, 0, stream>>>(zg2, f_conv_w, f_conv_b,
                                                     b_conv_w, b_conv_b, z2, z2b);
    // 7. xp = z @ xp_w  (LDS-dbuf MFMA)
    mfma_nt<<<dim3(22, 9, 2), 256, 0, stream>>>(
        z2b, (long)kN * kDI, xp_wt, (long)kXPW * kDI,
        xp2, kXPS, kN, kXPW, kDI);
    // 8. delta
    delta_kernel<<<dim3(2738, 2), 256, 0, stream>>>(xp2, delta2);
    // 9. chunk-parallel selective scan
    scan_partA<<<dim3(64, kNC), 256, 0, stream>>>(delta2, z2, xp2, f_Alog, b_Alog,
                                                  chunkP, chunkH);
    scan_partB<<<dim3(64), 256, 0, stream>>>(chunkP, chunkH, hin);
    scan_partC<<<dim3(64, kNC), 256, 0, stream>>>(delta2, z2, xp2, f_D, b_D,
                                                  f_Alog, b_Alog, hin, ybuf2);
    // 10. ygb = bf16(y * silu(gate))
    mulgate_kernel<<<dim3(2738, 2), 256, 0, stream>>>(zg2, ybuf2, ygb);
    // 11. gt = yg @ out_w  (LDS-dbuf MFMA)
    mfma_nt<<<dim3(22, 4, 2), 256, 0, stream>>>(
        ygb, (long)kN * kDI, out_wt, (long)kCO * kDI,
        gt2, (long)kN * kCO, kN, kCO, kDI);
    // 12. residual + LN + cat (bf16)
    resid_ln_cat_kernel<<<dim3(1369, 2), 256, 0, stream>>>(gt2, fused2, f_ln_g, f_ln_b,
                                                           b_ln_g, b_ln_b, catb);
    // 13. merged = cat @ merge_w  (LDS-dbuf MFMA)
    mfma_nt<<<dim3(22, 4, 1), 256, 0, stream>>>(
        catb, 0, mrg_wt, 0,
        merged, 0, kN, kCO, 2 * kCO);
    // 14. conv weight -> bf16 transposed [cout][2304]
    transpose_cast_kernel<<<dim3(72, 8, 1), 256, 0, stream>>>(co1_w, co1_w, wconvb, 2304, 256);
    // 15. zero padded bf16 upsample buffer
    hipMemsetAsync(upb, 0, (size_t)150 * 150 * 256 * sizeof(short), stream);
    // 16. bilinear upsample -> bf16 padded interior
    upsample_kernel<<<dim3(kNP), 256, 0, stream>>>(merged, upb);
    // 17. 3x3 conv via bf16 MFMA (LDS dbuf, K-step 64), NCHW output + bias
    conv_mfma_kernel<<<dim3(343, 2), 256, 0, stream>>>(upb, wconvb, co1_b, outp);
}